// Round 1
// baseline (18453.464 us; speedup 1.0000x reference)
//
#include <hip/hip_runtime.h>
#include <hip/hip_bf16.h>

#define B_ 4
#define P_ 1024
#define G_ 1024
#define L_ 2048
#define D_ 512
#define FF_ 2048
#define H_ 8
#define DH_ 64
#define LAYERS_ 4
#define LN_EPS_ 1e-5f

// ---------------- concat pcpt+gen -> x ----------------
__global__ __launch_bounds__(256) void concat_kernel(const float* __restrict__ p,
    const float* __restrict__ g, float* __restrict__ x)
{
  const int LD4 = L_*D_/4, PD4 = P_*D_/4;
  int i = blockIdx.x*256 + threadIdx.x;
  int b = i / LD4, r = i - b*LD4;
  float4 v;
  if (r < PD4) v = ((const float4*)p)[(size_t)b*PD4 + r];
  else         v = ((const float4*)g)[(size_t)b*PD4 + (r-PD4)];
  ((float4*)x)[i] = v;
}

// ---------------- writeout: x -> (x[:, :P], x[:, P:]) concat flat ----------------
__global__ __launch_bounds__(256) void writeout_kernel(const float* __restrict__ x,
    float* __restrict__ out)
{
  const int LD4 = L_*D_/4, PD4 = P_*D_/4, HALF = B_*PD4;
  int i = blockIdx.x*256 + threadIdx.x;
  int half = (i >= HALF) ? 1 : 0;
  int r = i - half*HALF;
  int b = r / PD4, q = r - b*PD4;
  ((float4*)out)[i] = ((const float4*)x)[(size_t)b*LD4 + half*PD4 + q];
}

// ---------------- fp32 tiled GEMM: C = A(MxK) @ W(KxN) + bias (+res) (relu) ----------------
#define BM 64
#define BN 64
#define BK 16

template<int RELU, int RES>
__global__ __launch_bounds__(256) void gemm_kernel(
    const float* __restrict__ A, const float* __restrict__ W,
    const float* __restrict__ bias, const float* __restrict__ res,
    float* __restrict__ C, int M, int N, int K)
{
  __shared__ float As[BK][BM+4];
  __shared__ float Ws[BK][BN+4];
  int t  = threadIdx.x;
  int tx = t & 15, ty = t >> 4;
  int m0 = blockIdx.y * BM, n0 = blockIdx.x * BN;

  float acc[4][4];
  #pragma unroll
  for (int i=0;i<4;++i)
    #pragma unroll
    for (int j=0;j<4;++j) acc[i][j]=0.f;

  int am = t >> 2;         // 0..63 row within A tile
  int ak = (t & 3) * 4;    // 0,4,8,12
  int wk = t >> 4;         // 0..15 row within W tile
  int wn = (t & 15) * 4;   // 0..60

  for (int k0 = 0; k0 < K; k0 += BK) {
    float4 av = *(const float4*)(A + (size_t)(m0+am)*K + k0 + ak);
    float4 wv = *(const float4*)(W + (size_t)(k0+wk)*N + n0 + wn);
    __syncthreads();
    As[ak+0][am]=av.x; As[ak+1][am]=av.y; As[ak+2][am]=av.z; As[ak+3][am]=av.w;
    *(float4*)&Ws[wk][wn] = wv;
    __syncthreads();
    #pragma unroll
    for (int k=0;k<BK;++k) {
      float a0=As[k][ty*4+0], a1=As[k][ty*4+1], a2=As[k][ty*4+2], a3=As[k][ty*4+3];
      float b0=Ws[k][tx*4+0], b1=Ws[k][tx*4+1], b2=Ws[k][tx*4+2], b3=Ws[k][tx*4+3];
      acc[0][0]+=a0*b0; acc[0][1]+=a0*b1; acc[0][2]+=a0*b2; acc[0][3]+=a0*b3;
      acc[1][0]+=a1*b0; acc[1][1]+=a1*b1; acc[1][2]+=a1*b2; acc[1][3]+=a1*b3;
      acc[2][0]+=a2*b0; acc[2][1]+=a2*b1; acc[2][2]+=a2*b2; acc[2][3]+=a2*b3;
      acc[3][0]+=a3*b0; acc[3][1]+=a3*b1; acc[3][2]+=a3*b2; acc[3][3]+=a3*b3;
    }
  }

  float4 bv = ((const float4*)(bias + n0))[tx];
  #pragma unroll
  for (int i=0;i<4;++i) {
    int m = m0 + ty*4 + i;
    float4 c;
    c.x = acc[i][0]+bv.x; c.y = acc[i][1]+bv.y;
    c.z = acc[i][2]+bv.z; c.w = acc[i][3]+bv.w;
    if (RES) {
      float4 rv = *(const float4*)(res + (size_t)m*N + n0 + tx*4);
      c.x+=rv.x; c.y+=rv.y; c.z+=rv.z; c.w+=rv.w;
    }
    if (RELU) {
      c.x=fmaxf(c.x,0.f); c.y=fmaxf(c.y,0.f); c.z=fmaxf(c.z,0.f); c.w=fmaxf(c.w,0.f);
    }
    *(float4*)(C + (size_t)m*N + n0 + tx*4) = c;
  }
}

// ---------------- sparse attention: one block per (b,h,l) ----------------
__global__ __launch_bounds__(256) void attn_kernel(const float* __restrict__ qkv,
                                                   float* __restrict__ outa)
{
  __shared__ float sq[64];
  __shared__ float ss[1024];
  __shared__ float red[4];
  __shared__ float sstat[3]; // [0]=m then den, [1]=ed, [2]=dlog
  __shared__ float4 sacc[16][16];

  const float scale = 0.125f; // 1/sqrt(64)
  int t = threadIdx.x;
  int idx = blockIdx.x;
  int l  = idx & (L_-1);
  int bh = idx >> 11;
  int h  = bh & (H_-1);
  int b  = bh >> 3;
  bool isgen = (l >= P_);

  const float* qrow = qkv + ((size_t)(b*L_+l)*3 + 0)*D_ + h*DH_;
  if (t < 64) sq[t] = qrow[t];
  __syncthreads();

  // diagonal self-term for gen rows (wave 0)
  if (isgen && t < 64) {
    const float* krowl = qkv + ((size_t)(b*L_+l)*3 + 1)*D_ + h*DH_;
    float prod = sq[t]*krowl[t];
    for (int off=32; off>0; off>>=1) prod += __shfl_down(prod, off, 64);
    if (t==0) sstat[2] = prod*scale;
  }

  // scores vs first P keys
  float smax = -1e30f;
  #pragma unroll
  for (int pp=0; pp<4; ++pp) {
    int p = pp*256 + t;
    const float4* krow = (const float4*)(qkv + ((size_t)(b*L_+p)*3 + 1)*D_ + h*DH_);
    float acc = 0.f;
    #pragma unroll
    for (int dq=0; dq<16; ++dq) {
      float4 kv = krow[dq];
      float4 q4 = ((const float4*)sq)[dq];
      acc += kv.x*q4.x + kv.y*q4.y + kv.z*q4.z + kv.w*q4.w;
    }
    float s = acc*scale;
    ss[p] = s;
    smax = fmaxf(smax, s);
  }
  for (int off=32; off>0; off>>=1) smax = fmaxf(smax, __shfl_down(smax, off, 64));
  __syncthreads();
  if ((t & 63)==0) red[t>>6] = smax;
  __syncthreads();
  if (t==0) {
    float m = fmaxf(fmaxf(red[0],red[1]), fmaxf(red[2],red[3]));
    if (isgen) m = fmaxf(m, sstat[2]);
    sstat[0] = m;
  }
  __syncthreads();
  float m = sstat[0];

  float lsum = 0.f;
  #pragma unroll
  for (int pp=0; pp<4; ++pp) {
    int p = pp*256 + t;
    float e = __expf(ss[p]-m);
    ss[p] = e;
    lsum += e;
  }
  for (int off=32; off>0; off>>=1) lsum += __shfl_down(lsum, off, 64);
  __syncthreads();
  if ((t & 63)==0) red[t>>6] = lsum;
  __syncthreads();
  if (t==0) {
    float den = red[0]+red[1]+red[2]+red[3];
    float ed = 0.f;
    if (isgen) { ed = __expf(sstat[2]-m); den += ed; }
    sstat[0] = den; sstat[1] = ed;
  }
  __syncthreads();
  float den = sstat[0], ed = sstat[1];

  // PV: group g covers 64 p's, lane c covers 4 dims
  int gch = t >> 4;
  int c   = t & 15;
  float4 accv = make_float4(0.f,0.f,0.f,0.f);
  #pragma unroll 4
  for (int pi=0; pi<64; ++pi) {
    int p = gch*64 + pi;
    float w = ss[p];
    float4 vv = ((const float4*)(qkv + ((size_t)(b*L_+p)*3 + 2)*D_ + h*DH_))[c];
    accv.x += w*vv.x; accv.y += w*vv.y; accv.z += w*vv.z; accv.w += w*vv.w;
  }
  sacc[gch][c] = accv;
  __syncthreads();
  if (t < 16) {
    float4 o = make_float4(0.f,0.f,0.f,0.f);
    #pragma unroll
    for (int gi=0; gi<16; ++gi) {
      float4 a4 = sacc[gi][t];
      o.x+=a4.x; o.y+=a4.y; o.z+=a4.z; o.w+=a4.w;
    }
    if (isgen) {
      float4 vg = ((const float4*)(qkv + ((size_t)(b*L_+l)*3 + 2)*D_ + h*DH_))[t];
      o.x += ed*vg.x; o.y += ed*vg.y; o.z += ed*vg.z; o.w += ed*vg.w;
    }
    float r = 1.f/den;
    o.x*=r; o.y*=r; o.z*=r; o.w*=r;
    ((float4*)(outa + (size_t)(b*L_+l)*D_ + h*DH_))[t] = o;
  }
}

// ---------------- LayerNorm over rows of 512, one wave per row ----------------
__global__ __launch_bounds__(64) void ln_kernel(const float* __restrict__ y,
    const float* __restrict__ gw, const float* __restrict__ bw,
    float* __restrict__ x)
{
  int row = blockIdx.x, t = threadIdx.x;
  const float4* yr = (const float4*)(y + (size_t)row*D_);
  float4 v0 = yr[t], v1 = yr[t+64];
  float s = v0.x+v0.y+v0.z+v0.w + v1.x+v1.y+v1.z+v1.w;
  for (int off=32; off>0; off>>=1) s += __shfl_down(s, off, 64);
  s = __shfl(s, 0, 64);
  float mu = s * (1.f/D_);
  float dx;
  float q = 0.f;
  dx=v0.x-mu; q+=dx*dx; dx=v0.y-mu; q+=dx*dx; dx=v0.z-mu; q+=dx*dx; dx=v0.w-mu; q+=dx*dx;
  dx=v1.x-mu; q+=dx*dx; dx=v1.y-mu; q+=dx*dx; dx=v1.z-mu; q+=dx*dx; dx=v1.w-mu; q+=dx*dx;
  for (int off=32; off>0; off>>=1) q += __shfl_down(q, off, 64);
  q = __shfl(q, 0, 64);
  float rinv = rsqrtf(q*(1.f/D_) + LN_EPS_);
  const float4* g4 = (const float4*)gw;
  const float4* b4 = (const float4*)bw;
  float4 gv0=g4[t], gv1=g4[t+64], bv0=b4[t], bv1=b4[t+64];
  float4 o0, o1;
  o0.x=(v0.x-mu)*rinv*gv0.x+bv0.x; o0.y=(v0.y-mu)*rinv*gv0.y+bv0.y;
  o0.z=(v0.z-mu)*rinv*gv0.z+bv0.z; o0.w=(v0.w-mu)*rinv*gv0.w+bv0.w;
  o1.x=(v1.x-mu)*rinv*gv1.x+bv1.x; o1.y=(v1.y-mu)*rinv*gv1.y+bv1.y;
  o1.z=(v1.z-mu)*rinv*gv1.z+bv1.z; o1.w=(v1.w-mu)*rinv*gv1.w+bv1.w;
  float4* xr = (float4*)(x + (size_t)row*D_);
  xr[t]=o0; xr[t+64]=o1;
}

extern "C" void kernel_launch(void* const* d_in, const int* in_sizes, int n_in,
                              void* d_out, int out_size, void* d_ws, size_t ws_size,
                              hipStream_t stream) {
  const float* pcpt = (const float*)d_in[0];
  const float* gen  = (const float*)d_in[1];
  // d_in[2]: padding mask (all false) — ignored
  const float* Wqkv = (const float*)d_in[3];
  const float* bqkv = (const float*)d_in[4];
  const float* Wo   = (const float*)d_in[5];
  const float* bo   = (const float*)d_in[6];
  const float* W1   = (const float*)d_in[7];
  const float* b1   = (const float*)d_in[8];
  const float* W2   = (const float*)d_in[9];
  const float* b2   = (const float*)d_in[10];
  const float* g1   = (const float*)d_in[11];
  const float* be1  = (const float*)d_in[12];
  const float* g2   = (const float*)d_in[13];
  const float* be2  = (const float*)d_in[14];
  float* out = (float*)d_out;

  float* xbuf = (float*)d_ws;                         // B*L*D
  float* big  = xbuf + (size_t)B_*L_*D_;              // B*L*FF (aliases qkv B*L*3D and h)
  float* abuf = big  + (size_t)B_*L_*FF_;             // B*L*D
  float* ybuf = abuf + (size_t)B_*L_*D_;              // B*L*D

  const int M = B_*L_;

  concat_kernel<<<4096, 256, 0, stream>>>(pcpt, gen, xbuf);

  for (int i = 0; i < LAYERS_; ++i) {
    const float* Wqkv_i = Wqkv + (size_t)i*D_*3*D_;
    const float* bqkv_i = bqkv + (size_t)i*3*D_;
    const float* Wo_i   = Wo   + (size_t)i*D_*D_;
    const float* bo_i   = bo   + (size_t)i*D_;
    const float* W1_i   = W1   + (size_t)i*D_*FF_;
    const float* b1_i   = b1   + (size_t)i*FF_;
    const float* W2_i   = W2   + (size_t)i*FF_*D_;
    const float* b2_i   = b2   + (size_t)i*D_;
    const float* g1_i   = g1   + (size_t)i*D_;
    const float* be1_i  = be1  + (size_t)i*D_;
    const float* g2_i   = g2   + (size_t)i*D_;
    const float* be2_i  = be2  + (size_t)i*D_;

    // qkv = x @ Wqkv + bqkv   (M x 1536, K=512)
    gemm_kernel<0,0><<<dim3(3*D_/BN, M/BM), 256, 0, stream>>>(
        xbuf, Wqkv_i, bqkv_i, nullptr, big, M, 3*D_, D_);

    // attention
    attn_kernel<<<B_*H_*L_, 256, 0, stream>>>(big, abuf);

    // y = a @ Wo + bo + x   (M x 512, K=512)
    gemm_kernel<0,1><<<dim3(D_/BN, M/BM), 256, 0, stream>>>(
        abuf, Wo_i, bo_i, xbuf, ybuf, M, D_, D_);

    // x = LN(y)
    ln_kernel<<<M, 64, 0, stream>>>(ybuf, g1_i, be1_i, xbuf);

    // h = relu(x @ W1 + b1)  (M x 2048, K=512)
    gemm_kernel<1,0><<<dim3(FF_/BN, M/BM), 256, 0, stream>>>(
        xbuf, W1_i, b1_i, nullptr, big, M, FF_, D_);

    // y = h @ W2 + b2 + x    (M x 512, K=2048)
    gemm_kernel<0,1><<<dim3(D_/BN, M/BM), 256, 0, stream>>>(
        big, W2_i, b2_i, xbuf, ybuf, M, D_, FF_);

    // x = LN(y)
    ln_kernel<<<M, 64, 0, stream>>>(ybuf, g2_i, be2_i, xbuf);
  }

  writeout_kernel<<<4096, 256, 0, stream>>>(xbuf, out);
}

// Round 2
// 4058.777 us; speedup vs baseline: 4.5466x; 4.5466x over previous
//
#include <hip/hip_runtime.h>
#include <hip/hip_bf16.h>

#define B_ 4
#define P_ 1024
#define G_ 1024
#define L_ 2048
#define D_ 512
#define FF_ 2048
#define H_ 8
#define DH_ 64
#define LAYERS_ 4
#define LN_EPS_ 1e-5f

// ---------------- concat pcpt+gen -> x ----------------
__global__ __launch_bounds__(256) void concat_kernel(const float* __restrict__ p,
    const float* __restrict__ g, float* __restrict__ x)
{
  const int LD4 = L_*D_/4, PD4 = P_*D_/4;
  int i = blockIdx.x*256 + threadIdx.x;
  int b = i / LD4, r = i - b*LD4;
  float4 v;
  if (r < PD4) v = ((const float4*)p)[(size_t)b*PD4 + r];
  else         v = ((const float4*)g)[(size_t)b*PD4 + (r-PD4)];
  ((float4*)x)[i] = v;
}

// ---------------- writeout: x -> (x[:, :P], x[:, P:]) concat flat ----------------
__global__ __launch_bounds__(256) void writeout_kernel(const float* __restrict__ x,
    float* __restrict__ out)
{
  const int LD4 = L_*D_/4, PD4 = P_*D_/4, HALF = B_*PD4;
  int i = blockIdx.x*256 + threadIdx.x;
  int half = (i >= HALF) ? 1 : 0;
  int r = i - half*HALF;
  int b = r / PD4, q = r - b*PD4;
  ((float4*)out)[i] = ((const float4*)x)[(size_t)b*LD4 + half*PD4 + q];
}

// ---------------- fp32 tiled GEMM: C = A(MxK) @ W(KxN) + bias (+res) (relu) ----------------
#define BM 64
#define BN 64
#define BK 16

template<int RELU, int RES>
__global__ __launch_bounds__(256) void gemm_kernel(
    const float* __restrict__ A, const float* __restrict__ W,
    const float* __restrict__ bias, const float* __restrict__ res,
    float* __restrict__ C, int M, int N, int K)
{
  __shared__ float As[BK][BM+4];
  __shared__ float Ws[BK][BN+4];
  int t  = threadIdx.x;
  int tx = t & 15, ty = t >> 4;
  int m0 = blockIdx.y * BM, n0 = blockIdx.x * BN;

  float acc[4][4];
  #pragma unroll
  for (int i=0;i<4;++i)
    #pragma unroll
    for (int j=0;j<4;++j) acc[i][j]=0.f;

  int am = t >> 2;         // 0..63 row within A tile
  int ak = (t & 3) * 4;    // 0,4,8,12
  int wk = t >> 4;         // 0..15 row within W tile
  int wn = (t & 15) * 4;   // 0..60

  for (int k0 = 0; k0 < K; k0 += BK) {
    float4 av = *(const float4*)(A + (size_t)(m0+am)*K + k0 + ak);
    float4 wv = *(const float4*)(W + (size_t)(k0+wk)*N + n0 + wn);
    __syncthreads();
    As[ak+0][am]=av.x; As[ak+1][am]=av.y; As[ak+2][am]=av.z; As[ak+3][am]=av.w;
    *(float4*)&Ws[wk][wn] = wv;
    __syncthreads();
    #pragma unroll
    for (int k=0;k<BK;++k) {
      float a0=As[k][ty*4+0], a1=As[k][ty*4+1], a2=As[k][ty*4+2], a3=As[k][ty*4+3];
      float b0=Ws[k][tx*4+0], b1=Ws[k][tx*4+1], b2=Ws[k][tx*4+2], b3=Ws[k][tx*4+3];
      acc[0][0]+=a0*b0; acc[0][1]+=a0*b1; acc[0][2]+=a0*b2; acc[0][3]+=a0*b3;
      acc[1][0]+=a1*b0; acc[1][1]+=a1*b1; acc[1][2]+=a1*b2; acc[1][3]+=a1*b3;
      acc[2][0]+=a2*b0; acc[2][1]+=a2*b1; acc[2][2]+=a2*b2; acc[2][3]+=a2*b3;
      acc[3][0]+=a3*b0; acc[3][1]+=a3*b1; acc[3][2]+=a3*b2; acc[3][3]+=a3*b3;
    }
  }

  float4 bv = ((const float4*)(bias + n0))[tx];
  #pragma unroll
  for (int i=0;i<4;++i) {
    int m = m0 + ty*4 + i;
    float4 c;
    c.x = acc[i][0]+bv.x; c.y = acc[i][1]+bv.y;
    c.z = acc[i][2]+bv.z; c.w = acc[i][3]+bv.w;
    if (RES) {
      float4 rv = *(const float4*)(res + (size_t)m*N + n0 + tx*4);
      c.x+=rv.x; c.y+=rv.y; c.z+=rv.z; c.w+=rv.w;
    }
    if (RELU) {
      c.x=fmaxf(c.x,0.f); c.y=fmaxf(c.y,0.f); c.z=fmaxf(c.z,0.f); c.w=fmaxf(c.w,0.f);
    }
    *(float4*)(C + (size_t)m*N + n0 + tx*4) = c;
  }
}

// ---------------- flash-style sparse attention ----------------
// One block per (b, h, q-tile of 64). 256 threads: tx = t&15 (k/d groups),
// ty = t>>4 (q-row group of 4). LDS tiles 64x68 (pad 4 keeps float4 align,
// breaks power-of-2 bank strides). Ks is reused to hold P after S-compute.
__global__ __launch_bounds__(256) void attn_flash(const float* __restrict__ qkv,
                                                  float* __restrict__ outa)
{
  __shared__ float Qs[64][68];
  __shared__ float Ks[64][68];   // aliased: K tile, then P tile, then K-diag
  __shared__ float Vs[64][68];   // V tile, then V-diag
  __shared__ float dls[64];

  const float scale = 0.125f;    // 1/sqrt(64)
  int t  = threadIdx.x;
  int tx = t & 15, ty = t >> 4;
  int qt = blockIdx.x & 31;
  int h  = (blockIdx.x >> 5) & 7;
  int b  = blockIdx.x >> 8;
  int l0 = qt * 64;
  bool isgen = (l0 >= P_);       // block-uniform

  const size_t base = ((size_t)b * L_) * 3 * D_;   // qkv[b]
  const int hoff = h * DH_;

  // ---- load Q tile (rows l0..l0+63) ----
  #pragma unroll
  for (int c = 0; c < 4; ++c) {
    int r = ty + 16*c;
    float4 v = *(const float4*)(qkv + base + (size_t)(l0 + r)*3*D_ + 0*D_ + hoff + 4*tx);
    *(float4*)&Qs[r][4*tx] = v;
  }

  float m[4], den[4], o[4][4];
  #pragma unroll
  for (int i=0;i<4;++i) {
    m[i] = -1e30f; den[i] = 0.f;
    #pragma unroll
    for (int j=0;j<4;++j) o[i][j] = 0.f;
  }

  for (int kt = 0; kt < 16; ++kt) {
    int p0 = kt * 64;
    __syncthreads();   // prev PV reads of Ks/Vs done
    #pragma unroll
    for (int c = 0; c < 4; ++c) {
      int r = ty + 16*c;
      const float* rowb = qkv + base + (size_t)(p0 + r)*3*D_;
      float4 kv = *(const float4*)(rowb + 1*D_ + hoff + 4*tx);
      float4 vv = *(const float4*)(rowb + 2*D_ + hoff + 4*tx);
      *(float4*)&Ks[r][4*tx] = kv;
      *(float4*)&Vs[r][4*tx] = vv;
    }
    __syncthreads();

    // ---- S = Q K^T (64x64x64), s[i][j] = S[4ty+i][tx+16j] ----
    float s[4][4];
    #pragma unroll
    for (int i=0;i<4;++i)
      #pragma unroll
      for (int j=0;j<4;++j) s[i][j]=0.f;

    #pragma unroll
    for (int dc = 0; dc < 16; ++dc) {
      float4 q0 = *(const float4*)&Qs[4*ty+0][4*dc];
      float4 q1 = *(const float4*)&Qs[4*ty+1][4*dc];
      float4 q2 = *(const float4*)&Qs[4*ty+2][4*dc];
      float4 q3 = *(const float4*)&Qs[4*ty+3][4*dc];
      float4 k0 = *(const float4*)&Ks[tx     ][4*dc];
      float4 k1 = *(const float4*)&Ks[tx + 16][4*dc];
      float4 k2 = *(const float4*)&Ks[tx + 32][4*dc];
      float4 k3 = *(const float4*)&Ks[tx + 48][4*dc];
      #define DOT4(a,bv) (fmaf((a).x,(bv).x, fmaf((a).y,(bv).y, fmaf((a).z,(bv).z, (a).w*(bv).w))))
      s[0][0]+=DOT4(q0,k0); s[0][1]+=DOT4(q0,k1); s[0][2]+=DOT4(q0,k2); s[0][3]+=DOT4(q0,k3);
      s[1][0]+=DOT4(q1,k0); s[1][1]+=DOT4(q1,k1); s[1][2]+=DOT4(q1,k2); s[1][3]+=DOT4(q1,k3);
      s[2][0]+=DOT4(q2,k0); s[2][1]+=DOT4(q2,k1); s[2][2]+=DOT4(q2,k2); s[2][3]+=DOT4(q2,k3);
      s[3][0]+=DOT4(q3,k0); s[3][1]+=DOT4(q3,k1); s[3][2]+=DOT4(q3,k2); s[3][3]+=DOT4(q3,k3);
      #undef DOT4
    }

    // ---- online softmax update (row stats across tx lanes, width 16) ----
    #pragma unroll
    for (int i=0;i<4;++i) {
      s[i][0]*=scale; s[i][1]*=scale; s[i][2]*=scale; s[i][3]*=scale;
      float rm = fmaxf(fmaxf(s[i][0],s[i][1]), fmaxf(s[i][2],s[i][3]));
      rm = fmaxf(rm, __shfl_xor(rm, 1, 16));
      rm = fmaxf(rm, __shfl_xor(rm, 2, 16));
      rm = fmaxf(rm, __shfl_xor(rm, 4, 16));
      rm = fmaxf(rm, __shfl_xor(rm, 8, 16));
      float mn = fmaxf(m[i], rm);
      float alpha = __expf(m[i] - mn);
      s[i][0] = __expf(s[i][0]-mn); s[i][1] = __expf(s[i][1]-mn);
      s[i][2] = __expf(s[i][2]-mn); s[i][3] = __expf(s[i][3]-mn);
      float ts = s[i][0]+s[i][1]+s[i][2]+s[i][3];
      ts += __shfl_xor(ts, 1, 16);
      ts += __shfl_xor(ts, 2, 16);
      ts += __shfl_xor(ts, 4, 16);
      ts += __shfl_xor(ts, 8, 16);
      den[i] = den[i]*alpha + ts;
      m[i] = mn;
      o[i][0]*=alpha; o[i][1]*=alpha; o[i][2]*=alpha; o[i][3]*=alpha;
    }

    // ---- P -> LDS (reuse Ks) ----
    __syncthreads();
    #pragma unroll
    for (int i=0;i<4;++i) {
      Ks[4*ty+i][tx     ] = s[i][0];
      Ks[4*ty+i][tx + 16] = s[i][1];
      Ks[4*ty+i][tx + 32] = s[i][2];
      Ks[4*ty+i][tx + 48] = s[i][3];
    }
    __syncthreads();

    // ---- O += P V (64x64x64), o[i][j] = O[4ty+i][4tx+j] ----
    #pragma unroll
    for (int kc = 0; kc < 16; ++kc) {
      float4 p0v = *(const float4*)&Ks[4*ty+0][4*kc];
      float4 p1v = *(const float4*)&Ks[4*ty+1][4*kc];
      float4 p2v = *(const float4*)&Ks[4*ty+2][4*kc];
      float4 p3v = *(const float4*)&Ks[4*ty+3][4*kc];
      float4 v0 = *(const float4*)&Vs[4*kc+0][4*tx];
      float4 v1 = *(const float4*)&Vs[4*kc+1][4*tx];
      float4 v2 = *(const float4*)&Vs[4*kc+2][4*tx];
      float4 v3 = *(const float4*)&Vs[4*kc+3][4*tx];
      #define PVROW(i, pv) \
        o[i][0]=fmaf(pv.x,v0.x,fmaf(pv.y,v1.x,fmaf(pv.z,v2.x,fmaf(pv.w,v3.x,o[i][0])))); \
        o[i][1]=fmaf(pv.x,v0.y,fmaf(pv.y,v1.y,fmaf(pv.z,v2.y,fmaf(pv.w,v3.y,o[i][1])))); \
        o[i][2]=fmaf(pv.x,v0.z,fmaf(pv.y,v1.z,fmaf(pv.z,v2.z,fmaf(pv.w,v3.z,o[i][2])))); \
        o[i][3]=fmaf(pv.x,v0.w,fmaf(pv.y,v1.w,fmaf(pv.z,v2.w,fmaf(pv.w,v3.w,o[i][3]))));
      PVROW(0, p0v) PVROW(1, p1v) PVROW(2, p2v) PVROW(3, p3v)
      #undef PVROW
    }
  }

  // ---- diagonal self-term for gen tiles ----
  if (isgen) {
    __syncthreads();
    #pragma unroll
    for (int c = 0; c < 4; ++c) {
      int r = ty + 16*c;
      const float* rowb = qkv + base + (size_t)(l0 + r)*3*D_;
      float4 kv = *(const float4*)(rowb + 1*D_ + hoff + 4*tx);
      float4 vv = *(const float4*)(rowb + 2*D_ + hoff + 4*tx);
      *(float4*)&Ks[r][4*tx] = kv;
      *(float4*)&Vs[r][4*tx] = vv;
    }
    __syncthreads();
    {
      int q = t >> 2, part = t & 3;
      float dsum = 0.f;
      #pragma unroll
      for (int u = 0; u < 4; ++u) {
        float4 qv = *(const float4*)&Qs[q][part*16 + 4*u];
        float4 kv = *(const float4*)&Ks[q][part*16 + 4*u];
        dsum = fmaf(qv.x,kv.x, fmaf(qv.y,kv.y, fmaf(qv.z,kv.z, fmaf(qv.w,kv.w, dsum))));
      }
      dsum += __shfl_xor(dsum, 1, 4);
      dsum += __shfl_xor(dsum, 2, 4);
      if (part == 0) dls[q] = dsum * scale;
    }
    __syncthreads();
    #pragma unroll
    for (int i=0;i<4;++i) {
      float dl = dls[4*ty+i];
      float mn = fmaxf(m[i], dl);
      float alpha = __expf(m[i] - mn);
      float ed = __expf(dl - mn);
      den[i] = den[i]*alpha + ed;
      float4 vg = *(const float4*)&Vs[4*ty+i][4*tx];
      o[i][0] = fmaf(ed, vg.x, o[i][0]*alpha);
      o[i][1] = fmaf(ed, vg.y, o[i][1]*alpha);
      o[i][2] = fmaf(ed, vg.z, o[i][2]*alpha);
      o[i][3] = fmaf(ed, vg.w, o[i][3]*alpha);
      m[i] = mn;
    }
  }

  // ---- epilogue ----
  #pragma unroll
  for (int i=0;i<4;++i) {
    float r = 1.f / den[i];
    float4 c = make_float4(o[i][0]*r, o[i][1]*r, o[i][2]*r, o[i][3]*r);
    *(float4*)(outa + ((size_t)b*L_ + l0 + 4*ty + i)*D_ + hoff + 4*tx) = c;
  }
}

// ---------------- LayerNorm over rows of 512, one wave per row ----------------
__global__ __launch_bounds__(64) void ln_kernel(const float* __restrict__ y,
    const float* __restrict__ gw, const float* __restrict__ bw,
    float* __restrict__ x)
{
  int row = blockIdx.x, t = threadIdx.x;
  const float4* yr = (const float4*)(y + (size_t)row*D_);
  float4 v0 = yr[t], v1 = yr[t+64];
  float s = v0.x+v0.y+v0.z+v0.w + v1.x+v1.y+v1.z+v1.w;
  for (int off=32; off>0; off>>=1) s += __shfl_down(s, off, 64);
  s = __shfl(s, 0, 64);
  float mu = s * (1.f/D_);
  float dx;
  float q = 0.f;
  dx=v0.x-mu; q+=dx*dx; dx=v0.y-mu; q+=dx*dx; dx=v0.z-mu; q+=dx*dx; dx=v0.w-mu; q+=dx*dx;
  dx=v1.x-mu; q+=dx*dx; dx=v1.y-mu; q+=dx*dx; dx=v1.z-mu; q+=dx*dx; dx=v1.w-mu; q+=dx*dx;
  for (int off=32; off>0; off>>=1) q += __shfl_down(q, off, 64);
  q = __shfl(q, 0, 64);
  float rinv = rsqrtf(q*(1.f/D_) + LN_EPS_);
  const float4* g4 = (const float4*)gw;
  const float4* b4 = (const float4*)bw;
  float4 gv0=g4[t], gv1=g4[t+64], bv0=b4[t], bv1=b4[t+64];
  float4 o0, o1;
  o0.x=(v0.x-mu)*rinv*gv0.x+bv0.x; o0.y=(v0.y-mu)*rinv*gv0.y+bv0.y;
  o0.z=(v0.z-mu)*rinv*gv0.z+bv0.z; o0.w=(v0.w-mu)*rinv*gv0.w+bv0.w;
  o1.x=(v1.x-mu)*rinv*gv1.x+bv1.x; o1.y=(v1.y-mu)*rinv*gv1.y+bv1.y;
  o1.z=(v1.z-mu)*rinv*gv1.z+bv1.z; o1.w=(v1.w-mu)*rinv*gv1.w+bv1.w;
  float4* xr = (float4*)(x + (size_t)row*D_);
  xr[t]=o0; xr[t+64]=o1;
}

extern "C" void kernel_launch(void* const* d_in, const int* in_sizes, int n_in,
                              void* d_out, int out_size, void* d_ws, size_t ws_size,
                              hipStream_t stream) {
  const float* pcpt = (const float*)d_in[0];
  const float* gen  = (const float*)d_in[1];
  // d_in[2]: padding mask (all false) — ignored
  const float* Wqkv = (const float*)d_in[3];
  const float* bqkv = (const float*)d_in[4];
  const float* Wo   = (const float*)d_in[5];
  const float* bo   = (const float*)d_in[6];
  const float* W1   = (const float*)d_in[7];
  const float* b1   = (const float*)d_in[8];
  const float* W2   = (const float*)d_in[9];
  const float* b2   = (const float*)d_in[10];
  const float* g1   = (const float*)d_in[11];
  const float* be1  = (const float*)d_in[12];
  const float* g2   = (const float*)d_in[13];
  const float* be2  = (const float*)d_in[14];
  float* out = (float*)d_out;

  float* xbuf = (float*)d_ws;                         // B*L*D
  float* big  = xbuf + (size_t)B_*L_*D_;              // B*L*FF (aliases qkv B*L*3D and h)
  float* abuf = big  + (size_t)B_*L_*FF_;             // B*L*D
  float* ybuf = abuf + (size_t)B_*L_*D_;              // B*L*D

  const int M = B_*L_;

  concat_kernel<<<4096, 256, 0, stream>>>(pcpt, gen, xbuf);

  for (int i = 0; i < LAYERS_; ++i) {
    const float* Wqkv_i = Wqkv + (size_t)i*D_*3*D_;
    const float* bqkv_i = bqkv + (size_t)i*3*D_;
    const float* Wo_i   = Wo   + (size_t)i*D_*D_;
    const float* bo_i   = bo   + (size_t)i*D_;
    const float* W1_i   = W1   + (size_t)i*D_*FF_;
    const float* b1_i   = b1   + (size_t)i*FF_;
    const float* W2_i   = W2   + (size_t)i*FF_*D_;
    const float* b2_i   = b2   + (size_t)i*D_;
    const float* g1_i   = g1   + (size_t)i*D_;
    const float* be1_i  = be1  + (size_t)i*D_;
    const float* g2_i   = g2   + (size_t)i*D_;
    const float* be2_i  = be2  + (size_t)i*D_;

    // qkv = x @ Wqkv + bqkv   (M x 1536, K=512)
    gemm_kernel<0,0><<<dim3(3*D_/BN, M/BM), 256, 0, stream>>>(
        xbuf, Wqkv_i, bqkv_i, nullptr, big, M, 3*D_, D_);

    // attention (flash-tiled)
    attn_flash<<<B_*H_*(L_/64), 256, 0, stream>>>(big, abuf);

    // y = a @ Wo + bo + x   (M x 512, K=512)
    gemm_kernel<0,1><<<dim3(D_/BN, M/BM), 256, 0, stream>>>(
        abuf, Wo_i, bo_i, xbuf, ybuf, M, D_, D_);

    // x = LN(y)
    ln_kernel<<<M, 64, 0, stream>>>(ybuf, g1_i, be1_i, xbuf);

    // h = relu(x @ W1 + b1)  (M x 2048, K=512)
    gemm_kernel<1,0><<<dim3(FF_/BN, M/BM), 256, 0, stream>>>(
        xbuf, W1_i, b1_i, nullptr, big, M, FF_, D_);

    // y = h @ W2 + b2 + x    (M x 512, K=2048)
    gemm_kernel<0,1><<<dim3(D_/BN, M/BM), 256, 0, stream>>>(
        big, W2_i, b2_i, xbuf, ybuf, M, D_, FF_);

    // x = LN(y)
    ln_kernel<<<M, 64, 0, stream>>>(ybuf, g2_i, be2_i, xbuf);
  }

  writeout_kernel<<<4096, 256, 0, stream>>>(xbuf, out);
}

// Round 3
// 2377.804 us; speedup vs baseline: 7.7607x; 1.7069x over previous
//
#include <hip/hip_runtime.h>
#include <hip/hip_bf16.h>

#define B_ 4
#define P_ 1024
#define G_ 1024
#define L_ 2048
#define D_ 512
#define FF_ 2048
#define H_ 8
#define DH_ 64
#define LAYERS_ 4
#define LN_EPS_ 1e-5f

typedef __attribute__((ext_vector_type(8))) short bf16x8;
typedef __attribute__((ext_vector_type(4))) float f32x4;

__device__ __forceinline__ ushort f2b(float f) {
  unsigned u = __float_as_uint(f);
  unsigned r = (u + 0x7fffu + ((u >> 16) & 1u)) >> 16;
  return (ushort)r;
}

// ---------------- concat pcpt+gen -> x (fp32) + xbf (bf16) ----------------
__global__ __launch_bounds__(256) void concat_kernel(const float* __restrict__ p,
    const float* __restrict__ g, float* __restrict__ x, ushort* __restrict__ xb)
{
  const int LD4 = L_*D_/4, PD4 = P_*D_/4;
  int i = blockIdx.x*256 + threadIdx.x;
  int b = i / LD4, r = i - b*LD4;
  float4 v;
  if (r < PD4) v = ((const float4*)p)[(size_t)b*PD4 + r];
  else         v = ((const float4*)g)[(size_t)b*PD4 + (r-PD4)];
  ((float4*)x)[i] = v;
  ushort4 h; h.x=f2b(v.x); h.y=f2b(v.y); h.z=f2b(v.z); h.w=f2b(v.w);
  ((ushort4*)xb)[i] = h;
}

// ---------------- writeout: x -> (x[:, :P], x[:, P:]) concat flat ----------------
__global__ __launch_bounds__(256) void writeout_kernel(const float* __restrict__ x,
    float* __restrict__ out)
{
  const int LD4 = L_*D_/4, PD4 = P_*D_/4, HALF = B_*PD4;
  int i = blockIdx.x*256 + threadIdx.x;
  int half = (i >= HALF) ? 1 : 0;
  int r = i - half*HALF;
  int b = r / PD4, q = r - b*PD4;
  ((float4*)out)[i] = ((const float4*)x)[(size_t)b*LD4 + half*PD4 + q];
}

// ---------------- weight transpose+convert: src K x N fp32 -> dst N x K bf16 ----------------
__global__ __launch_bounds__(256) void wconv_kernel(const float* __restrict__ src,
    ushort* __restrict__ dst, int K, int N)
{
  __shared__ float tile[32][33];
  int n0 = blockIdx.x*32, k0 = blockIdx.y*32, l = blockIdx.z;
  src += (size_t)l*K*N; dst += (size_t)l*K*N;
  int tx = threadIdx.x & 31, ty = threadIdx.x >> 5;   // ty 0..7
  #pragma unroll
  for (int u=0;u<4;++u) tile[ty+8*u][tx] = src[(size_t)(k0+ty+8*u)*N + n0+tx];
  __syncthreads();
  #pragma unroll
  for (int u=0;u<4;++u) dst[(size_t)(n0+ty+8*u)*K + k0+tx] = f2b(tile[tx][ty+8*u]);
}

// ---------------- bf16 MFMA GEMM: C = A(MxK) @ Bt(NxK)^T + bias (+res fp32) (relu) ----------------
// 128x128 tile, BK=32, 256 threads = 4 waves, each wave 64x64 via 4x4 of 16x16x32.
template<int RELU, int RES, int OUTBF>
__global__ __launch_bounds__(256) void mgemm(
    const ushort* __restrict__ A,    // M x K bf16
    const ushort* __restrict__ Bt,   // N x K bf16 (transposed weight)
    const float* __restrict__ bias,  // N fp32
    const float* __restrict__ res,   // M x N fp32 (if RES)
    void* __restrict__ Cout,         // fp32 or bf16 M x N
    int M, int N, int K)
{
  __shared__ ushort As[128*32];
  __shared__ ushort Bs[128*32];
  int t = threadIdx.x;
  int lane = t & 63, w = t >> 6;
  int wm = (w >> 1) * 64, wn = (w & 1) * 64;
  int m0 = blockIdx.y * 128, n0 = blockIdx.x * 128;

  f32x4 acc[4][4] = {};

  // staging: thread t loads 16B at (row = t>>2, col8 = (t&3)*8), rows +0 and +64
  int srow = t >> 2;
  int scol = (t & 3) * 8;
  const ushort* Ag = A + (size_t)(m0 + srow)*K + scol;
  const ushort* Bg = Bt + (size_t)(n0 + srow)*K + scol;
  ushort* Asw = As + srow*32 + scol;
  ushort* Bsw = Bs + srow*32 + scol;

  // fragment read base: lane&15 = row-in-16tile, lane>>4 = k-quad
  int fr = lane & 15, fq = lane >> 4;
  const ushort* Ard = As + (wm + fr)*32 + fq*8;
  const ushort* Brd = Bs + (wn + fr)*32 + fq*8;

  for (int k0 = 0; k0 < K; k0 += 32) {
    uint4 a0 = *(const uint4*)(Ag);
    uint4 a1 = *(const uint4*)(Ag + (size_t)64*K);
    uint4 b0 = *(const uint4*)(Bg);
    uint4 b1 = *(const uint4*)(Bg + (size_t)64*K);
    Ag += 32; Bg += 32;
    __syncthreads();
    *(uint4*)(Asw)         = a0;
    *(uint4*)(Asw + 64*32) = a1;
    *(uint4*)(Bsw)         = b0;
    *(uint4*)(Bsw + 64*32) = b1;
    __syncthreads();
    bf16x8 af[4], bfr[4];
    #pragma unroll
    for (int i=0;i<4;++i) af[i]  = *(const bf16x8*)(Ard + i*16*32);
    #pragma unroll
    for (int j=0;j<4;++j) bfr[j] = *(const bf16x8*)(Brd + j*16*32);
    #pragma unroll
    for (int i=0;i<4;++i)
      #pragma unroll
      for (int j=0;j<4;++j)
        acc[i][j] = __builtin_amdgcn_mfma_f32_16x16x32_bf16(af[i], bfr[j], acc[i][j], 0, 0, 0);
  }

  // epilogue: D[m = quad*4 + r][n = lane&15] per 16x16 tile
  int ncol = lane & 15;
  int rquad = (lane >> 4) * 4;
  #pragma unroll
  for (int j=0;j<4;++j) {
    int n = n0 + wn + j*16 + ncol;
    float bv = bias[n];
    #pragma unroll
    for (int i=0;i<4;++i) {
      int mbase = m0 + wm + i*16 + rquad;
      #pragma unroll
      for (int r=0;r<4;++r) {
        int m = mbase + r;
        float c = acc[i][j][r] + bv;
        if (RES) c += res[(size_t)m*N + n];
        if (RELU) c = fmaxf(c, 0.f);
        if (OUTBF) ((ushort*)Cout)[(size_t)m*N + n] = f2b(c);
        else       ((float*)Cout)[(size_t)m*N + n] = c;
      }
    }
  }
}

// ---------------- flash-style sparse attention (fp32 in, bf16 out) ----------------
__global__ __launch_bounds__(256) void attn_flash(const float* __restrict__ qkv,
                                                  ushort* __restrict__ outa)
{
  __shared__ float Qs[64][68];
  __shared__ float Ks[64][68];
  __shared__ float Vs[64][68];
  __shared__ float dls[64];

  const float scale = 0.125f;
  int t  = threadIdx.x;
  int tx = t & 15, ty = t >> 4;
  int qt = blockIdx.x & 31;
  int h  = (blockIdx.x >> 5) & 7;
  int b  = blockIdx.x >> 8;
  int l0 = qt * 64;
  bool isgen = (l0 >= P_);

  const size_t base = ((size_t)b * L_) * 3 * D_;
  const int hoff = h * DH_;

  #pragma unroll
  for (int c = 0; c < 4; ++c) {
    int r = ty + 16*c;
    float4 v = *(const float4*)(qkv + base + (size_t)(l0 + r)*3*D_ + 0*D_ + hoff + 4*tx);
    *(float4*)&Qs[r][4*tx] = v;
  }

  float m[4], den[4], o[4][4];
  #pragma unroll
  for (int i=0;i<4;++i) {
    m[i] = -1e30f; den[i] = 0.f;
    #pragma unroll
    for (int j=0;j<4;++j) o[i][j] = 0.f;
  }

  for (int kt = 0; kt < 16; ++kt) {
    int p0 = kt * 64;
    __syncthreads();
    #pragma unroll
    for (int c = 0; c < 4; ++c) {
      int r = ty + 16*c;
      const float* rowb = qkv + base + (size_t)(p0 + r)*3*D_;
      float4 kv = *(const float4*)(rowb + 1*D_ + hoff + 4*tx);
      float4 vv = *(const float4*)(rowb + 2*D_ + hoff + 4*tx);
      *(float4*)&Ks[r][4*tx] = kv;
      *(float4*)&Vs[r][4*tx] = vv;
    }
    __syncthreads();

    float s[4][4];
    #pragma unroll
    for (int i=0;i<4;++i)
      #pragma unroll
      for (int j=0;j<4;++j) s[i][j]=0.f;

    #pragma unroll
    for (int dc = 0; dc < 16; ++dc) {
      float4 q0 = *(const float4*)&Qs[4*ty+0][4*dc];
      float4 q1 = *(const float4*)&Qs[4*ty+1][4*dc];
      float4 q2 = *(const float4*)&Qs[4*ty+2][4*dc];
      float4 q3 = *(const float4*)&Qs[4*ty+3][4*dc];
      float4 k0 = *(const float4*)&Ks[tx     ][4*dc];
      float4 k1 = *(const float4*)&Ks[tx + 16][4*dc];
      float4 k2 = *(const float4*)&Ks[tx + 32][4*dc];
      float4 k3 = *(const float4*)&Ks[tx + 48][4*dc];
      #define DOT4(a,bv) (fmaf((a).x,(bv).x, fmaf((a).y,(bv).y, fmaf((a).z,(bv).z, (a).w*(bv).w))))
      s[0][0]+=DOT4(q0,k0); s[0][1]+=DOT4(q0,k1); s[0][2]+=DOT4(q0,k2); s[0][3]+=DOT4(q0,k3);
      s[1][0]+=DOT4(q1,k0); s[1][1]+=DOT4(q1,k1); s[1][2]+=DOT4(q1,k2); s[1][3]+=DOT4(q1,k3);
      s[2][0]+=DOT4(q2,k0); s[2][1]+=DOT4(q2,k1); s[2][2]+=DOT4(q2,k2); s[2][3]+=DOT4(q2,k3);
      s[3][0]+=DOT4(q3,k0); s[3][1]+=DOT4(q3,k1); s[3][2]+=DOT4(q3,k2); s[3][3]+=DOT4(q3,k3);
      #undef DOT4
    }

    #pragma unroll
    for (int i=0;i<4;++i) {
      s[i][0]*=scale; s[i][1]*=scale; s[i][2]*=scale; s[i][3]*=scale;
      float rm = fmaxf(fmaxf(s[i][0],s[i][1]), fmaxf(s[i][2],s[i][3]));
      rm = fmaxf(rm, __shfl_xor(rm, 1, 16));
      rm = fmaxf(rm, __shfl_xor(rm, 2, 16));
      rm = fmaxf(rm, __shfl_xor(rm, 4, 16));
      rm = fmaxf(rm, __shfl_xor(rm, 8, 16));
      float mn = fmaxf(m[i], rm);
      float alpha = __expf(m[i] - mn);
      s[i][0] = __expf(s[i][0]-mn); s[i][1] = __expf(s[i][1]-mn);
      s[i][2] = __expf(s[i][2]-mn); s[i][3] = __expf(s[i][3]-mn);
      float ts = s[i][0]+s[i][1]+s[i][2]+s[i][3];
      ts += __shfl_xor(ts, 1, 16);
      ts += __shfl_xor(ts, 2, 16);
      ts += __shfl_xor(ts, 4, 16);
      ts += __shfl_xor(ts, 8, 16);
      den[i] = den[i]*alpha + ts;
      m[i] = mn;
      o[i][0]*=alpha; o[i][1]*=alpha; o[i][2]*=alpha; o[i][3]*=alpha;
    }

    __syncthreads();
    #pragma unroll
    for (int i=0;i<4;++i) {
      Ks[4*ty+i][tx     ] = s[i][0];
      Ks[4*ty+i][tx + 16] = s[i][1];
      Ks[4*ty+i][tx + 32] = s[i][2];
      Ks[4*ty+i][tx + 48] = s[i][3];
    }
    __syncthreads();

    #pragma unroll
    for (int kc = 0; kc < 16; ++kc) {
      float4 p0v = *(const float4*)&Ks[4*ty+0][4*kc];
      float4 p1v = *(const float4*)&Ks[4*ty+1][4*kc];
      float4 p2v = *(const float4*)&Ks[4*ty+2][4*kc];
      float4 p3v = *(const float4*)&Ks[4*ty+3][4*kc];
      float4 v0 = *(const float4*)&Vs[4*kc+0][4*tx];
      float4 v1 = *(const float4*)&Vs[4*kc+1][4*tx];
      float4 v2 = *(const float4*)&Vs[4*kc+2][4*tx];
      float4 v3 = *(const float4*)&Vs[4*kc+3][4*tx];
      #define PVROW(i, pv) \
        o[i][0]=fmaf(pv.x,v0.x,fmaf(pv.y,v1.x,fmaf(pv.z,v2.x,fmaf(pv.w,v3.x,o[i][0])))); \
        o[i][1]=fmaf(pv.x,v0.y,fmaf(pv.y,v1.y,fmaf(pv.z,v2.y,fmaf(pv.w,v3.y,o[i][1])))); \
        o[i][2]=fmaf(pv.x,v0.z,fmaf(pv.y,v1.z,fmaf(pv.z,v2.z,fmaf(pv.w,v3.z,o[i][2])))); \
        o[i][3]=fmaf(pv.x,v0.w,fmaf(pv.y,v1.w,fmaf(pv.z,v2.w,fmaf(pv.w,v3.w,o[i][3]))));
      PVROW(0, p0v) PVROW(1, p1v) PVROW(2, p2v) PVROW(3, p3v)
      #undef PVROW
    }
  }

  if (isgen) {
    __syncthreads();
    #pragma unroll
    for (int c = 0; c < 4; ++c) {
      int r = ty + 16*c;
      const float* rowb = qkv + base + (size_t)(l0 + r)*3*D_;
      float4 kv = *(const float4*)(rowb + 1*D_ + hoff + 4*tx);
      float4 vv = *(const float4*)(rowb + 2*D_ + hoff + 4*tx);
      *(float4*)&Ks[r][4*tx] = kv;
      *(float4*)&Vs[r][4*tx] = vv;
    }
    __syncthreads();
    {
      int q = t >> 2, part = t & 3;
      float dsum = 0.f;
      #pragma unroll
      for (int u = 0; u < 4; ++u) {
        float4 qv = *(const float4*)&Qs[q][part*16 + 4*u];
        float4 kv = *(const float4*)&Ks[q][part*16 + 4*u];
        dsum = fmaf(qv.x,kv.x, fmaf(qv.y,kv.y, fmaf(qv.z,kv.z, fmaf(qv.w,kv.w, dsum))));
      }
      dsum += __shfl_xor(dsum, 1, 4);
      dsum += __shfl_xor(dsum, 2, 4);
      if (part == 0) dls[q] = dsum * scale;
    }
    __syncthreads();
    #pragma unroll
    for (int i=0;i<4;++i) {
      float dl = dls[4*ty+i];
      float mn = fmaxf(m[i], dl);
      float alpha = __expf(m[i] - mn);
      float ed = __expf(dl - mn);
      den[i] = den[i]*alpha + ed;
      float4 vg = *(const float4*)&Vs[4*ty+i][4*tx];
      o[i][0] = fmaf(ed, vg.x, o[i][0]*alpha);
      o[i][1] = fmaf(ed, vg.y, o[i][1]*alpha);
      o[i][2] = fmaf(ed, vg.z, o[i][2]*alpha);
      o[i][3] = fmaf(ed, vg.w, o[i][3]*alpha);
      m[i] = mn;
    }
  }

  #pragma unroll
  for (int i=0;i<4;++i) {
    float r = 1.f / den[i];
    ushort4 c;
    c.x = f2b(o[i][0]*r); c.y = f2b(o[i][1]*r);
    c.z = f2b(o[i][2]*r); c.w = f2b(o[i][3]*r);
    *(ushort4*)(outa + ((size_t)b*L_ + l0 + 4*ty + i)*D_ + hoff + 4*tx) = c;
  }
}

// ---------------- LayerNorm -> x fp32 + xbf bf16 ----------------
__global__ __launch_bounds__(64) void ln_kernel(const float* __restrict__ y,
    const float* __restrict__ gw, const float* __restrict__ bw,
    float* __restrict__ x, ushort* __restrict__ xb)
{
  int row = blockIdx.x, t = threadIdx.x;
  const float4* yr = (const float4*)(y + (size_t)row*D_);
  float4 v0 = yr[t], v1 = yr[t+64];
  float s = v0.x+v0.y+v0.z+v0.w + v1.x+v1.y+v1.z+v1.w;
  for (int off=32; off>0; off>>=1) s += __shfl_down(s, off, 64);
  s = __shfl(s, 0, 64);
  float mu = s * (1.f/D_);
  float dx;
  float q = 0.f;
  dx=v0.x-mu; q+=dx*dx; dx=v0.y-mu; q+=dx*dx; dx=v0.z-mu; q+=dx*dx; dx=v0.w-mu; q+=dx*dx;
  dx=v1.x-mu; q+=dx*dx; dx=v1.y-mu; q+=dx*dx; dx=v1.z-mu; q+=dx*dx; dx=v1.w-mu; q+=dx*dx;
  for (int off=32; off>0; off>>=1) q += __shfl_down(q, off, 64);
  q = __shfl(q, 0, 64);
  float rinv = rsqrtf(q*(1.f/D_) + LN_EPS_);
  const float4* g4 = (const float4*)gw;
  const float4* b4 = (const float4*)bw;
  float4 gv0=g4[t], gv1=g4[t+64], bv0=b4[t], bv1=b4[t+64];
  float4 o0, o1;
  o0.x=(v0.x-mu)*rinv*gv0.x+bv0.x; o0.y=(v0.y-mu)*rinv*gv0.y+bv0.y;
  o0.z=(v0.z-mu)*rinv*gv0.z+bv0.z; o0.w=(v0.w-mu)*rinv*gv0.w+bv0.w;
  o1.x=(v1.x-mu)*rinv*gv1.x+bv1.x; o1.y=(v1.y-mu)*rinv*gv1.y+bv1.y;
  o1.z=(v1.z-mu)*rinv*gv1.z+bv1.z; o1.w=(v1.w-mu)*rinv*gv1.w+bv1.w;
  float4* xr = (float4*)(x + (size_t)row*D_);
  xr[t]=o0; xr[t+64]=o1;
  ushort4 h0, h1;
  h0.x=f2b(o0.x); h0.y=f2b(o0.y); h0.z=f2b(o0.z); h0.w=f2b(o0.w);
  h1.x=f2b(o1.x); h1.y=f2b(o1.y); h1.z=f2b(o1.z); h1.w=f2b(o1.w);
  ushort4* xbr = (ushort4*)(xb + (size_t)row*D_);
  xbr[t]=h0; xbr[t+64]=h1;
}

extern "C" void kernel_launch(void* const* d_in, const int* in_sizes, int n_in,
                              void* d_out, int out_size, void* d_ws, size_t ws_size,
                              hipStream_t stream) {
  const float* pcpt = (const float*)d_in[0];
  const float* gen  = (const float*)d_in[1];
  const float* Wqkv = (const float*)d_in[3];
  const float* bqkv = (const float*)d_in[4];
  const float* Wo   = (const float*)d_in[5];
  const float* bo   = (const float*)d_in[6];
  const float* W1   = (const float*)d_in[7];
  const float* b1   = (const float*)d_in[8];
  const float* W2   = (const float*)d_in[9];
  const float* b2   = (const float*)d_in[10];
  const float* g1   = (const float*)d_in[11];
  const float* be1  = (const float*)d_in[12];
  const float* g2   = (const float*)d_in[13];
  const float* be2  = (const float*)d_in[14];
  float* out = (float*)d_out;

  const size_t XD  = (size_t)B_*L_*D_;     // 4,194,304
  const size_t QKV = (size_t)B_*L_*3*D_;   // 12,582,912

  float*  xbuf = (float*)d_ws;                 // fp32 x (residual)
  ushort* xbf  = (ushort*)(xbuf + XD);         // bf16 x
  float*  big  = (float*)(xbf + XD);           // fp32 qkv  /  bf16 h (aliased)
  ushort* hbf  = (ushort*)big;
  ushort* abf  = (ushort*)(big + QKV);         // bf16 attention out
  ushort* wb   = abf + XD;                     // bf16 transposed weights
  ushort* wqkv_b = wb;                                   // 4 x 1536 x 512
  ushort* wo_b   = wqkv_b + (size_t)4*3*D_*D_;           // 4 x 512 x 512
  ushort* w1_b   = wo_b   + (size_t)4*D_*D_;             // 4 x 2048 x 512
  ushort* w2_b   = w1_b   + (size_t)4*FF_*D_;            // 4 x 512 x 2048
  float*  ybuf = out;                          // reuse output buffer as y scratch

  const int M = B_*L_;

  // one-time (per launch) weight transpose+convert
  wconv_kernel<<<dim3(3*D_/32, D_/32, 4), 256, 0, stream>>>(Wqkv, wqkv_b, D_, 3*D_);
  wconv_kernel<<<dim3(D_/32,   D_/32, 4), 256, 0, stream>>>(Wo,   wo_b,   D_, D_);
  wconv_kernel<<<dim3(FF_/32,  D_/32, 4), 256, 0, stream>>>(W1,   w1_b,   D_, FF_);
  wconv_kernel<<<dim3(D_/32,  FF_/32, 4), 256, 0, stream>>>(W2,   w2_b,   FF_, D_);

  concat_kernel<<<4096, 256, 0, stream>>>(pcpt, gen, xbuf, xbf);

  for (int i = 0; i < LAYERS_; ++i) {
    const ushort* wqkv_i = wqkv_b + (size_t)i*3*D_*D_;
    const ushort* wo_i   = wo_b   + (size_t)i*D_*D_;
    const ushort* w1_i   = w1_b   + (size_t)i*FF_*D_;
    const ushort* w2_i   = w2_b   + (size_t)i*D_*FF_;
    const float* bqkv_i = bqkv + (size_t)i*3*D_;
    const float* bo_i   = bo   + (size_t)i*D_;
    const float* b1_i   = b1   + (size_t)i*FF_;
    const float* b2_i   = b2   + (size_t)i*D_;
    const float* g1_i   = g1   + (size_t)i*D_;
    const float* be1_i  = be1  + (size_t)i*D_;
    const float* g2_i   = g2   + (size_t)i*D_;
    const float* be2_i  = be2  + (size_t)i*D_;

    // qkv = x @ Wqkv + bqkv  -> fp32 (attention input)
    mgemm<0,0,0><<<dim3(3*D_/128, M/128), 256, 0, stream>>>(
        xbf, wqkv_i, bqkv_i, nullptr, big, M, 3*D_, D_);

    // attention (flash-tiled) -> bf16
    attn_flash<<<B_*H_*(L_/64), 256, 0, stream>>>(big, abf);

    // y = a @ Wo + bo + x -> fp32
    mgemm<0,1,0><<<dim3(D_/128, M/128), 256, 0, stream>>>(
        abf, wo_i, bo_i, xbuf, ybuf, M, D_, D_);

    // x = LN(y)
    ln_kernel<<<M, 64, 0, stream>>>(ybuf, g1_i, be1_i, xbuf, xbf);

    // h = relu(x @ W1 + b1) -> bf16
    mgemm<1,0,1><<<dim3(FF_/128, M/128), 256, 0, stream>>>(
        xbf, w1_i, b1_i, nullptr, hbf, M, FF_, D_);

    // y = h @ W2 + b2 + x -> fp32
    mgemm<0,1,0><<<dim3(D_/128, M/128), 256, 0, stream>>>(
        hbf, w2_i, b2_i, xbuf, ybuf, M, D_, FF_);

    // x = LN(y)
    ln_kernel<<<M, 64, 0, stream>>>(ybuf, g2_i, be2_i, xbuf, xbf);
  }

  writeout_kernel<<<4096, 256, 0, stream>>>(xbuf, out);
}

// Round 4
// 1036.526 us; speedup vs baseline: 17.8032x; 2.2940x over previous
//
#include <hip/hip_runtime.h>
#include <hip/hip_bf16.h>

#define B_ 4
#define P_ 1024
#define G_ 1024
#define L_ 2048
#define D_ 512
#define FF_ 2048
#define H_ 8
#define DH_ 64
#define LAYERS_ 4
#define LN_EPS_ 1e-5f

typedef __attribute__((ext_vector_type(8))) short bf16x8;
typedef __attribute__((ext_vector_type(4))) float f32x4;

__device__ __forceinline__ ushort f2b(float f) {
  unsigned u = __float_as_uint(f);
  unsigned r = (u + 0x7fffu + ((u >> 16) & 1u)) >> 16;
  return (ushort)r;
}
__device__ __forceinline__ float b2f(ushort u) {
  return __uint_as_float(((unsigned)u) << 16);
}

// ---------------- concat pcpt+gen -> x (fp32) + xbf (bf16) ----------------
__global__ __launch_bounds__(256) void concat_kernel(const float* __restrict__ p,
    const float* __restrict__ g, float* __restrict__ x, ushort* __restrict__ xb)
{
  const int LD4 = L_*D_/4, PD4 = P_*D_/4;
  int i = blockIdx.x*256 + threadIdx.x;
  int b = i / LD4, r = i - b*LD4;
  float4 v;
  if (r < PD4) v = ((const float4*)p)[(size_t)b*PD4 + r];
  else         v = ((const float4*)g)[(size_t)b*PD4 + (r-PD4)];
  ((float4*)x)[i] = v;
  ushort4 h; h.x=f2b(v.x); h.y=f2b(v.y); h.z=f2b(v.z); h.w=f2b(v.w);
  ((ushort4*)xb)[i] = h;
}

// ---------------- writeout ----------------
__global__ __launch_bounds__(256) void writeout_kernel(const float* __restrict__ x,
    float* __restrict__ out)
{
  const int LD4 = L_*D_/4, PD4 = P_*D_/4, HALF = B_*PD4;
  int i = blockIdx.x*256 + threadIdx.x;
  int half = (i >= HALF) ? 1 : 0;
  int r = i - half*HALF;
  int b = r / PD4, q = r - b*PD4;
  ((float4*)out)[i] = ((const float4*)x)[(size_t)b*LD4 + half*PD4 + q];
}

// ---------------- weight transpose+convert: src K x N fp32 -> dst N x K bf16 ----------------
__global__ __launch_bounds__(256) void wconv_kernel(const float* __restrict__ src,
    ushort* __restrict__ dst, int K, int N)
{
  __shared__ float tile[32][33];
  int n0 = blockIdx.x*32, k0 = blockIdx.y*32, l = blockIdx.z;
  src += (size_t)l*K*N; dst += (size_t)l*K*N;
  int tx = threadIdx.x & 31, ty = threadIdx.x >> 5;
  #pragma unroll
  for (int u=0;u<4;++u) tile[ty+8*u][tx] = src[(size_t)(k0+ty+8*u)*N + n0+tx];
  __syncthreads();
  #pragma unroll
  for (int u=0;u<4;++u) dst[(size_t)(n0+ty+8*u)*K + k0+tx] = f2b(tile[tx][ty+8*u]);
}

// ---------------- bf16 MFMA GEMM (generic) ----------------
template<int RELU, int RES, int OUTBF>
__global__ __launch_bounds__(256) void mgemm(
    const ushort* __restrict__ A, const ushort* __restrict__ Bt,
    const float* __restrict__ bias, const float* __restrict__ res,
    void* __restrict__ Cout, int M, int N, int K)
{
  __shared__ ushort As[128*32];
  __shared__ ushort Bs[128*32];
  int t = threadIdx.x;
  int lane = t & 63, w = t >> 6;
  int wm = (w >> 1) * 64, wn = (w & 1) * 64;
  int m0 = blockIdx.y * 128, n0 = blockIdx.x * 128;

  f32x4 acc[4][4] = {};

  int srow = t >> 2;
  int scol = (t & 3) * 8;
  const ushort* Ag = A + (size_t)(m0 + srow)*K + scol;
  const ushort* Bg = Bt + (size_t)(n0 + srow)*K + scol;
  ushort* Asw = As + srow*32 + scol;
  ushort* Bsw = Bs + srow*32 + scol;

  int fr = lane & 15, fq = lane >> 4;
  const ushort* Ard = As + (wm + fr)*32 + fq*8;
  const ushort* Brd = Bs + (wn + fr)*32 + fq*8;

  for (int k0 = 0; k0 < K; k0 += 32) {
    uint4 a0 = *(const uint4*)(Ag);
    uint4 a1 = *(const uint4*)(Ag + (size_t)64*K);
    uint4 b0 = *(const uint4*)(Bg);
    uint4 b1 = *(const uint4*)(Bg + (size_t)64*K);
    Ag += 32; Bg += 32;
    __syncthreads();
    *(uint4*)(Asw)         = a0;
    *(uint4*)(Asw + 64*32) = a1;
    *(uint4*)(Bsw)         = b0;
    *(uint4*)(Bsw + 64*32) = b1;
    __syncthreads();
    bf16x8 af[4], bfr[4];
    #pragma unroll
    for (int i=0;i<4;++i) af[i]  = *(const bf16x8*)(Ard + i*16*32);
    #pragma unroll
    for (int j=0;j<4;++j) bfr[j] = *(const bf16x8*)(Brd + j*16*32);
    #pragma unroll
    for (int i=0;i<4;++i)
      #pragma unroll
      for (int j=0;j<4;++j)
        acc[i][j] = __builtin_amdgcn_mfma_f32_16x16x32_bf16(af[i], bfr[j], acc[i][j], 0, 0, 0);
  }

  int ncol = lane & 15;
  int rquad = (lane >> 4) * 4;
  #pragma unroll
  for (int j=0;j<4;++j) {
    int n = n0 + wn + j*16 + ncol;
    float bv = bias[n];
    #pragma unroll
    for (int i=0;i<4;++i) {
      int mbase = m0 + wm + i*16 + rquad;
      #pragma unroll
      for (int r=0;r<4;++r) {
        int m = mbase + r;
        float c = acc[i][j][r] + bv;
        if (RES) c += res[(size_t)m*N + n];
        if (RELU) c = fmaxf(c, 0.f);
        if (OUTBF) ((ushort*)Cout)[(size_t)m*N + n] = f2b(c);
        else       ((float*)Cout)[(size_t)m*N + n] = c;
      }
    }
  }
}

// ---------------- QKV GEMM: bf16 out to q/k head-major + v transposed ----------------
__global__ __launch_bounds__(256) void mgemm_qkv(
    const ushort* __restrict__ A,    // M x 512 bf16 (x)
    const ushort* __restrict__ Bt,   // 1536 x 512 bf16
    const float* __restrict__ bias,  // 1536
    ushort* __restrict__ qb,         // [b,h,l,64]
    ushort* __restrict__ kb,         // [b,h,l,64]
    ushort* __restrict__ vtb)        // [b,h,64,l]
{
  const int K = D_, N = 3*D_;
  __shared__ ushort As[128*32];
  __shared__ ushort Bs[128*32];
  int t = threadIdx.x;
  int lane = t & 63, w = t >> 6;
  int wm = (w >> 1) * 64, wn = (w & 1) * 64;
  int m0 = blockIdx.y * 128, n0 = blockIdx.x * 128;

  f32x4 acc[4][4] = {};

  int srow = t >> 2;
  int scol = (t & 3) * 8;
  const ushort* Ag = A + (size_t)(m0 + srow)*K + scol;
  const ushort* Bg = Bt + (size_t)(n0 + srow)*K + scol;
  ushort* Asw = As + srow*32 + scol;
  ushort* Bsw = Bs + srow*32 + scol;

  int fr = lane & 15, fq = lane >> 4;
  const ushort* Ard = As + (wm + fr)*32 + fq*8;
  const ushort* Brd = Bs + (wn + fr)*32 + fq*8;

  for (int k0 = 0; k0 < K; k0 += 32) {
    uint4 a0 = *(const uint4*)(Ag);
    uint4 a1 = *(const uint4*)(Ag + (size_t)64*K);
    uint4 b0 = *(const uint4*)(Bg);
    uint4 b1 = *(const uint4*)(Bg + (size_t)64*K);
    Ag += 32; Bg += 32;
    __syncthreads();
    *(uint4*)(Asw)         = a0;
    *(uint4*)(Asw + 64*32) = a1;
    *(uint4*)(Bsw)         = b0;
    *(uint4*)(Bsw + 64*32) = b1;
    __syncthreads();
    bf16x8 af[4], bfr[4];
    #pragma unroll
    for (int i=0;i<4;++i) af[i]  = *(const bf16x8*)(Ard + i*16*32);
    #pragma unroll
    for (int j=0;j<4;++j) bfr[j] = *(const bf16x8*)(Brd + j*16*32);
    #pragma unroll
    for (int i=0;i<4;++i)
      #pragma unroll
      for (int j=0;j<4;++j)
        acc[i][j] = __builtin_amdgcn_mfma_f32_16x16x32_bf16(af[i], bfr[j], acc[i][j], 0, 0, 0);
  }

  int ncol = lane & 15;
  int rquad = (lane >> 4) * 4;
  #pragma unroll
  for (int j=0;j<4;++j) {
    int n = n0 + wn + j*16 + ncol;
    float bv = bias[n];
    int part = n >> 9;            // 0=q 1=k 2=v (uniform per block since 128|512)
    int wi = n & 511;
    int h = wi >> 6, d = wi & 63;
    #pragma unroll
    for (int i=0;i<4;++i) {
      int mbase = m0 + wm + i*16 + rquad;
      #pragma unroll
      for (int r=0;r<4;++r) {
        int m = mbase + r;
        int b = m >> 11, l = m & 2047;
        int bh = b*H_ + h;
        ushort c = f2b(acc[i][j][r] + bv);
        if (part == 0)      qb[((size_t)bh*L_ + l)*DH_ + d] = c;
        else if (part == 1) kb[((size_t)bh*L_ + l)*DH_ + d] = c;
        else                vtb[((size_t)bh*DH_ + d)*L_ + l] = c;
      }
    }
  }
}

// ---------------- MFMA flash attention ----------------
// block = (b,h,qtile of 64). 4 waves x 16 q-rows. All operands bf16 in LDS.
__global__ __launch_bounds__(256) void attn_mfma(
    const ushort* __restrict__ qb, const ushort* __restrict__ kb,
    const ushort* __restrict__ vtb, ushort* __restrict__ outa)
{
  __shared__ ushort Qs[64*72];
  __shared__ ushort Ks[64*72];
  __shared__ ushort Vts[64*72];
  __shared__ ushort Ps[4*16*72];
  __shared__ float dls[64];

  const float scale = 0.125f;
  int t = threadIdx.x;
  int lane = t & 63, w = t >> 6;
  int qt = blockIdx.x & 31;
  int h  = (blockIdx.x >> 5) & 7;
  int b  = blockIdx.x >> 8;
  int l0 = qt * 64;
  bool isgen = (l0 >= P_);
  int bh = b*H_ + h;

  const ushort* qg  = qb  + ((size_t)bh*L_ + l0)*DH_;   // 64 rows stride 64
  const ushort* kgb = kb  + (size_t)bh*L_*DH_;          // keys, stride 64
  const ushort* vtg = vtb + (size_t)bh*DH_*L_;          // 64 d-rows stride L_

  int sr = t >> 3, sc = (t & 7) * 8;   // staging: rows sr, sr+32; col sc

  // ---- stage Q ----
  {
    uint4 x0 = *(const uint4*)(qg + (size_t)sr*DH_ + sc);
    uint4 x1 = *(const uint4*)(qg + (size_t)(sr+32)*DH_ + sc);
    *(uint4*)(Qs + sr*72 + sc) = x0;
    *(uint4*)(Qs + (sr+32)*72 + sc) = x1;
  }
  __syncthreads();

  int fr = lane & 15, fq = lane >> 4;
  // cache Q A-frags (wave's 16 rows), 2 K-steps
  bf16x8 qf[2];
  qf[0] = *(const bf16x8*)(Qs + (16*w + fr)*72 + 0*32 + fq*8);
  qf[1] = *(const bf16x8*)(Qs + (16*w + fr)*72 + 1*32 + fq*8);

  float m[4], den[4];
  f32x4 o[4] = {};
  #pragma unroll
  for (int r=0;r<4;++r) { m[r] = -1e30f; den[r] = 0.f; }

  ushort* Pw = Ps + w*16*72;

  for (int kt = 0; kt < 16; ++kt) {
    int p0 = kt * 64;
    __syncthreads();
    {
      uint4 k0v = *(const uint4*)(kgb + (size_t)(p0+sr)*DH_ + sc);
      uint4 k1v = *(const uint4*)(kgb + (size_t)(p0+sr+32)*DH_ + sc);
      uint4 v0v = *(const uint4*)(vtg + (size_t)sr*L_ + p0 + sc);
      uint4 v1v = *(const uint4*)(vtg + (size_t)(sr+32)*L_ + p0 + sc);
      *(uint4*)(Ks + sr*72 + sc) = k0v;
      *(uint4*)(Ks + (sr+32)*72 + sc) = k1v;
      *(uint4*)(Vts + sr*72 + sc) = v0v;
      *(uint4*)(Vts + (sr+32)*72 + sc) = v1v;
    }
    __syncthreads();

    // ---- S = Q K^T : 4 n-tiles x 2 k-steps ----
    f32x4 sc4[4] = {};
    #pragma unroll
    for (int s=0;s<2;++s) {
      #pragma unroll
      for (int j=0;j<4;++j) {
        bf16x8 kf = *(const bf16x8*)(Ks + (j*16 + fr)*72 + s*32 + fq*8);
        sc4[j] = __builtin_amdgcn_mfma_f32_16x16x32_bf16(qf[s], kf, sc4[j], 0, 0, 0);
      }
    }

    // ---- online softmax (C-layout: row = fq*4+r, col = j*16 + fr) ----
    float p[4][4];
    #pragma unroll
    for (int r=0;r<4;++r) {
      float s0 = sc4[0][r]*scale, s1 = sc4[1][r]*scale,
            s2 = sc4[2][r]*scale, s3 = sc4[3][r]*scale;
      float rm = fmaxf(fmaxf(s0,s1), fmaxf(s2,s3));
      rm = fmaxf(rm, __shfl_xor(rm, 1, 16));
      rm = fmaxf(rm, __shfl_xor(rm, 2, 16));
      rm = fmaxf(rm, __shfl_xor(rm, 4, 16));
      rm = fmaxf(rm, __shfl_xor(rm, 8, 16));
      float mn = fmaxf(m[r], rm);
      float alpha = __expf(m[r] - mn);
      float e0 = __expf(s0-mn), e1 = __expf(s1-mn), e2 = __expf(s2-mn), e3 = __expf(s3-mn);
      float ts = e0+e1+e2+e3;
      ts += __shfl_xor(ts, 1, 16);
      ts += __shfl_xor(ts, 2, 16);
      ts += __shfl_xor(ts, 4, 16);
      ts += __shfl_xor(ts, 8, 16);
      den[r] = den[r]*alpha + ts;
      m[r] = mn;
      p[0][r]=e0; p[1][r]=e1; p[2][r]=e2; p[3][r]=e3;
      #pragma unroll
      for (int j=0;j<4;++j) o[j][r] *= alpha;
    }

    // ---- P -> wave-private LDS (A layout source) ----
    #pragma unroll
    for (int r=0;r<4;++r)
      #pragma unroll
      for (int j=0;j<4;++j)
        Pw[(fq*4+r)*72 + j*16 + fr] = f2b(p[j][r]);
    asm volatile("s_waitcnt lgkmcnt(0)" ::: "memory");

    // ---- O += P V ----
    #pragma unroll
    for (int s=0;s<2;++s) {
      bf16x8 pf = *(const bf16x8*)(Pw + fr*72 + s*32 + fq*8);
      #pragma unroll
      for (int j=0;j<4;++j) {
        bf16x8 vf = *(const bf16x8*)(Vts + (j*16 + fr)*72 + s*32 + fq*8);
        o[j] = __builtin_amdgcn_mfma_f32_16x16x32_bf16(pf, vf, o[j], 0, 0, 0);
      }
    }
  }

  // ---- diagonal self-term for gen tiles ----
  if (isgen) {
    __syncthreads();
    {
      uint4 k0v = *(const uint4*)(kgb + (size_t)(l0+sr)*DH_ + sc);
      uint4 k1v = *(const uint4*)(kgb + (size_t)(l0+sr+32)*DH_ + sc);
      uint4 v0v = *(const uint4*)(vtg + (size_t)sr*L_ + l0 + sc);
      uint4 v1v = *(const uint4*)(vtg + (size_t)(sr+32)*L_ + l0 + sc);
      *(uint4*)(Ks + sr*72 + sc) = k0v;
      *(uint4*)(Ks + (sr+32)*72 + sc) = k1v;
      *(uint4*)(Vts + sr*72 + sc) = v0v;
      *(uint4*)(Vts + (sr+32)*72 + sc) = v1v;
    }
    __syncthreads();
    {
      int row = t >> 2, part = t & 3;
      float dsum = 0.f;
      #pragma unroll
      for (int u=0;u<16;++u) {
        int d = part*16 + u;
        dsum = fmaf(b2f(Qs[row*72+d]), b2f(Ks[row*72+d]), dsum);
      }
      dsum += __shfl_xor(dsum, 1, 4);
      dsum += __shfl_xor(dsum, 2, 4);
      if (part == 0) dls[row] = dsum * scale;
    }
    __syncthreads();
    #pragma unroll
    for (int r=0;r<4;++r) {
      int rr = 16*w + fq*4 + r;
      float dl = dls[rr];
      float mn = fmaxf(m[r], dl);
      float alpha = __expf(m[r] - mn);
      float ed = __expf(dl - mn);
      den[r] = den[r]*alpha + ed;
      #pragma unroll
      for (int j=0;j<4;++j) {
        float vv = b2f(Vts[(j*16 + fr)*72 + rr]);
        o[j][r] = o[j][r]*alpha + ed*vv;
      }
      m[r] = mn;
    }
  }

  // ---- epilogue: out[b, l, h*64 + d] bf16 ----
  #pragma unroll
  for (int r=0;r<4;++r) {
    float inv = 1.f / den[r];
    int l = l0 + 16*w + fq*4 + r;
    #pragma unroll
    for (int j=0;j<4;++j)
      outa[((size_t)b*L_ + l)*D_ + h*DH_ + j*16 + fr] = f2b(o[j][r]*inv);
  }
}

// ---------------- LayerNorm -> x fp32 + xbf bf16 ----------------
__global__ __launch_bounds__(64) void ln_kernel(const float* __restrict__ y,
    const float* __restrict__ gw, const float* __restrict__ bw,
    float* __restrict__ x, ushort* __restrict__ xb)
{
  int row = blockIdx.x, t = threadIdx.x;
  const float4* yr = (const float4*)(y + (size_t)row*D_);
  float4 v0 = yr[t], v1 = yr[t+64];
  float s = v0.x+v0.y+v0.z+v0.w + v1.x+v1.y+v1.z+v1.w;
  for (int off=32; off>0; off>>=1) s += __shfl_down(s, off, 64);
  s = __shfl(s, 0, 64);
  float mu = s * (1.f/D_);
  float dx;
  float q = 0.f;
  dx=v0.x-mu; q+=dx*dx; dx=v0.y-mu; q+=dx*dx; dx=v0.z-mu; q+=dx*dx; dx=v0.w-mu; q+=dx*dx;
  dx=v1.x-mu; q+=dx*dx; dx=v1.y-mu; q+=dx*dx; dx=v1.z-mu; q+=dx*dx; dx=v1.w-mu; q+=dx*dx;
  for (int off=32; off>0; off>>=1) q += __shfl_down(q, off, 64);
  q = __shfl(q, 0, 64);
  float rinv = rsqrtf(q*(1.f/D_) + LN_EPS_);
  const float4* g4 = (const float4*)gw;
  const float4* b4 = (const float4*)bw;
  float4 gv0=g4[t], gv1=g4[t+64], bv0=b4[t], bv1=b4[t+64];
  float4 o0, o1;
  o0.x=(v0.x-mu)*rinv*gv0.x+bv0.x; o0.y=(v0.y-mu)*rinv*gv0.y+bv0.y;
  o0.z=(v0.z-mu)*rinv*gv0.z+bv0.z; o0.w=(v0.w-mu)*rinv*gv0.w+bv0.w;
  o1.x=(v1.x-mu)*rinv*gv1.x+bv1.x; o1.y=(v1.y-mu)*rinv*gv1.y+bv1.y;
  o1.z=(v1.z-mu)*rinv*gv1.z+bv1.z; o1.w=(v1.w-mu)*rinv*gv1.w+bv1.w;
  float4* xr = (float4*)(x + (size_t)row*D_);
  xr[t]=o0; xr[t+64]=o1;
  ushort4 h0, h1;
  h0.x=f2b(o0.x); h0.y=f2b(o0.y); h0.z=f2b(o0.z); h0.w=f2b(o0.w);
  h1.x=f2b(o1.x); h1.y=f2b(o1.y); h1.z=f2b(o1.z); h1.w=f2b(o1.w);
  ushort4* xbr = (ushort4*)(xb + (size_t)row*D_);
  xbr[t]=h0; xbr[t+64]=h1;
}

extern "C" void kernel_launch(void* const* d_in, const int* in_sizes, int n_in,
                              void* d_out, int out_size, void* d_ws, size_t ws_size,
                              hipStream_t stream) {
  const float* pcpt = (const float*)d_in[0];
  const float* gen  = (const float*)d_in[1];
  const float* Wqkv = (const float*)d_in[3];
  const float* bqkv = (const float*)d_in[4];
  const float* Wo   = (const float*)d_in[5];
  const float* bo   = (const float*)d_in[6];
  const float* W1   = (const float*)d_in[7];
  const float* b1   = (const float*)d_in[8];
  const float* W2   = (const float*)d_in[9];
  const float* b2   = (const float*)d_in[10];
  const float* g1   = (const float*)d_in[11];
  const float* be1  = (const float*)d_in[12];
  const float* g2   = (const float*)d_in[13];
  const float* be2  = (const float*)d_in[14];
  float* out = (float*)d_out;

  const size_t XD  = (size_t)B_*L_*D_;        // 4,194,304
  const size_t HKV = (size_t)B_*H_*L_*DH_;    // 4,194,304
  const size_t HFF = (size_t)B_*L_*FF_;       // 16,777,216

  float*  xbuf = (float*)d_ws;                     // 16 MB fp32 residual
  ushort* xbf  = (ushort*)(xbuf + XD);             // 8 MB bf16 x
  ushort* region = xbf + XD;                       // max(3*HKV, HFF) = HFF ushorts
  ushort* qb  = region;                            // aliased with hbf
  ushort* kb  = region + HKV;
  ushort* vtb = region + 2*HKV;
  ushort* hbf = region;
  ushort* abf = region + HFF;                      // 8 MB bf16 attn out
  ushort* wb  = abf + XD;                          // bf16 transposed weights
  ushort* wqkv_b = wb;
  ushort* wo_b   = wqkv_b + (size_t)4*3*D_*D_;
  ushort* w1_b   = wo_b   + (size_t)4*D_*D_;
  ushort* w2_b   = w1_b   + (size_t)4*FF_*D_;
  float*  ybuf = out;                              // reuse out as y scratch

  const int M = B_*L_;

  wconv_kernel<<<dim3(3*D_/32, D_/32, 4), 256, 0, stream>>>(Wqkv, wqkv_b, D_, 3*D_);
  wconv_kernel<<<dim3(D_/32,   D_/32, 4), 256, 0, stream>>>(Wo,   wo_b,   D_, D_);
  wconv_kernel<<<dim3(FF_/32,  D_/32, 4), 256, 0, stream>>>(W1,   w1_b,   D_, FF_);
  wconv_kernel<<<dim3(D_/32,  FF_/32, 4), 256, 0, stream>>>(W2,   w2_b,   FF_, D_);

  concat_kernel<<<4096, 256, 0, stream>>>(pcpt, gen, xbuf, xbf);

  for (int i = 0; i < LAYERS_; ++i) {
    const ushort* wqkv_i = wqkv_b + (size_t)i*3*D_*D_;
    const ushort* wo_i   = wo_b   + (size_t)i*D_*D_;
    const ushort* w1_i   = w1_b   + (size_t)i*FF_*D_;
    const ushort* w2_i   = w2_b   + (size_t)i*D_*FF_;
    const float* bqkv_i = bqkv + (size_t)i*3*D_;
    const float* bo_i   = bo   + (size_t)i*D_;
    const float* b1_i   = b1   + (size_t)i*FF_;
    const float* b2_i   = b2   + (size_t)i*D_;
    const float* g1_i   = g1   + (size_t)i*D_;
    const float* be1_i  = be1  + (size_t)i*D_;
    const float* g2_i   = g2   + (size_t)i*D_;
    const float* be2_i  = be2  + (size_t)i*D_;

    // qkv = x @ Wqkv + bqkv -> bf16 q/k head-major, v transposed
    mgemm_qkv<<<dim3(3*D_/128, M/128), 256, 0, stream>>>(
        xbf, wqkv_i, bqkv_i, qb, kb, vtb);

    // attention (MFMA flash) -> bf16
    attn_mfma<<<B_*H_*(L_/64), 256, 0, stream>>>(qb, kb, vtb, abf);

    // y = a @ Wo + bo + x -> fp32
    mgemm<0,1,0><<<dim3(D_/128, M/128), 256, 0, stream>>>(
        abf, wo_i, bo_i, xbuf, ybuf, M, D_, D_);

    ln_kernel<<<M, 64, 0, stream>>>(ybuf, g1_i, be1_i, xbuf, xbf);

    // h = relu(x @ W1 + b1) -> bf16
    mgemm<1,0,1><<<dim3(FF_/128, M/128), 256, 0, stream>>>(
        xbf, w1_i, b1_i, nullptr, hbf, M, FF_, D_);

    // y = h @ W2 + b2 + x -> fp32
    mgemm<0,1,0><<<dim3(D_/128, M/128), 256, 0, stream>>>(
        hbf, w2_i, b2_i, xbuf, ybuf, M, D_, FF_);

    ln_kernel<<<M, 64, 0, stream>>>(ybuf, g2_i, be2_i, xbuf, xbf);
  }

  writeout_kernel<<<4096, 256, 0, stream>>>(xbuf, out);
}

// Round 5
// 952.062 us; speedup vs baseline: 19.3826x; 1.0887x over previous
//
#include <hip/hip_runtime.h>
#include <hip/hip_bf16.h>

#define B_ 4
#define P_ 1024
#define G_ 1024
#define L_ 2048
#define D_ 512
#define FF_ 2048
#define H_ 8
#define DH_ 64
#define LAYERS_ 4
#define LN_EPS_ 1e-5f

typedef __attribute__((ext_vector_type(8))) short bf16x8;
typedef __attribute__((ext_vector_type(4))) float f32x4;

__device__ __forceinline__ ushort f2b(float f) {
  unsigned u = __float_as_uint(f);
  unsigned r = (u + 0x7fffu + ((u >> 16) & 1u)) >> 16;
  return (ushort)r;
}
__device__ __forceinline__ float b2f(ushort u) {
  return __uint_as_float(((unsigned)u) << 16);
}

// async 16B global->LDS (DMA; dest = wave-uniform base + lane*16)
__device__ __forceinline__ void gld16(const ushort* g, ushort* l) {
  __builtin_amdgcn_global_load_lds(
      (const __attribute__((address_space(1))) void*)g,
      (__attribute__((address_space(3))) void*)l, 16, 0, 0);
}

// ---------------- concat pcpt+gen -> x (fp32) + xbf (bf16) ----------------
__global__ __launch_bounds__(256) void concat_kernel(const float* __restrict__ p,
    const float* __restrict__ g, float* __restrict__ x, ushort* __restrict__ xb)
{
  const int LD4 = L_*D_/4, PD4 = P_*D_/4;
  int i = blockIdx.x*256 + threadIdx.x;
  int b = i / LD4, r = i - b*LD4;
  float4 v;
  if (r < PD4) v = ((const float4*)p)[(size_t)b*PD4 + r];
  else         v = ((const float4*)g)[(size_t)b*PD4 + (r-PD4)];
  ((float4*)x)[i] = v;
  ushort4 h; h.x=f2b(v.x); h.y=f2b(v.y); h.z=f2b(v.z); h.w=f2b(v.w);
  ((ushort4*)xb)[i] = h;
}

// ---------------- writeout ----------------
__global__ __launch_bounds__(256) void writeout_kernel(const float* __restrict__ x,
    float* __restrict__ out)
{
  const int LD4 = L_*D_/4, PD4 = P_*D_/4, HALF = B_*PD4;
  int i = blockIdx.x*256 + threadIdx.x;
  int half = (i >= HALF) ? 1 : 0;
  int r = i - half*HALF;
  int b = r / PD4, q = r - b*PD4;
  ((float4*)out)[i] = ((const float4*)x)[(size_t)b*LD4 + half*PD4 + q];
}

// ---------------- weight transpose+convert: src K x N fp32 -> dst N x K bf16 ----------------
__global__ __launch_bounds__(256) void wconv_kernel(const float* __restrict__ src,
    ushort* __restrict__ dst, int K, int N)
{
  __shared__ float tile[32][33];
  int n0 = blockIdx.x*32, k0 = blockIdx.y*32, l = blockIdx.z;
  src += (size_t)l*K*N; dst += (size_t)l*K*N;
  int tx = threadIdx.x & 31, ty = threadIdx.x >> 5;
  #pragma unroll
  for (int u=0;u<4;++u) tile[ty+8*u][tx] = src[(size_t)(k0+ty+8*u)*N + n0+tx];
  __syncthreads();
  #pragma unroll
  for (int u=0;u<4;++u) dst[(size_t)(n0+ty+8*u)*K + k0+tx] = f2b(tile[tx][ty+8*u]);
}

// ---------------- bf16 MFMA GEMM, BN_ in {128,64}, BM=128, BK=32 ----------------
// BN_=128: 4 waves as 2x2 of 64x64.  BN_=64: 4 waves stacked, each 32x64.
template<int BN_, int RELU, int RES, int OUTBF>
__global__ __launch_bounds__(256) void mgemm(
    const ushort* __restrict__ A, const ushort* __restrict__ Bt,
    const float* __restrict__ bias, const float* __restrict__ res,
    void* __restrict__ Cout, int M, int N, int K)
{
  constexpr int MI = (BN_ == 128) ? 4 : 2;
  __shared__ ushort As[128*32];
  __shared__ ushort Bs[BN_*32];
  int t = threadIdx.x;
  int lane = t & 63, w = t >> 6;
  int wm = (BN_ == 128) ? (w >> 1) * 64 : w * 32;
  int wn = (BN_ == 128) ? (w & 1) * 64 : 0;
  int m0 = blockIdx.y * 128, n0 = blockIdx.x * BN_;

  f32x4 acc[MI][4] = {};

  // staging source: thread t covers 16B at (row=t>>2, col8=(t&3)*8);
  // LDS dest = base + t*16B (contiguous in t -> matches global_load_lds semantics)
  const ushort* Ag = A  + (size_t)(m0 + (t >> 2))*K + (t & 3)*8;
  const ushort* Bg = Bt + (size_t)(n0 + (t >> 2))*K + (t & 3)*8;
  ushort* Asl = As + t*8;
  ushort* Bsl = Bs + t*8;

  int fr = lane & 15, fq = lane >> 4;
  const ushort* Ard = As + (wm + fr)*32 + fq*8;
  const ushort* Brd = Bs + (wn + fr)*32 + fq*8;

  for (int k0 = 0; k0 < K; k0 += 32) {
    __syncthreads();                       // prev iter's ds_reads done
    gld16(Ag,          Asl);
    gld16(Ag + 64*K,   Asl + 64*32);
    gld16(Bg,          Bsl);
    if (BN_ == 128) gld16(Bg + 64*K, Bsl + 64*32);
    Ag += 32; Bg += 32;
    __syncthreads();                       // drains vmcnt -> LDS valid
    bf16x8 af[MI], bfr[4];
    #pragma unroll
    for (int i=0;i<MI;++i) af[i]  = *(const bf16x8*)(Ard + i*16*32);
    #pragma unroll
    for (int j=0;j<4;++j)  bfr[j] = *(const bf16x8*)(Brd + j*16*32);
    #pragma unroll
    for (int i=0;i<MI;++i)
      #pragma unroll
      for (int j=0;j<4;++j)
        acc[i][j] = __builtin_amdgcn_mfma_f32_16x16x32_bf16(af[i], bfr[j], acc[i][j], 0, 0, 0);
  }

  int ncol = lane & 15;
  int rquad = (lane >> 4) * 4;
  #pragma unroll
  for (int j=0;j<4;++j) {
    int n = n0 + wn + j*16 + ncol;
    float bv = bias[n];
    #pragma unroll
    for (int i=0;i<MI;++i) {
      int mbase = m0 + wm + i*16 + rquad;
      #pragma unroll
      for (int r=0;r<4;++r) {
        int m = mbase + r;
        float c = acc[i][j][r] + bv;
        if (RES) c += res[(size_t)m*N + n];
        if (RELU) c = fmaxf(c, 0.f);
        if (OUTBF) ((ushort*)Cout)[(size_t)m*N + n] = f2b(c);
        else       ((float*)Cout)[(size_t)m*N + n] = c;
      }
    }
  }
}

// ---------------- QKV GEMM: bf16 out to q/k head-major + v transposed ----------------
__global__ __launch_bounds__(256) void mgemm_qkv(
    const ushort* __restrict__ A,    // M x 512 bf16 (x)
    const ushort* __restrict__ Bt,   // 1536 x 512 bf16
    const float* __restrict__ bias,  // 1536
    ushort* __restrict__ qb,         // [b,h,l,64]
    ushort* __restrict__ kb,         // [b,h,l,64]
    ushort* __restrict__ vtb)        // [b,h,64,l]
{
  const int K = D_;
  __shared__ ushort As[128*32];
  __shared__ ushort Bs[128*32];
  int t = threadIdx.x;
  int lane = t & 63, w = t >> 6;
  int wm = (w >> 1) * 64, wn = (w & 1) * 64;
  int m0 = blockIdx.y * 128, n0 = blockIdx.x * 128;

  f32x4 acc[4][4] = {};

  const ushort* Ag = A  + (size_t)(m0 + (t >> 2))*K + (t & 3)*8;
  const ushort* Bg = Bt + (size_t)(n0 + (t >> 2))*K + (t & 3)*8;
  ushort* Asl = As + t*8;
  ushort* Bsl = Bs + t*8;

  int fr = lane & 15, fq = lane >> 4;
  const ushort* Ard = As + (wm + fr)*32 + fq*8;
  const ushort* Brd = Bs + (wn + fr)*32 + fq*8;

  for (int k0 = 0; k0 < K; k0 += 32) {
    __syncthreads();
    gld16(Ag,        Asl);
    gld16(Ag + 64*K, Asl + 64*32);
    gld16(Bg,        Bsl);
    gld16(Bg + 64*K, Bsl + 64*32);
    Ag += 32; Bg += 32;
    __syncthreads();
    bf16x8 af[4], bfr[4];
    #pragma unroll
    for (int i=0;i<4;++i) af[i]  = *(const bf16x8*)(Ard + i*16*32);
    #pragma unroll
    for (int j=0;j<4;++j) bfr[j] = *(const bf16x8*)(Brd + j*16*32);
    #pragma unroll
    for (int i=0;i<4;++i)
      #pragma unroll
      for (int j=0;j<4;++j)
        acc[i][j] = __builtin_amdgcn_mfma_f32_16x16x32_bf16(af[i], bfr[j], acc[i][j], 0, 0, 0);
  }

  int ncol = lane & 15;
  int rquad = (lane >> 4) * 4;
  #pragma unroll
  for (int j=0;j<4;++j) {
    int n = n0 + wn + j*16 + ncol;
    float bv = bias[n];
    int part = n >> 9;            // 0=q 1=k 2=v (block-uniform: 128 | 512)
    int wi = n & 511;
    int h = wi >> 6, d = wi & 63;
    #pragma unroll
    for (int i=0;i<4;++i) {
      int mbase = m0 + wm + i*16 + rquad;
      #pragma unroll
      for (int r=0;r<4;++r) {
        int m = mbase + r;
        int b = m >> 11, l = m & 2047;
        int bh = b*H_ + h;
        ushort c = f2b(acc[i][j][r] + bv);
        if (part == 0)      qb[((size_t)bh*L_ + l)*DH_ + d] = c;
        else if (part == 1) kb[((size_t)bh*L_ + l)*DH_ + d] = c;
        else                vtb[((size_t)bh*DH_ + d)*L_ + l] = c;
      }
    }
  }
}

// ---------------- MFMA flash attention ----------------
__global__ __launch_bounds__(256) void attn_mfma(
    const ushort* __restrict__ qb, const ushort* __restrict__ kb,
    const ushort* __restrict__ vtb, ushort* __restrict__ outa)
{
  __shared__ ushort Qs[64*72];
  __shared__ ushort Ks[64*72];
  __shared__ ushort Vts[64*72];
  __shared__ ushort Ps[4*16*72];
  __shared__ float dls[64];

  const float scale = 0.125f;
  int t = threadIdx.x;
  int lane = t & 63, w = t >> 6;
  int qt = blockIdx.x & 31;
  int h  = (blockIdx.x >> 5) & 7;
  int b  = blockIdx.x >> 8;
  int l0 = qt * 64;
  bool isgen = (l0 >= P_);
  int bh = b*H_ + h;

  const ushort* qg  = qb  + ((size_t)bh*L_ + l0)*DH_;
  const ushort* kgb = kb  + (size_t)bh*L_*DH_;
  const ushort* vtg = vtb + (size_t)bh*DH_*L_;

  int sr = t >> 3, sc = (t & 7) * 8;

  {
    uint4 x0 = *(const uint4*)(qg + (size_t)sr*DH_ + sc);
    uint4 x1 = *(const uint4*)(qg + (size_t)(sr+32)*DH_ + sc);
    *(uint4*)(Qs + sr*72 + sc) = x0;
    *(uint4*)(Qs + (sr+32)*72 + sc) = x1;
  }
  __syncthreads();

  int fr = lane & 15, fq = lane >> 4;
  bf16x8 qf[2];
  qf[0] = *(const bf16x8*)(Qs + (16*w + fr)*72 + 0*32 + fq*8);
  qf[1] = *(const bf16x8*)(Qs + (16*w + fr)*72 + 1*32 + fq*8);

  float m[4], den[4];
  f32x4 o[4] = {};
  #pragma unroll
  for (int r=0;r<4;++r) { m[r] = -1e30f; den[r] = 0.f; }

  ushort* Pw = Ps + w*16*72;

  for (int kt = 0; kt < 16; ++kt) {
    int p0 = kt * 64;
    __syncthreads();
    {
      uint4 k0v = *(const uint4*)(kgb + (size_t)(p0+sr)*DH_ + sc);
      uint4 k1v = *(const uint4*)(kgb + (size_t)(p0+sr+32)*DH_ + sc);
      uint4 v0v = *(const uint4*)(vtg + (size_t)sr*L_ + p0 + sc);
      uint4 v1v = *(const uint4*)(vtg + (size_t)(sr+32)*L_ + p0 + sc);
      *(uint4*)(Ks + sr*72 + sc) = k0v;
      *(uint4*)(Ks + (sr+32)*72 + sc) = k1v;
      *(uint4*)(Vts + sr*72 + sc) = v0v;
      *(uint4*)(Vts + (sr+32)*72 + sc) = v1v;
    }
    __syncthreads();

    f32x4 sc4[4] = {};
    #pragma unroll
    for (int s=0;s<2;++s) {
      #pragma unroll
      for (int j=0;j<4;++j) {
        bf16x8 kf = *(const bf16x8*)(Ks + (j*16 + fr)*72 + s*32 + fq*8);
        sc4[j] = __builtin_amdgcn_mfma_f32_16x16x32_bf16(qf[s], kf, sc4[j], 0, 0, 0);
      }
    }

    float p[4][4];
    #pragma unroll
    for (int r=0;r<4;++r) {
      float s0 = sc4[0][r]*scale, s1 = sc4[1][r]*scale,
            s2 = sc4[2][r]*scale, s3 = sc4[3][r]*scale;
      float rm = fmaxf(fmaxf(s0,s1), fmaxf(s2,s3));
      rm = fmaxf(rm, __shfl_xor(rm, 1, 16));
      rm = fmaxf(rm, __shfl_xor(rm, 2, 16));
      rm = fmaxf(rm, __shfl_xor(rm, 4, 16));
      rm = fmaxf(rm, __shfl_xor(rm, 8, 16));
      float mn = fmaxf(m[r], rm);
      float alpha = __expf(m[r] - mn);
      float e0 = __expf(s0-mn), e1 = __expf(s1-mn), e2 = __expf(s2-mn), e3 = __expf(s3-mn);
      float ts = e0+e1+e2+e3;
      ts += __shfl_xor(ts, 1, 16);
      ts += __shfl_xor(ts, 2, 16);
      ts += __shfl_xor(ts, 4, 16);
      ts += __shfl_xor(ts, 8, 16);
      den[r] = den[r]*alpha + ts;
      m[r] = mn;
      p[0][r]=e0; p[1][r]=e1; p[2][r]=e2; p[3][r]=e3;
      #pragma unroll
      for (int j=0;j<4;++j) o[j][r] *= alpha;
    }

    #pragma unroll
    for (int r=0;r<4;++r)
      #pragma unroll
      for (int j=0;j<4;++j)
        Pw[(fq*4+r)*72 + j*16 + fr] = f2b(p[j][r]);
    asm volatile("s_waitcnt lgkmcnt(0)" ::: "memory");

    #pragma unroll
    for (int s=0;s<2;++s) {
      bf16x8 pf = *(const bf16x8*)(Pw + fr*72 + s*32 + fq*8);
      #pragma unroll
      for (int j=0;j<4;++j) {
        bf16x8 vf = *(const bf16x8*)(Vts + (j*16 + fr)*72 + s*32 + fq*8);
        o[j] = __builtin_amdgcn_mfma_f32_16x16x32_bf16(pf, vf, o[j], 0, 0, 0);
      }
    }
  }

  if (isgen) {
    __syncthreads();
    {
      uint4 k0v = *(const uint4*)(kgb + (size_t)(l0+sr)*DH_ + sc);
      uint4 k1v = *(const uint4*)(kgb + (size_t)(l0+sr+32)*DH_ + sc);
      uint4 v0v = *(const uint4*)(vtg + (size_t)sr*L_ + l0 + sc);
      uint4 v1v = *(const uint4*)(vtg + (size_t)(sr+32)*L_ + l0 + sc);
      *(uint4*)(Ks + sr*72 + sc) = k0v;
      *(uint4*)(Ks + (sr+32)*72 + sc) = k1v;
      *(uint4*)(Vts + sr*72 + sc) = v0v;
      *(uint4*)(Vts + (sr+32)*72 + sc) = v1v;
    }
    __syncthreads();
    {
      int row = t >> 2, part = t & 3;
      float dsum = 0.f;
      #pragma unroll
      for (int u=0;u<16;++u) {
        int d = part*16 + u;
        dsum = fmaf(b2f(Qs[row*72+d]), b2f(Ks[row*72+d]), dsum);
      }
      dsum += __shfl_xor(dsum, 1, 4);
      dsum += __shfl_xor(dsum, 2, 4);
      if (part == 0) dls[row] = dsum * scale;
    }
    __syncthreads();
    #pragma unroll
    for (int r=0;r<4;++r) {
      int rr = 16*w + fq*4 + r;
      float dl = dls[rr];
      float mn = fmaxf(m[r], dl);
      float alpha = __expf(m[r] - mn);
      float ed = __expf(dl - mn);
      den[r] = den[r]*alpha + ed;
      #pragma unroll
      for (int j=0;j<4;++j) {
        float vv = b2f(Vts[(j*16 + fr)*72 + rr]);
        o[j][r] = o[j][r]*alpha + ed*vv;
      }
      m[r] = mn;
    }
  }

  #pragma unroll
  for (int r=0;r<4;++r) {
    float inv = 1.f / den[r];
    int l = l0 + 16*w + fq*4 + r;
    #pragma unroll
    for (int j=0;j<4;++j)
      outa[((size_t)b*L_ + l)*D_ + h*DH_ + j*16 + fr] = f2b(o[j][r]*inv);
  }
}

// ---------------- LayerNorm -> x fp32 + xbf bf16 ----------------
__global__ __launch_bounds__(64) void ln_kernel(const float* __restrict__ y,
    const float* __restrict__ gw, const float* __restrict__ bw,
    float* __restrict__ x, ushort* __restrict__ xb)
{
  int row = blockIdx.x, t = threadIdx.x;
  const float4* yr = (const float4*)(y + (size_t)row*D_);
  float4 v0 = yr[t], v1 = yr[t+64];
  float s = v0.x+v0.y+v0.z+v0.w + v1.x+v1.y+v1.z+v1.w;
  for (int off=32; off>0; off>>=1) s += __shfl_down(s, off, 64);
  s = __shfl(s, 0, 64);
  float mu = s * (1.f/D_);
  float dx;
  float q = 0.f;
  dx=v0.x-mu; q+=dx*dx; dx=v0.y-mu; q+=dx*dx; dx=v0.z-mu; q+=dx*dx; dx=v0.w-mu; q+=dx*dx;
  dx=v1.x-mu; q+=dx*dx; dx=v1.y-mu; q+=dx*dx; dx=v1.z-mu; q+=dx*dx; dx=v1.w-mu; q+=dx*dx;
  for (int off=32; off>0; off>>=1) q += __shfl_down(q, off, 64);
  q = __shfl(q, 0, 64);
  float rinv = rsqrtf(q*(1.f/D_) + LN_EPS_);
  const float4* g4 = (const float4*)gw;
  const float4* b4 = (const float4*)bw;
  float4 gv0=g4[t], gv1=g4[t+64], bv0=b4[t], bv1=b4[t+64];
  float4 o0, o1;
  o0.x=(v0.x-mu)*rinv*gv0.x+bv0.x; o0.y=(v0.y-mu)*rinv*gv0.y+bv0.y;
  o0.z=(v0.z-mu)*rinv*gv0.z+bv0.z; o0.w=(v0.w-mu)*rinv*gv0.w+bv0.w;
  o1.x=(v1.x-mu)*rinv*gv1.x+bv1.x; o1.y=(v1.y-mu)*rinv*gv1.y+bv1.y;
  o1.z=(v1.z-mu)*rinv*gv1.z+bv1.z; o1.w=(v1.w-mu)*rinv*gv1.w+bv1.w;
  float4* xr = (float4*)(x + (size_t)row*D_);
  xr[t]=o0; xr[t+64]=o1;
  ushort4 h0, h1;
  h0.x=f2b(o0.x); h0.y=f2b(o0.y); h0.z=f2b(o0.z); h0.w=f2b(o0.w);
  h1.x=f2b(o1.x); h1.y=f2b(o1.y); h1.z=f2b(o1.z); h1.w=f2b(o1.w);
  ushort4* xbr = (ushort4*)(xb + (size_t)row*D_);
  xbr[t]=h0; xbr[t+64]=h1;
}

extern "C" void kernel_launch(void* const* d_in, const int* in_sizes, int n_in,
                              void* d_out, int out_size, void* d_ws, size_t ws_size,
                              hipStream_t stream) {
  const float* pcpt = (const float*)d_in[0];
  const float* gen  = (const float*)d_in[1];
  const float* Wqkv = (const float*)d_in[3];
  const float* bqkv = (const float*)d_in[4];
  const float* Wo   = (const float*)d_in[5];
  const float* bo   = (const float*)d_in[6];
  const float* W1   = (const float*)d_in[7];
  const float* b1   = (const float*)d_in[8];
  const float* W2   = (const float*)d_in[9];
  const float* b2   = (const float*)d_in[10];
  const float* g1   = (const float*)d_in[11];
  const float* be1  = (const float*)d_in[12];
  const float* g2   = (const float*)d_in[13];
  const float* be2  = (const float*)d_in[14];
  float* out = (float*)d_out;

  const size_t XD  = (size_t)B_*L_*D_;        // 4,194,304
  const size_t HKV = (size_t)B_*H_*L_*DH_;    // 4,194,304
  const size_t HFF = (size_t)B_*L_*FF_;       // 16,777,216

  float*  xbuf = (float*)d_ws;
  ushort* xbf  = (ushort*)(xbuf + XD);
  ushort* region = xbf + XD;
  ushort* qb  = region;                        // aliased with hbf
  ushort* kb  = region + HKV;
  ushort* vtb = region + 2*HKV;
  ushort* hbf = region;
  ushort* abf = region + HFF;
  ushort* wb  = abf + XD;
  ushort* wqkv_b = wb;
  ushort* wo_b   = wqkv_b + (size_t)4*3*D_*D_;
  ushort* w1_b   = wo_b   + (size_t)4*D_*D_;
  ushort* w2_b   = w1_b   + (size_t)4*FF_*D_;
  float*  ybuf = out;

  const int M = B_*L_;

  wconv_kernel<<<dim3(3*D_/32, D_/32, 4), 256, 0, stream>>>(Wqkv, wqkv_b, D_, 3*D_);
  wconv_kernel<<<dim3(D_/32,   D_/32, 4), 256, 0, stream>>>(Wo,   wo_b,   D_, D_);
  wconv_kernel<<<dim3(FF_/32,  D_/32, 4), 256, 0, stream>>>(W1,   w1_b,   D_, FF_);
  wconv_kernel<<<dim3(D_/32,  FF_/32, 4), 256, 0, stream>>>(W2,   w2_b,   FF_, D_);

  concat_kernel<<<4096, 256, 0, stream>>>(pcpt, gen, xbuf, xbf);

  for (int i = 0; i < LAYERS_; ++i) {
    const ushort* wqkv_i = wqkv_b + (size_t)i*3*D_*D_;
    const ushort* wo_i   = wo_b   + (size_t)i*D_*D_;
    const ushort* w1_i   = w1_b   + (size_t)i*FF_*D_;
    const ushort* w2_i   = w2_b   + (size_t)i*D_*FF_;
    const float* bqkv_i = bqkv + (size_t)i*3*D_;
    const float* bo_i   = bo   + (size_t)i*D_;
    const float* b1_i   = b1   + (size_t)i*FF_;
    const float* b2_i   = b2   + (size_t)i*D_;
    const float* g1_i   = g1   + (size_t)i*D_;
    const float* be1_i  = be1  + (size_t)i*D_;
    const float* g2_i   = g2   + (size_t)i*D_;
    const float* be2_i  = be2  + (size_t)i*D_;

    // qkv = x @ Wqkv + bqkv -> bf16 q/k head-major, v transposed
    mgemm_qkv<<<dim3(3*D_/128, M/128), 256, 0, stream>>>(
        xbf, wqkv_i, bqkv_i, qb, kb, vtb);

    // attention (MFMA flash) -> bf16
    attn_mfma<<<B_*H_*(L_/64), 256, 0, stream>>>(qb, kb, vtb, abf);

    // y = a @ Wo + bo + x -> fp32  (BN=64: 512 blocks = 2/CU)
    mgemm<64,0,1,0><<<dim3(D_/64, M/128), 256, 0, stream>>>(
        abf, wo_i, bo_i, xbuf, ybuf, M, D_, D_);

    ln_kernel<<<M, 64, 0, stream>>>(ybuf, g1_i, be1_i, xbuf, xbf);

    // h = relu(x @ W1 + b1) -> bf16  (BN=128: 1024 blocks)
    mgemm<128,1,0,1><<<dim3(FF_/128, M/128), 256, 0, stream>>>(
        xbf, w1_i, b1_i, nullptr, hbf, M, FF_, D_);

    // y = h @ W2 + b2 + x -> fp32  (BN=64)
    mgemm<64,0,1,0><<<dim3(D_/64, M/128), 256, 0, stream>>>(
        hbf, w2_i, b2_i, xbuf, ybuf, M, D_, FF_);

    ln_kernel<<<M, 64, 0, stream>>>(ybuf, g2_i, be2_i, xbuf, xbf);
  }

  writeout_kernel<<<4096, 256, 0, stream>>>(xbuf, out);
}

// Round 6
// 861.111 us; speedup vs baseline: 21.4298x; 1.1056x over previous
//
#include <hip/hip_runtime.h>
#include <hip/hip_bf16.h>

#define B_ 4
#define P_ 1024
#define G_ 1024
#define L_ 2048
#define D_ 512
#define FF_ 2048
#define H_ 8
#define DH_ 64
#define LAYERS_ 4
#define LN_EPS_ 1e-5f

typedef __attribute__((ext_vector_type(8))) short bf16x8;
typedef __attribute__((ext_vector_type(4))) float f32x4;

__device__ __forceinline__ ushort f2b(float f) {
  unsigned u = __float_as_uint(f);
  unsigned r = (u + 0x7fffu + ((u >> 16) & 1u)) >> 16;
  return (ushort)r;
}
__device__ __forceinline__ float b2f(ushort u) {
  return __uint_as_float(((unsigned)u) << 16);
}

// async 16B global->LDS (DMA; dest = wave-uniform base + lane*16)
__device__ __forceinline__ void gld16(const ushort* g, ushort* l) {
  __builtin_amdgcn_global_load_lds(
      (const __attribute__((address_space(1))) void*)g,
      (__attribute__((address_space(3))) void*)l, 16, 0, 0);
}

// ---------------- concat pcpt+gen -> x (fp32) + xbf (bf16) ----------------
__global__ __launch_bounds__(256) void concat_kernel(const float* __restrict__ p,
    const float* __restrict__ g, float* __restrict__ x, ushort* __restrict__ xb)
{
  const int LD4 = L_*D_/4, PD4 = P_*D_/4;
  int i = blockIdx.x*256 + threadIdx.x;
  int b = i / LD4, r = i - b*LD4;
  float4 v;
  if (r < PD4) v = ((const float4*)p)[(size_t)b*PD4 + r];
  else         v = ((const float4*)g)[(size_t)b*PD4 + (r-PD4)];
  ((float4*)x)[i] = v;
  ushort4 h; h.x=f2b(v.x); h.y=f2b(v.y); h.z=f2b(v.z); h.w=f2b(v.w);
  ((ushort4*)xb)[i] = h;
}

// ---------------- writeout ----------------
__global__ __launch_bounds__(256) void writeout_kernel(const float* __restrict__ x,
    float* __restrict__ out)
{
  const int LD4 = L_*D_/4, PD4 = P_*D_/4, HALF = B_*PD4;
  int i = blockIdx.x*256 + threadIdx.x;
  int half = (i >= HALF) ? 1 : 0;
  int r = i - half*HALF;
  int b = r / PD4, q = r - b*PD4;
  ((float4*)out)[i] = ((const float4*)x)[(size_t)b*LD4 + half*PD4 + q];
}

// ---------------- weight transpose+convert: src K x N fp32 -> dst N x K bf16 ----------------
__global__ __launch_bounds__(256) void wconv_kernel(const float* __restrict__ src,
    ushort* __restrict__ dst, int K, int N)
{
  __shared__ float tile[32][33];
  int n0 = blockIdx.x*32, k0 = blockIdx.y*32, l = blockIdx.z;
  src += (size_t)l*K*N; dst += (size_t)l*K*N;
  int tx = threadIdx.x & 31, ty = threadIdx.x >> 5;
  #pragma unroll
  for (int u=0;u<4;++u) tile[ty+8*u][tx] = src[(size_t)(k0+ty+8*u)*N + n0+tx];
  __syncthreads();
  #pragma unroll
  for (int u=0;u<4;++u) dst[(size_t)(n0+ty+8*u)*K + k0+tx] = f2b(tile[tx][ty+8*u]);
}

// ---------------- bf16 MFMA GEMM, BN_ in {128,64}, BM=128, BK=32 ----------------
template<int BN_, int RELU, int RES, int OUTBF>
__global__ __launch_bounds__(256) void mgemm(
    const ushort* __restrict__ A, const ushort* __restrict__ Bt,
    const float* __restrict__ bias, const float* __restrict__ res,
    void* __restrict__ Cout, int M, int N, int K)
{
  constexpr int MI = (BN_ == 128) ? 4 : 2;
  __shared__ ushort As[128*32];
  __shared__ ushort Bs[BN_*32];
  int t = threadIdx.x;
  int lane = t & 63, w = t >> 6;
  int wm = (BN_ == 128) ? (w >> 1) * 64 : w * 32;
  int wn = (BN_ == 128) ? (w & 1) * 64 : 0;
  int m0 = blockIdx.y * 128, n0 = blockIdx.x * BN_;

  f32x4 acc[MI][4] = {};

  const ushort* Ag = A  + (size_t)(m0 + (t >> 2))*K + (t & 3)*8;
  const ushort* Bg = Bt + (size_t)(n0 + (t >> 2))*K + (t & 3)*8;
  ushort* Asl = As + t*8;
  ushort* Bsl = Bs + t*8;

  int fr = lane & 15, fq = lane >> 4;
  const ushort* Ard = As + (wm + fr)*32 + fq*8;
  const ushort* Brd = Bs + (wn + fr)*32 + fq*8;

  for (int k0 = 0; k0 < K; k0 += 32) {
    __syncthreads();
    gld16(Ag,          Asl);
    gld16(Ag + 64*K,   Asl + 64*32);
    gld16(Bg,          Bsl);
    if (BN_ == 128) gld16(Bg + 64*K, Bsl + 64*32);
    Ag += 32; Bg += 32;
    __syncthreads();
    bf16x8 af[MI], bfr[4];
    #pragma unroll
    for (int i=0;i<MI;++i) af[i]  = *(const bf16x8*)(Ard + i*16*32);
    #pragma unroll
    for (int j=0;j<4;++j)  bfr[j] = *(const bf16x8*)(Brd + j*16*32);
    #pragma unroll
    for (int i=0;i<MI;++i)
      #pragma unroll
      for (int j=0;j<4;++j)
        acc[i][j] = __builtin_amdgcn_mfma_f32_16x16x32_bf16(af[i], bfr[j], acc[i][j], 0, 0, 0);
  }

  int ncol = lane & 15;
  int rquad = (lane >> 4) * 4;
  #pragma unroll
  for (int j=0;j<4;++j) {
    int n = n0 + wn + j*16 + ncol;
    float bv = bias[n];
    #pragma unroll
    for (int i=0;i<MI;++i) {
      int mbase = m0 + wm + i*16 + rquad;
      #pragma unroll
      for (int r=0;r<4;++r) {
        int m = mbase + r;
        float c = acc[i][j][r] + bv;
        if (RES) c += res[(size_t)m*N + n];
        if (RELU) c = fmaxf(c, 0.f);
        if (OUTBF) ((ushort*)Cout)[(size_t)m*N + n] = f2b(c);
        else       ((float*)Cout)[(size_t)m*N + n] = c;
      }
    }
  }
}

// ---------------- QKV GEMM: bf16 out; q pre-scaled by 1/8; v transposed ----------------
__global__ __launch_bounds__(256) void mgemm_qkv(
    const ushort* __restrict__ A,    // M x 512 bf16 (x)
    const ushort* __restrict__ Bt,   // 1536 x 512 bf16
    const float* __restrict__ bias,  // 1536
    ushort* __restrict__ qb,         // [b,h,l,64]  (pre-scaled by 0.125)
    ushort* __restrict__ kb,         // [b,h,l,64]
    ushort* __restrict__ vtb)        // [b,h,64,l]
{
  const int K = D_;
  __shared__ ushort As[128*32];
  __shared__ ushort Bs[128*32];
  int t = threadIdx.x;
  int lane = t & 63, w = t >> 6;
  int wm = (w >> 1) * 64, wn = (w & 1) * 64;
  int m0 = blockIdx.y * 128, n0 = blockIdx.x * 128;

  f32x4 acc[4][4] = {};

  const ushort* Ag = A  + (size_t)(m0 + (t >> 2))*K + (t & 3)*8;
  const ushort* Bg = Bt + (size_t)(n0 + (t >> 2))*K + (t & 3)*8;
  ushort* Asl = As + t*8;
  ushort* Bsl = Bs + t*8;

  int fr = lane & 15, fq = lane >> 4;
  const ushort* Ard = As + (wm + fr)*32 + fq*8;
  const ushort* Brd = Bs + (wn + fr)*32 + fq*8;

  for (int k0 = 0; k0 < K; k0 += 32) {
    __syncthreads();
    gld16(Ag,        Asl);
    gld16(Ag + 64*K, Asl + 64*32);
    gld16(Bg,        Bsl);
    gld16(Bg + 64*K, Bsl + 64*32);
    Ag += 32; Bg += 32;
    __syncthreads();
    bf16x8 af[4], bfr[4];
    #pragma unroll
    for (int i=0;i<4;++i) af[i]  = *(const bf16x8*)(Ard + i*16*32);
    #pragma unroll
    for (int j=0;j<4;++j) bfr[j] = *(const bf16x8*)(Brd + j*16*32);
    #pragma unroll
    for (int i=0;i<4;++i)
      #pragma unroll
      for (int j=0;j<4;++j)
        acc[i][j] = __builtin_amdgcn_mfma_f32_16x16x32_bf16(af[i], bfr[j], acc[i][j], 0, 0, 0);
  }

  int ncol = lane & 15;
  int rquad = (lane >> 4) * 4;
  #pragma unroll
  for (int j=0;j<4;++j) {
    int n = n0 + wn + j*16 + ncol;
    float bv = bias[n];
    int part = n >> 9;            // 0=q 1=k 2=v (block-uniform: 128 | 512)
    int wi = n & 511;
    int h = wi >> 6, d = wi & 63;
    #pragma unroll
    for (int i=0;i<4;++i) {
      int mbase = m0 + wm + i*16 + rquad;
      #pragma unroll
      for (int r=0;r<4;++r) {
        int m = mbase + r;
        int b = m >> 11, l = m & 2047;
        int bh = b*H_ + h;
        float cv = acc[i][j][r] + bv;
        if (part == 0) cv *= 0.125f;       // fold 1/sqrt(dh) into q
        ushort c = f2b(cv);
        if (part == 0)      qb[((size_t)bh*L_ + l)*DH_ + d] = c;
        else if (part == 1) kb[((size_t)bh*L_ + l)*DH_ + d] = c;
        else                vtb[((size_t)bh*DH_ + d)*L_ + l] = c;
      }
    }
  }
}

// ---------------- MFMA flash attention, one-pass softmax ----------------
__global__ __launch_bounds__(256) void attn_mfma(
    const ushort* __restrict__ qb, const ushort* __restrict__ kb,
    const ushort* __restrict__ vtb, ushort* __restrict__ outa)
{
  __shared__ ushort Qs[64*72];
  __shared__ ushort Ks[64*72];
  __shared__ ushort Vts[64*72];
  __shared__ ushort Ps[4*16*72];
  __shared__ float dls[64];

  int t = threadIdx.x;
  int lane = t & 63, w = t >> 6;
  int qt = blockIdx.x & 31;
  int h  = (blockIdx.x >> 5) & 7;
  int b  = blockIdx.x >> 8;
  int l0 = qt * 64;
  bool isgen = (l0 >= P_);
  int bh = b*H_ + h;

  const ushort* qg  = qb  + ((size_t)bh*L_ + l0)*DH_;
  const ushort* kgb = kb  + (size_t)bh*L_*DH_;
  const ushort* vtg = vtb + (size_t)bh*DH_*L_;

  int sr = t >> 3, sc = (t & 7) * 8;

  {
    uint4 x0 = *(const uint4*)(qg + (size_t)sr*DH_ + sc);
    uint4 x1 = *(const uint4*)(qg + (size_t)(sr+32)*DH_ + sc);
    *(uint4*)(Qs + sr*72 + sc) = x0;
    *(uint4*)(Qs + (sr+32)*72 + sc) = x1;
  }
  __syncthreads();

  int fr = lane & 15, fq = lane >> 4;
  bf16x8 qf[2];
  qf[0] = *(const bf16x8*)(Qs + (16*w + fr)*72 + 0*32 + fq*8);
  qf[1] = *(const bf16x8*)(Qs + (16*w + fr)*72 + 1*32 + fq*8);

  float den[4] = {0.f, 0.f, 0.f, 0.f};
  f32x4 o[4] = {};

  ushort* Pw = Ps + w*16*72;

  // register prefetch of K/V tile kt=0
  uint4 pk0 = *(const uint4*)(kgb + (size_t)sr*DH_ + sc);
  uint4 pk1 = *(const uint4*)(kgb + (size_t)(sr+32)*DH_ + sc);
  uint4 pv0 = *(const uint4*)(vtg + (size_t)sr*L_ + sc);
  uint4 pv1 = *(const uint4*)(vtg + (size_t)(sr+32)*L_ + sc);

  for (int kt = 0; kt < 16; ++kt) {
    __syncthreads();
    *(uint4*)(Ks + sr*72 + sc) = pk0;
    *(uint4*)(Ks + (sr+32)*72 + sc) = pk1;
    *(uint4*)(Vts + sr*72 + sc) = pv0;
    *(uint4*)(Vts + (sr+32)*72 + sc) = pv1;
    __syncthreads();

    if (kt < 15) {   // prefetch next tile; latency hides under compute below
      int p1 = (kt + 1) * 64;
      pk0 = *(const uint4*)(kgb + (size_t)(p1+sr)*DH_ + sc);
      pk1 = *(const uint4*)(kgb + (size_t)(p1+sr+32)*DH_ + sc);
      pv0 = *(const uint4*)(vtg + (size_t)sr*L_ + p1 + sc);
      pv1 = *(const uint4*)(vtg + (size_t)(sr+32)*L_ + p1 + sc);
    }

    // ---- S = Qs K^T (q pre-scaled) ----
    f32x4 sc4[4] = {};
    #pragma unroll
    for (int s=0;s<2;++s) {
      #pragma unroll
      for (int j=0;j<4;++j) {
        bf16x8 kf = *(const bf16x8*)(Ks + (j*16 + fr)*72 + s*32 + fq*8);
        sc4[j] = __builtin_amdgcn_mfma_f32_16x16x32_bf16(qf[s], kf, sc4[j], 0, 0, 0);
      }
    }

    // ---- one-pass softmax: e = exp(s), den accumulates lane-locally ----
    #pragma unroll
    for (int r=0;r<4;++r) {
      float e0 = __expf(sc4[0][r]);
      float e1 = __expf(sc4[1][r]);
      float e2 = __expf(sc4[2][r]);
      float e3 = __expf(sc4[3][r]);
      den[r] += (e0+e1) + (e2+e3);
      // RTZ bf16 pack (e >= 0)
      Pw[(fq*4+r)*72 +  0 + fr] = (ushort)(__float_as_uint(e0) >> 16);
      Pw[(fq*4+r)*72 + 16 + fr] = (ushort)(__float_as_uint(e1) >> 16);
      Pw[(fq*4+r)*72 + 32 + fr] = (ushort)(__float_as_uint(e2) >> 16);
      Pw[(fq*4+r)*72 + 48 + fr] = (ushort)(__float_as_uint(e3) >> 16);
    }
    asm volatile("s_waitcnt lgkmcnt(0)" ::: "memory");

    // ---- O += P V ----
    #pragma unroll
    for (int s=0;s<2;++s) {
      bf16x8 pf = *(const bf16x8*)(Pw + fr*72 + s*32 + fq*8);
      #pragma unroll
      for (int j=0;j<4;++j) {
        bf16x8 vf = *(const bf16x8*)(Vts + (j*16 + fr)*72 + s*32 + fq*8);
        o[j] = __builtin_amdgcn_mfma_f32_16x16x32_bf16(pf, vf, o[j], 0, 0, 0);
      }
    }
  }

  // ---- cross-lane den reduction (cols live across fr lanes, width 16) ----
  #pragma unroll
  for (int r=0;r<4;++r) {
    float d = den[r];
    d += __shfl_xor(d, 1, 16);
    d += __shfl_xor(d, 2, 16);
    d += __shfl_xor(d, 4, 16);
    d += __shfl_xor(d, 8, 16);
    den[r] = d;
  }

  // ---- diagonal self-term for gen tiles ----
  if (isgen) {
    __syncthreads();
    {
      uint4 k0v = *(const uint4*)(kgb + (size_t)(l0+sr)*DH_ + sc);
      uint4 k1v = *(const uint4*)(kgb + (size_t)(l0+sr+32)*DH_ + sc);
      uint4 v0v = *(const uint4*)(vtg + (size_t)sr*L_ + l0 + sc);
      uint4 v1v = *(const uint4*)(vtg + (size_t)(sr+32)*L_ + l0 + sc);
      *(uint4*)(Ks + sr*72 + sc) = k0v;
      *(uint4*)(Ks + (sr+32)*72 + sc) = k1v;
      *(uint4*)(Vts + sr*72 + sc) = v0v;
      *(uint4*)(Vts + (sr+32)*72 + sc) = v1v;
    }
    __syncthreads();
    {
      int row = t >> 2, part = t & 3;
      float dsum = 0.f;
      #pragma unroll
      for (int u=0;u<16;++u) {
        int d = part*16 + u;
        dsum = fmaf(b2f(Qs[row*72+d]), b2f(Ks[row*72+d]), dsum);  // q pre-scaled
      }
      dsum += __shfl_xor(dsum, 1, 4);
      dsum += __shfl_xor(dsum, 2, 4);
      if (part == 0) dls[row] = dsum;
    }
    __syncthreads();
    #pragma unroll
    for (int r=0;r<4;++r) {
      int rr = 16*w + fq*4 + r;
      float ed = __expf(dls[rr]);
      den[r] += ed;
      #pragma unroll
      for (int j=0;j<4;++j) {
        float vv = b2f(Vts[(j*16 + fr)*72 + rr]);
        o[j][r] += ed*vv;
      }
    }
  }

  // ---- epilogue: out[b, l, h*64 + d] bf16 ----
  #pragma unroll
  for (int r=0;r<4;++r) {
    float inv = 1.f / den[r];
    int l = l0 + 16*w + fq*4 + r;
    #pragma unroll
    for (int j=0;j<4;++j)
      outa[((size_t)b*L_ + l)*D_ + h*DH_ + j*16 + fr] = f2b(o[j][r]*inv);
  }
}

// ---------------- LayerNorm -> x fp32 + xbf bf16 ----------------
__global__ __launch_bounds__(64) void ln_kernel(const float* __restrict__ y,
    const float* __restrict__ gw, const float* __restrict__ bw,
    float* __restrict__ x, ushort* __restrict__ xb)
{
  int row = blockIdx.x, t = threadIdx.x;
  const float4* yr = (const float4*)(y + (size_t)row*D_);
  float4 v0 = yr[t], v1 = yr[t+64];
  float s = v0.x+v0.y+v0.z+v0.w + v1.x+v1.y+v1.z+v1.w;
  for (int off=32; off>0; off>>=1) s += __shfl_down(s, off, 64);
  s = __shfl(s, 0, 64);
  float mu = s * (1.f/D_);
  float dx;
  float q = 0.f;
  dx=v0.x-mu; q+=dx*dx; dx=v0.y-mu; q+=dx*dx; dx=v0.z-mu; q+=dx*dx; dx=v0.w-mu; q+=dx*dx;
  dx=v1.x-mu; q+=dx*dx; dx=v1.y-mu; q+=dx*dx; dx=v1.z-mu; q+=dx*dx; dx=v1.w-mu; q+=dx*dx;
  for (int off=32; off>0; off>>=1) q += __shfl_down(q, off, 64);
  q = __shfl(q, 0, 64);
  float rinv = rsqrtf(q*(1.f/D_) + LN_EPS_);
  const float4* g4 = (const float4*)gw;
  const float4* b4 = (const float4*)bw;
  float4 gv0=g4[t], gv1=g4[t+64], bv0=b4[t], bv1=b4[t+64];
  float4 o0, o1;
  o0.x=(v0.x-mu)*rinv*gv0.x+bv0.x; o0.y=(v0.y-mu)*rinv*gv0.y+bv0.y;
  o0.z=(v0.z-mu)*rinv*gv0.z+bv0.z; o0.w=(v0.w-mu)*rinv*gv0.w+bv0.w;
  o1.x=(v1.x-mu)*rinv*gv1.x+bv1.x; o1.y=(v1.y-mu)*rinv*gv1.y+bv1.y;
  o1.z=(v1.z-mu)*rinv*gv1.z+bv1.z; o1.w=(v1.w-mu)*rinv*gv1.w+bv1.w;
  float4* xr = (float4*)(x + (size_t)row*D_);
  xr[t]=o0; xr[t+64]=o1;
  ushort4 h0, h1;
  h0.x=f2b(o0.x); h0.y=f2b(o0.y); h0.z=f2b(o0.z); h0.w=f2b(o0.w);
  h1.x=f2b(o1.x); h1.y=f2b(o1.y); h1.z=f2b(o1.z); h1.w=f2b(o1.w);
  ushort4* xbr = (ushort4*)(xb + (size_t)row*D_);
  xbr[t]=h0; xbr[t+64]=h1;
}

extern "C" void kernel_launch(void* const* d_in, const int* in_sizes, int n_in,
                              void* d_out, int out_size, void* d_ws, size_t ws_size,
                              hipStream_t stream) {
  const float* pcpt = (const float*)d_in[0];
  const float* gen  = (const float*)d_in[1];
  const float* Wqkv = (const float*)d_in[3];
  const float* bqkv = (const float*)d_in[4];
  const float* Wo   = (const float*)d_in[5];
  const float* bo   = (const float*)d_in[6];
  const float* W1   = (const float*)d_in[7];
  const float* b1   = (const float*)d_in[8];
  const float* W2   = (const float*)d_in[9];
  const float* b2   = (const float*)d_in[10];
  const float* g1   = (const float*)d_in[11];
  const float* be1  = (const float*)d_in[12];
  const float* g2   = (const float*)d_in[13];
  const float* be2  = (const float*)d_in[14];
  float* out = (float*)d_out;

  const size_t XD  = (size_t)B_*L_*D_;
  const size_t HKV = (size_t)B_*H_*L_*DH_;
  const size_t HFF = (size_t)B_*L_*FF_;

  float*  xbuf = (float*)d_ws;
  ushort* xbf  = (ushort*)(xbuf + XD);
  ushort* region = xbf + XD;
  ushort* qb  = region;                        // aliased with hbf
  ushort* kb  = region + HKV;
  ushort* vtb = region + 2*HKV;
  ushort* hbf = region;
  ushort* abf = region + HFF;
  ushort* wb  = abf + XD;
  ushort* wqkv_b = wb;
  ushort* wo_b   = wqkv_b + (size_t)4*3*D_*D_;
  ushort* w1_b   = wo_b   + (size_t)4*D_*D_;
  ushort* w2_b   = w1_b   + (size_t)4*FF_*D_;
  float*  ybuf = out;

  const int M = B_*L_;

  wconv_kernel<<<dim3(3*D_/32, D_/32, 4), 256, 0, stream>>>(Wqkv, wqkv_b, D_, 3*D_);
  wconv_kernel<<<dim3(D_/32,   D_/32, 4), 256, 0, stream>>>(Wo,   wo_b,   D_, D_);
  wconv_kernel<<<dim3(FF_/32,  D_/32, 4), 256, 0, stream>>>(W1,   w1_b,   D_, FF_);
  wconv_kernel<<<dim3(D_/32,  FF_/32, 4), 256, 0, stream>>>(W2,   w2_b,   FF_, D_);

  concat_kernel<<<4096, 256, 0, stream>>>(pcpt, gen, xbuf, xbf);

  for (int i = 0; i < LAYERS_; ++i) {
    const ushort* wqkv_i = wqkv_b + (size_t)i*3*D_*D_;
    const ushort* wo_i   = wo_b   + (size_t)i*D_*D_;
    const ushort* w1_i   = w1_b   + (size_t)i*FF_*D_;
    const ushort* w2_i   = w2_b   + (size_t)i*D_*FF_;
    const float* bqkv_i = bqkv + (size_t)i*3*D_;
    const float* bo_i   = bo   + (size_t)i*D_;
    const float* b1_i   = b1   + (size_t)i*FF_;
    const float* b2_i   = b2   + (size_t)i*D_;
    const float* g1_i   = g1   + (size_t)i*D_;
    const float* be1_i  = be1  + (size_t)i*D_;
    const float* g2_i   = g2   + (size_t)i*D_;
    const float* be2_i  = be2  + (size_t)i*D_;

    mgemm_qkv<<<dim3(3*D_/128, M/128), 256, 0, stream>>>(
        xbf, wqkv_i, bqkv_i, qb, kb, vtb);

    attn_mfma<<<B_*H_*(L_/64), 256, 0, stream>>>(qb, kb, vtb, abf);

    mgemm<64,0,1,0><<<dim3(D_/64, M/128), 256, 0, stream>>>(
        abf, wo_i, bo_i, xbuf, ybuf, M, D_, D_);

    ln_kernel<<<M, 64, 0, stream>>>(ybuf, g1_i, be1_i, xbuf, xbf);

    mgemm<128,1,0,1><<<dim3(FF_/128, M/128), 256, 0, stream>>>(
        xbf, w1_i, b1_i, nullptr, hbf, M, FF_, D_);

    mgemm<64,0,1,0><<<dim3(D_/64, M/128), 256, 0, stream>>>(
        hbf, w2_i, b2_i, xbuf, ybuf, M, D_, FF_);

    ln_kernel<<<M, 64, 0, stream>>>(ybuf, g2_i, be2_i, xbuf, xbf);
  }

  writeout_kernel<<<4096, 256, 0, stream>>>(xbuf, out);
}

// Round 7
// 843.208 us; speedup vs baseline: 21.8848x; 1.0212x over previous
//
#include <hip/hip_runtime.h>
#include <hip/hip_bf16.h>

#define B_ 4
#define P_ 1024
#define G_ 1024
#define L_ 2048
#define D_ 512
#define FF_ 2048
#define H_ 8
#define DH_ 64
#define LAYERS_ 4
#define LN_EPS_ 1e-5f

typedef __attribute__((ext_vector_type(8))) short bf16x8;
typedef __attribute__((ext_vector_type(4))) float f32x4;

__device__ __forceinline__ ushort f2b(float f) {
  unsigned u = __float_as_uint(f);
  unsigned r = (u + 0x7fffu + ((u >> 16) & 1u)) >> 16;
  return (ushort)r;
}
__device__ __forceinline__ float b2f(ushort u) {
  return __uint_as_float(((unsigned)u) << 16);
}

// async 16B global->LDS (DMA; dest = wave-uniform base + lane*16)
__device__ __forceinline__ void gld16(const ushort* g, ushort* l) {
  __builtin_amdgcn_global_load_lds(
      (const __attribute__((address_space(1))) void*)g,
      (__attribute__((address_space(3))) void*)l, 16, 0, 0);
}

// ---------------- concat pcpt+gen -> x (fp32) + xbf (bf16) ----------------
__global__ __launch_bounds__(256) void concat_kernel(const float* __restrict__ p,
    const float* __restrict__ g, float* __restrict__ x, ushort* __restrict__ xb)
{
  const int LD4 = L_*D_/4, PD4 = P_*D_/4;
  int i = blockIdx.x*256 + threadIdx.x;
  int b = i / LD4, r = i - b*LD4;
  float4 v;
  if (r < PD4) v = ((const float4*)p)[(size_t)b*PD4 + r];
  else         v = ((const float4*)g)[(size_t)b*PD4 + (r-PD4)];
  ((float4*)x)[i] = v;
  ushort4 h; h.x=f2b(v.x); h.y=f2b(v.y); h.z=f2b(v.z); h.w=f2b(v.w);
  ((ushort4*)xb)[i] = h;
}

// ---------------- writeout ----------------
__global__ __launch_bounds__(256) void writeout_kernel(const float* __restrict__ x,
    float* __restrict__ out)
{
  const int LD4 = L_*D_/4, PD4 = P_*D_/4, HALF = B_*PD4;
  int i = blockIdx.x*256 + threadIdx.x;
  int half = (i >= HALF) ? 1 : 0;
  int r = i - half*HALF;
  int b = r / PD4, q = r - b*PD4;
  ((float4*)out)[i] = ((const float4*)x)[(size_t)b*LD4 + half*PD4 + q];
}

// ---------------- weight transpose+convert: src K x N fp32 -> dst N x K bf16 ----------------
__global__ __launch_bounds__(256) void wconv_kernel(const float* __restrict__ src,
    ushort* __restrict__ dst, int K, int N)
{
  __shared__ float tile[32][33];
  int n0 = blockIdx.x*32, k0 = blockIdx.y*32, l = blockIdx.z;
  src += (size_t)l*K*N; dst += (size_t)l*K*N;
  int tx = threadIdx.x & 31, ty = threadIdx.x >> 5;
  #pragma unroll
  for (int u=0;u<4;++u) tile[ty+8*u][tx] = src[(size_t)(k0+ty+8*u)*N + n0+tx];
  __syncthreads();
  #pragma unroll
  for (int u=0;u<4;++u) dst[(size_t)(n0+ty+8*u)*K + k0+tx] = f2b(tile[tx][ty+8*u]);
}

// ---------------- bf16 MFMA GEMM, BN_ in {128,64}, BM=128, BK=32 ----------------
// Grid: (m-tiles fast, n-tiles slow) -> all n-tiles of an m-band share an XCD
// (id%8 round-robin; m-tiles per n = 64, 64%8==0), so the shared A-band lives
// in that XCD's L2 once instead of being fetched 8-16x across XCDs.
template<int BN_, int RELU, int RES, int OUTBF>
__global__ __launch_bounds__(256) void mgemm(
    const ushort* __restrict__ A, const ushort* __restrict__ Bt,
    const float* __restrict__ bias, const float* __restrict__ res,
    void* __restrict__ Cout, int M, int N, int K)
{
  constexpr int MI = (BN_ == 128) ? 4 : 2;
  __shared__ ushort As[128*32];
  __shared__ ushort Bs[BN_*32];
  int t = threadIdx.x;
  int lane = t & 63, w = t >> 6;
  int wm = (BN_ == 128) ? (w >> 1) * 64 : w * 32;
  int wn = (BN_ == 128) ? (w & 1) * 64 : 0;
  int m0 = blockIdx.x * 128, n0 = blockIdx.y * BN_;

  f32x4 acc[MI][4] = {};

  const ushort* Ag = A  + (size_t)(m0 + (t >> 2))*K + (t & 3)*8;
  const ushort* Bg = Bt + (size_t)(n0 + (t >> 2))*K + (t & 3)*8;
  ushort* Asl = As + t*8;
  ushort* Bsl = Bs + t*8;

  int fr = lane & 15, fq = lane >> 4;
  const ushort* Ard = As + (wm + fr)*32 + fq*8;
  const ushort* Brd = Bs + (wn + fr)*32 + fq*8;

  for (int k0 = 0; k0 < K; k0 += 32) {
    __syncthreads();
    gld16(Ag,          Asl);
    gld16(Ag + 64*K,   Asl + 64*32);
    gld16(Bg,          Bsl);
    if (BN_ == 128) gld16(Bg + 64*K, Bsl + 64*32);
    Ag += 32; Bg += 32;
    __syncthreads();
    bf16x8 af[MI], bfr[4];
    #pragma unroll
    for (int i=0;i<MI;++i) af[i]  = *(const bf16x8*)(Ard + i*16*32);
    #pragma unroll
    for (int j=0;j<4;++j)  bfr[j] = *(const bf16x8*)(Brd + j*16*32);
    #pragma unroll
    for (int i=0;i<MI;++i)
      #pragma unroll
      for (int j=0;j<4;++j)
        acc[i][j] = __builtin_amdgcn_mfma_f32_16x16x32_bf16(af[i], bfr[j], acc[i][j], 0, 0, 0);
  }

  int ncol = lane & 15;
  int rquad = (lane >> 4) * 4;
  #pragma unroll
  for (int j=0;j<4;++j) {
    int n = n0 + wn + j*16 + ncol;
    float bv = bias[n];
    #pragma unroll
    for (int i=0;i<MI;++i) {
      int mbase = m0 + wm + i*16 + rquad;
      #pragma unroll
      for (int r=0;r<4;++r) {
        int m = mbase + r;
        float c = acc[i][j][r] + bv;
        if (RES) c += res[(size_t)m*N + n];
        if (RELU) c = fmaxf(c, 0.f);
        if (OUTBF) ((ushort*)Cout)[(size_t)m*N + n] = f2b(c);
        else       ((float*)Cout)[(size_t)m*N + n] = c;
      }
    }
  }
}

// ---------------- QKV GEMM: bf16 out; q pre-scaled by 1/8; v transposed ----------------
__global__ __launch_bounds__(256) void mgemm_qkv(
    const ushort* __restrict__ A,    // M x 512 bf16 (x)
    const ushort* __restrict__ Bt,   // 1536 x 512 bf16
    const float* __restrict__ bias,  // 1536
    ushort* __restrict__ qb,         // [b,h,l,64]  (pre-scaled by 0.125)
    ushort* __restrict__ kb,         // [b,h,l,64]
    ushort* __restrict__ vtb)        // [b,h,64,l]
{
  const int K = D_;
  __shared__ ushort As[128*32];
  __shared__ ushort Bs[128*32];
  int t = threadIdx.x;
  int lane = t & 63, w = t >> 6;
  int wm = (w >> 1) * 64, wn = (w & 1) * 64;
  int m0 = blockIdx.x * 128, n0 = blockIdx.y * 128;

  f32x4 acc[4][4] = {};

  const ushort* Ag = A  + (size_t)(m0 + (t >> 2))*K + (t & 3)*8;
  const ushort* Bg = Bt + (size_t)(n0 + (t >> 2))*K + (t & 3)*8;
  ushort* Asl = As + t*8;
  ushort* Bsl = Bs + t*8;

  int fr = lane & 15, fq = lane >> 4;
  const ushort* Ard = As + (wm + fr)*32 + fq*8;
  const ushort* Brd = Bs + (wn + fr)*32 + fq*8;

  for (int k0 = 0; k0 < K; k0 += 32) {
    __syncthreads();
    gld16(Ag,        Asl);
    gld16(Ag + 64*K, Asl + 64*32);
    gld16(Bg,        Bsl);
    gld16(Bg + 64*K, Bsl + 64*32);
    Ag += 32; Bg += 32;
    __syncthreads();
    bf16x8 af[4], bfr[4];
    #pragma unroll
    for (int i=0;i<4;++i) af[i]  = *(const bf16x8*)(Ard + i*16*32);
    #pragma unroll
    for (int j=0;j<4;++j) bfr[j] = *(const bf16x8*)(Brd + j*16*32);
    #pragma unroll
    for (int i=0;i<4;++i)
      #pragma unroll
      for (int j=0;j<4;++j)
        acc[i][j] = __builtin_amdgcn_mfma_f32_16x16x32_bf16(af[i], bfr[j], acc[i][j], 0, 0, 0);
  }

  int ncol = lane & 15;
  int rquad = (lane >> 4) * 4;
  #pragma unroll
  for (int j=0;j<4;++j) {
    int n = n0 + wn + j*16 + ncol;
    float bv = bias[n];
    int part = n >> 9;            // 0=q 1=k 2=v (block-uniform: 128 | 512)
    int wi = n & 511;
    int h = wi >> 6, d = wi & 63;
    #pragma unroll
    for (int i=0;i<4;++i) {
      int mbase = m0 + wm + i*16 + rquad;
      #pragma unroll
      for (int r=0;r<4;++r) {
        int m = mbase + r;
        int b = m >> 11, l = m & 2047;
        int bh = b*H_ + h;
        float cv = acc[i][j][r] + bv;
        if (part == 0) cv *= 0.125f;       // fold 1/sqrt(dh) into q
        ushort c = f2b(cv);
        if (part == 0)      qb[((size_t)bh*L_ + l)*DH_ + d] = c;
        else if (part == 1) kb[((size_t)bh*L_ + l)*DH_ + d] = c;
        else                vtb[((size_t)bh*DH_ + d)*L_ + l] = c;
      }
    }
  }
}

// ---------------- MFMA flash attention, one-pass softmax ----------------
__global__ __launch_bounds__(256) void attn_mfma(
    const ushort* __restrict__ qb, const ushort* __restrict__ kb,
    const ushort* __restrict__ vtb, ushort* __restrict__ outa)
{
  __shared__ ushort Qs[64*72];
  __shared__ ushort Ks[64*72];
  __shared__ ushort Vts[64*72];
  __shared__ ushort Ps[4*16*72];
  __shared__ float dls[64];

  int t = threadIdx.x;
  int lane = t & 63, w = t >> 6;
  int qt = blockIdx.x & 31;
  int h  = (blockIdx.x >> 5) & 7;
  int b  = blockIdx.x >> 8;
  int l0 = qt * 64;
  bool isgen = (l0 >= P_);
  int bh = b*H_ + h;

  const ushort* qg  = qb  + ((size_t)bh*L_ + l0)*DH_;
  const ushort* kgb = kb  + (size_t)bh*L_*DH_;
  const ushort* vtg = vtb + (size_t)bh*DH_*L_;

  int sr = t >> 3, sc = (t & 7) * 8;

  {
    uint4 x0 = *(const uint4*)(qg + (size_t)sr*DH_ + sc);
    uint4 x1 = *(const uint4*)(qg + (size_t)(sr+32)*DH_ + sc);
    *(uint4*)(Qs + sr*72 + sc) = x0;
    *(uint4*)(Qs + (sr+32)*72 + sc) = x1;
  }
  __syncthreads();

  int fr = lane & 15, fq = lane >> 4;
  bf16x8 qf[2];
  qf[0] = *(const bf16x8*)(Qs + (16*w + fr)*72 + 0*32 + fq*8);
  qf[1] = *(const bf16x8*)(Qs + (16*w + fr)*72 + 1*32 + fq*8);

  float den[4] = {0.f, 0.f, 0.f, 0.f};
  f32x4 o[4] = {};

  ushort* Pw = Ps + w*16*72;

  // register prefetch of K/V tile kt=0
  uint4 pk0 = *(const uint4*)(kgb + (size_t)sr*DH_ + sc);
  uint4 pk1 = *(const uint4*)(kgb + (size_t)(sr+32)*DH_ + sc);
  uint4 pv0 = *(const uint4*)(vtg + (size_t)sr*L_ + sc);
  uint4 pv1 = *(const uint4*)(vtg + (size_t)(sr+32)*L_ + sc);

  for (int kt = 0; kt < 16; ++kt) {
    __syncthreads();
    *(uint4*)(Ks + sr*72 + sc) = pk0;
    *(uint4*)(Ks + (sr+32)*72 + sc) = pk1;
    *(uint4*)(Vts + sr*72 + sc) = pv0;
    *(uint4*)(Vts + (sr+32)*72 + sc) = pv1;
    __syncthreads();

    if (kt < 15) {
      int p1 = (kt + 1) * 64;
      pk0 = *(const uint4*)(kgb + (size_t)(p1+sr)*DH_ + sc);
      pk1 = *(const uint4*)(kgb + (size_t)(p1+sr+32)*DH_ + sc);
      pv0 = *(const uint4*)(vtg + (size_t)sr*L_ + p1 + sc);
      pv1 = *(const uint4*)(vtg + (size_t)(sr+32)*L_ + p1 + sc);
    }

    f32x4 sc4[4] = {};
    #pragma unroll
    for (int s=0;s<2;++s) {
      #pragma unroll
      for (int j=0;j<4;++j) {
        bf16x8 kf = *(const bf16x8*)(Ks + (j*16 + fr)*72 + s*32 + fq*8);
        sc4[j] = __builtin_amdgcn_mfma_f32_16x16x32_bf16(qf[s], kf, sc4[j], 0, 0, 0);
      }
    }

    #pragma unroll
    for (int r=0;r<4;++r) {
      float e0 = __expf(sc4[0][r]);
      float e1 = __expf(sc4[1][r]);
      float e2 = __expf(sc4[2][r]);
      float e3 = __expf(sc4[3][r]);
      den[r] += (e0+e1) + (e2+e3);
      Pw[(fq*4+r)*72 +  0 + fr] = (ushort)(__float_as_uint(e0) >> 16);
      Pw[(fq*4+r)*72 + 16 + fr] = (ushort)(__float_as_uint(e1) >> 16);
      Pw[(fq*4+r)*72 + 32 + fr] = (ushort)(__float_as_uint(e2) >> 16);
      Pw[(fq*4+r)*72 + 48 + fr] = (ushort)(__float_as_uint(e3) >> 16);
    }
    asm volatile("s_waitcnt lgkmcnt(0)" ::: "memory");

    #pragma unroll
    for (int s=0;s<2;++s) {
      bf16x8 pf = *(const bf16x8*)(Pw + fr*72 + s*32 + fq*8);
      #pragma unroll
      for (int j=0;j<4;++j) {
        bf16x8 vf = *(const bf16x8*)(Vts + (j*16 + fr)*72 + s*32 + fq*8);
        o[j] = __builtin_amdgcn_mfma_f32_16x16x32_bf16(pf, vf, o[j], 0, 0, 0);
      }
    }
  }

  #pragma unroll
  for (int r=0;r<4;++r) {
    float d = den[r];
    d += __shfl_xor(d, 1, 16);
    d += __shfl_xor(d, 2, 16);
    d += __shfl_xor(d, 4, 16);
    d += __shfl_xor(d, 8, 16);
    den[r] = d;
  }

  if (isgen) {
    __syncthreads();
    {
      uint4 k0v = *(const uint4*)(kgb + (size_t)(l0+sr)*DH_ + sc);
      uint4 k1v = *(const uint4*)(kgb + (size_t)(l0+sr+32)*DH_ + sc);
      uint4 v0v = *(const uint4*)(vtg + (size_t)sr*L_ + l0 + sc);
      uint4 v1v = *(const uint4*)(vtg + (size_t)(sr+32)*L_ + l0 + sc);
      *(uint4*)(Ks + sr*72 + sc) = k0v;
      *(uint4*)(Ks + (sr+32)*72 + sc) = k1v;
      *(uint4*)(Vts + sr*72 + sc) = v0v;
      *(uint4*)(Vts + (sr+32)*72 + sc) = v1v;
    }
    __syncthreads();
    {
      int row = t >> 2, part = t & 3;
      float dsum = 0.f;
      #pragma unroll
      for (int u=0;u<16;++u) {
        int d = part*16 + u;
        dsum = fmaf(b2f(Qs[row*72+d]), b2f(Ks[row*72+d]), dsum);
      }
      dsum += __shfl_xor(dsum, 1, 4);
      dsum += __shfl_xor(dsum, 2, 4);
      if (part == 0) dls[row] = dsum;
    }
    __syncthreads();
    #pragma unroll
    for (int r=0;r<4;++r) {
      int rr = 16*w + fq*4 + r;
      float ed = __expf(dls[rr]);
      den[r] += ed;
      #pragma unroll
      for (int j=0;j<4;++j) {
        float vv = b2f(Vts[(j*16 + fr)*72 + rr]);
        o[j][r] += ed*vv;
      }
    }
  }

  #pragma unroll
  for (int r=0;r<4;++r) {
    float inv = 1.f / den[r];
    int l = l0 + 16*w + fq*4 + r;
    #pragma unroll
    for (int j=0;j<4;++j)
      outa[((size_t)b*L_ + l)*D_ + h*DH_ + j*16 + fr] = f2b(o[j][r]*inv);
  }
}

// ---------------- LayerNorm -> x fp32 + xbf bf16 ----------------
__global__ __launch_bounds__(64) void ln_kernel(const float* __restrict__ y,
    const float* __restrict__ gw, const float* __restrict__ bw,
    float* __restrict__ x, ushort* __restrict__ xb)
{
  int row = blockIdx.x, t = threadIdx.x;
  const float4* yr = (const float4*)(y + (size_t)row*D_);
  float4 v0 = yr[t], v1 = yr[t+64];
  float s = v0.x+v0.y+v0.z+v0.w + v1.x+v1.y+v1.z+v1.w;
  for (int off=32; off>0; off>>=1) s += __shfl_down(s, off, 64);
  s = __shfl(s, 0, 64);
  float mu = s * (1.f/D_);
  float dx;
  float q = 0.f;
  dx=v0.x-mu; q+=dx*dx; dx=v0.y-mu; q+=dx*dx; dx=v0.z-mu; q+=dx*dx; dx=v0.w-mu; q+=dx*dx;
  dx=v1.x-mu; q+=dx*dx; dx=v1.y-mu; q+=dx*dx; dx=v1.z-mu; q+=dx*dx; dx=v1.w-mu; q+=dx*dx;
  for (int off=32; off>0; off>>=1) q += __shfl_down(q, off, 64);
  q = __shfl(q, 0, 64);
  float rinv = rsqrtf(q*(1.f/D_) + LN_EPS_);
  const float4* g4 = (const float4*)gw;
  const float4* b4 = (const float4*)bw;
  float4 gv0=g4[t], gv1=g4[t+64], bv0=b4[t], bv1=b4[t+64];
  float4 o0, o1;
  o0.x=(v0.x-mu)*rinv*gv0.x+bv0.x; o0.y=(v0.y-mu)*rinv*gv0.y+bv0.y;
  o0.z=(v0.z-mu)*rinv*gv0.z+bv0.z; o0.w=(v0.w-mu)*rinv*gv0.w+bv0.w;
  o1.x=(v1.x-mu)*rinv*gv1.x+bv1.x; o1.y=(v1.y-mu)*rinv*gv1.y+bv1.y;
  o1.z=(v1.z-mu)*rinv*gv1.z+bv1.z; o1.w=(v1.w-mu)*rinv*gv1.w+bv1.w;
  float4* xr = (float4*)(x + (size_t)row*D_);
  xr[t]=o0; xr[t+64]=o1;
  ushort4 h0, h1;
  h0.x=f2b(o0.x); h0.y=f2b(o0.y); h0.z=f2b(o0.z); h0.w=f2b(o0.w);
  h1.x=f2b(o1.x); h1.y=f2b(o1.y); h1.z=f2b(o1.z); h1.w=f2b(o1.w);
  ushort4* xbr = (ushort4*)(xb + (size_t)row*D_);
  xbr[t]=h0; xbr[t+64]=h1;
}

extern "C" void kernel_launch(void* const* d_in, const int* in_sizes, int n_in,
                              void* d_out, int out_size, void* d_ws, size_t ws_size,
                              hipStream_t stream) {
  const float* pcpt = (const float*)d_in[0];
  const float* gen  = (const float*)d_in[1];
  const float* Wqkv = (const float*)d_in[3];
  const float* bqkv = (const float*)d_in[4];
  const float* Wo   = (const float*)d_in[5];
  const float* bo   = (const float*)d_in[6];
  const float* W1   = (const float*)d_in[7];
  const float* b1   = (const float*)d_in[8];
  const float* W2   = (const float*)d_in[9];
  const float* b2   = (const float*)d_in[10];
  const float* g1   = (const float*)d_in[11];
  const float* be1  = (const float*)d_in[12];
  const float* g2   = (const float*)d_in[13];
  const float* be2  = (const float*)d_in[14];
  float* out = (float*)d_out;

  const size_t XD  = (size_t)B_*L_*D_;
  const size_t HKV = (size_t)B_*H_*L_*DH_;
  const size_t HFF = (size_t)B_*L_*FF_;

  float*  xbuf = (float*)d_ws;
  ushort* xbf  = (ushort*)(xbuf + XD);
  ushort* region = xbf + XD;
  ushort* qb  = region;                        // aliased with hbf
  ushort* kb  = region + HKV;
  ushort* vtb = region + 2*HKV;
  ushort* hbf = region;
  ushort* abf = region + HFF;
  ushort* wb  = abf + XD;
  ushort* wqkv_b = wb;
  ushort* wo_b   = wqkv_b + (size_t)4*3*D_*D_;
  ushort* w1_b   = wo_b   + (size_t)4*D_*D_;
  ushort* w2_b   = w1_b   + (size_t)4*FF_*D_;
  float*  ybuf = out;

  const int M = B_*L_;

  wconv_kernel<<<dim3(3*D_/32, D_/32, 4), 256, 0, stream>>>(Wqkv, wqkv_b, D_, 3*D_);
  wconv_kernel<<<dim3(D_/32,   D_/32, 4), 256, 0, stream>>>(Wo,   wo_b,   D_, D_);
  wconv_kernel<<<dim3(FF_/32,  D_/32, 4), 256, 0, stream>>>(W1,   w1_b,   D_, FF_);
  wconv_kernel<<<dim3(D_/32,  FF_/32, 4), 256, 0, stream>>>(W2,   w2_b,   FF_, D_);

  concat_kernel<<<4096, 256, 0, stream>>>(pcpt, gen, xbuf, xbf);

  for (int i = 0; i < LAYERS_; ++i) {
    const ushort* wqkv_i = wqkv_b + (size_t)i*3*D_*D_;
    const ushort* wo_i   = wo_b   + (size_t)i*D_*D_;
    const ushort* w1_i   = w1_b   + (size_t)i*FF_*D_;
    const ushort* w2_i   = w2_b   + (size_t)i*D_*FF_;
    const float* bqkv_i = bqkv + (size_t)i*3*D_;
    const float* bo_i   = bo   + (size_t)i*D_;
    const float* b1_i   = b1   + (size_t)i*FF_;
    const float* b2_i   = b2   + (size_t)i*D_;
    const float* g1_i   = g1   + (size_t)i*D_;
    const float* be1_i  = be1  + (size_t)i*D_;
    const float* g2_i   = g2   + (size_t)i*D_;
    const float* be2_i  = be2  + (size_t)i*D_;

    // grid: (m-tiles, n-tiles) -> n-tiles of an m-band share an XCD
    mgemm_qkv<<<dim3(M/128, 3*D_/128), 256, 0, stream>>>(
        xbf, wqkv_i, bqkv_i, qb, kb, vtb);

    attn_mfma<<<B_*H_*(L_/64), 256, 0, stream>>>(qb, kb, vtb, abf);

    mgemm<64,0,1,0><<<dim3(M/128, D_/64), 256, 0, stream>>>(
        abf, wo_i, bo_i, xbuf, ybuf, M, D_, D_);

    ln_kernel<<<M, 64, 0, stream>>>(ybuf, g1_i, be1_i, xbuf, xbf);

    mgemm<128,1,0,1><<<dim3(M/128, FF_/128), 256, 0, stream>>>(
        xbf, w1_i, b1_i, nullptr, hbf, M, FF_, D_);

    mgemm<64,0,1,0><<<dim3(M/128, D_/64), 256, 0, stream>>>(
        hbf, w2_i, b2_i, xbuf, ybuf, M, D_, FF_);

    ln_kernel<<<M, 64, 0, stream>>>(ybuf, g2_i, be2_i, xbuf, xbf);
  }

  writeout_kernel<<<4096, 256, 0, stream>>>(xbuf, out);
}

// Round 8
// 833.708 us; speedup vs baseline: 22.1342x; 1.0114x over previous
//
#include <hip/hip_runtime.h>
#include <hip/hip_bf16.h>

#define B_ 4
#define P_ 1024
#define G_ 1024
#define L_ 2048
#define D_ 512
#define FF_ 2048
#define H_ 8
#define DH_ 64
#define LAYERS_ 4
#define LN_EPS_ 1e-5f

typedef __attribute__((ext_vector_type(8))) short bf16x8;
typedef __attribute__((ext_vector_type(4))) float f32x4;

__device__ __forceinline__ ushort f2b(float f) {
  unsigned u = __float_as_uint(f);
  unsigned r = (u + 0x7fffu + ((u >> 16) & 1u)) >> 16;
  return (ushort)r;
}
__device__ __forceinline__ float b2f(ushort u) {
  return __uint_as_float(((unsigned)u) << 16);
}

// async 16B global->LDS (DMA; dest = wave-uniform base + lane*16)
__device__ __forceinline__ void gld16(const ushort* g, ushort* l) {
  __builtin_amdgcn_global_load_lds(
      (const __attribute__((address_space(1))) void*)g,
      (__attribute__((address_space(3))) void*)l, 16, 0, 0);
}

// ---------------- concat pcpt+gen -> x (fp32) + xbf (bf16) ----------------
__global__ __launch_bounds__(256) void concat_kernel(const float* __restrict__ p,
    const float* __restrict__ g, float* __restrict__ x, ushort* __restrict__ xb)
{
  const int LD4 = L_*D_/4, PD4 = P_*D_/4;
  int i = blockIdx.x*256 + threadIdx.x;
  int b = i / LD4, r = i - b*LD4;
  float4 v;
  if (r < PD4) v = ((const float4*)p)[(size_t)b*PD4 + r];
  else         v = ((const float4*)g)[(size_t)b*PD4 + (r-PD4)];
  ((float4*)x)[i] = v;
  ushort4 h; h.x=f2b(v.x); h.y=f2b(v.y); h.z=f2b(v.z); h.w=f2b(v.w);
  ((ushort4*)xb)[i] = h;
}

// ---------------- writeout ----------------
__global__ __launch_bounds__(256) void writeout_kernel(const float* __restrict__ x,
    float* __restrict__ out)
{
  const int LD4 = L_*D_/4, PD4 = P_*D_/4, HALF = B_*PD4;
  int i = blockIdx.x*256 + threadIdx.x;
  int half = (i >= HALF) ? 1 : 0;
  int r = i - half*HALF;
  int b = r / PD4, q = r - b*PD4;
  ((float4*)out)[i] = ((const float4*)x)[(size_t)b*LD4 + half*PD4 + q];
}

// ---------------- weight transpose+convert: src K x N fp32 -> dst N x K bf16 ----------------
__global__ __launch_bounds__(256) void wconv_kernel(const float* __restrict__ src,
    ushort* __restrict__ dst, int K, int N)
{
  __shared__ float tile[32][33];
  int n0 = blockIdx.x*32, k0 = blockIdx.y*32, l = blockIdx.z;
  src += (size_t)l*K*N; dst += (size_t)l*K*N;
  int tx = threadIdx.x & 31, ty = threadIdx.x >> 5;
  #pragma unroll
  for (int u=0;u<4;++u) tile[ty+8*u][tx] = src[(size_t)(k0+ty+8*u)*N + n0+tx];
  __syncthreads();
  #pragma unroll
  for (int u=0;u<4;++u) dst[(size_t)(n0+ty+8*u)*K + k0+tx] = f2b(tile[tx][ty+8*u]);
}

// ---------------- bf16 MFMA GEMM, BN_ in {128,64}, BM=128, BK=32 ----------------
// LDS layout XOR-swizzled: 16B chunk c of row r -> slot 4r + (c ^ ((r>>1)&3)).
// Loader (dest slot fixed = t by global_load_lds): lane t fetches global chunk
// (t&3)^((t>>3)&3). Reader adds 8*(fq ^ ((fr>>1)&3)). 8 consecutive rows hit
// 8 distinct bank groups -> 2 lanes/bank (free) instead of 8-way conflicts.
template<int BN_, int RELU, int RES, int OUTBF>
__global__ __launch_bounds__(256) void mgemm(
    const ushort* __restrict__ A, const ushort* __restrict__ Bt,
    const float* __restrict__ bias, const float* __restrict__ res,
    void* __restrict__ Cout, int M, int N, int K)
{
  constexpr int MI = (BN_ == 128) ? 4 : 2;
  __shared__ ushort As[128*32];
  __shared__ ushort Bs[BN_*32];
  int t = threadIdx.x;
  int lane = t & 63, w = t >> 6;
  int wm = (BN_ == 128) ? (w >> 1) * 64 : w * 32;
  int wn = (BN_ == 128) ? (w & 1) * 64 : 0;
  int m0 = blockIdx.x * 128, n0 = blockIdx.y * BN_;

  f32x4 acc[MI][4] = {};

  int cg = ((t & 3) ^ ((t >> 3) & 3)) * 8;     // swizzled global chunk
  const ushort* Ag = A  + (size_t)(m0 + (t >> 2))*K + cg;
  const ushort* Bg = Bt + (size_t)(n0 + (t >> 2))*K + cg;
  ushort* Asl = As + t*8;
  ushort* Bsl = Bs + t*8;

  int fr = lane & 15, fq = lane >> 4;
  int sw = (fq ^ ((fr >> 1) & 3)) * 8;         // swizzled read chunk
  const ushort* Ard = As + (wm + fr)*32 + sw;
  const ushort* Brd = Bs + (wn + fr)*32 + sw;

  for (int k0 = 0; k0 < K; k0 += 32) {
    __syncthreads();
    gld16(Ag,          Asl);
    gld16(Ag + 64*K,   Asl + 64*32);
    gld16(Bg,          Bsl);
    if (BN_ == 128) gld16(Bg + 64*K, Bsl + 64*32);
    Ag += 32; Bg += 32;
    __syncthreads();
    bf16x8 af[MI], bfr[4];
    #pragma unroll
    for (int i=0;i<MI;++i) af[i]  = *(const bf16x8*)(Ard + i*16*32);
    #pragma unroll
    for (int j=0;j<4;++j)  bfr[j] = *(const bf16x8*)(Brd + j*16*32);
    #pragma unroll
    for (int i=0;i<MI;++i)
      #pragma unroll
      for (int j=0;j<4;++j)
        acc[i][j] = __builtin_amdgcn_mfma_f32_16x16x32_bf16(af[i], bfr[j], acc[i][j], 0, 0, 0);
  }

  int ncol = lane & 15;
  int rquad = (lane >> 4) * 4;
  #pragma unroll
  for (int j=0;j<4;++j) {
    int n = n0 + wn + j*16 + ncol;
    float bv = bias[n];
    #pragma unroll
    for (int i=0;i<MI;++i) {
      int mbase = m0 + wm + i*16 + rquad;
      #pragma unroll
      for (int r=0;r<4;++r) {
        int m = mbase + r;
        float c = acc[i][j][r] + bv;
        if (RES) c += res[(size_t)m*N + n];
        if (RELU) c = fmaxf(c, 0.f);
        if (OUTBF) ((ushort*)Cout)[(size_t)m*N + n] = f2b(c);
        else       ((float*)Cout)[(size_t)m*N + n] = c;
      }
    }
  }
}

// ---------------- QKV GEMM: bf16 out; q pre-scaled by 1/8; v transposed ----------------
__global__ __launch_bounds__(256) void mgemm_qkv(
    const ushort* __restrict__ A,    // M x 512 bf16 (x)
    const ushort* __restrict__ Bt,   // 1536 x 512 bf16
    const float* __restrict__ bias,  // 1536
    ushort* __restrict__ qb,         // [b,h,l,64]  (pre-scaled by 0.125)
    ushort* __restrict__ kb,         // [b,h,l,64]
    ushort* __restrict__ vtb)        // [b,h,64,l]
{
  const int K = D_;
  __shared__ ushort As[128*32];
  __shared__ ushort Bs[128*32];
  int t = threadIdx.x;
  int lane = t & 63, w = t >> 6;
  int wm = (w >> 1) * 64, wn = (w & 1) * 64;
  int m0 = blockIdx.x * 128, n0 = blockIdx.y * 128;

  f32x4 acc[4][4] = {};

  int cg = ((t & 3) ^ ((t >> 3) & 3)) * 8;
  const ushort* Ag = A  + (size_t)(m0 + (t >> 2))*K + cg;
  const ushort* Bg = Bt + (size_t)(n0 + (t >> 2))*K + cg;
  ushort* Asl = As + t*8;
  ushort* Bsl = Bs + t*8;

  int fr = lane & 15, fq = lane >> 4;
  int sw = (fq ^ ((fr >> 1) & 3)) * 8;
  const ushort* Ard = As + (wm + fr)*32 + sw;
  const ushort* Brd = Bs + (wn + fr)*32 + sw;

  for (int k0 = 0; k0 < K; k0 += 32) {
    __syncthreads();
    gld16(Ag,        Asl);
    gld16(Ag + 64*K, Asl + 64*32);
    gld16(Bg,        Bsl);
    gld16(Bg + 64*K, Bsl + 64*32);
    Ag += 32; Bg += 32;
    __syncthreads();
    bf16x8 af[4], bfr[4];
    #pragma unroll
    for (int i=0;i<4;++i) af[i]  = *(const bf16x8*)(Ard + i*16*32);
    #pragma unroll
    for (int j=0;j<4;++j) bfr[j] = *(const bf16x8*)(Brd + j*16*32);
    #pragma unroll
    for (int i=0;i<4;++i)
      #pragma unroll
      for (int j=0;j<4;++j)
        acc[i][j] = __builtin_amdgcn_mfma_f32_16x16x32_bf16(af[i], bfr[j], acc[i][j], 0, 0, 0);
  }

  int ncol = lane & 15;
  int rquad = (lane >> 4) * 4;
  #pragma unroll
  for (int j=0;j<4;++j) {
    int n = n0 + wn + j*16 + ncol;
    float bv = bias[n];
    int part = n >> 9;            // 0=q 1=k 2=v (block-uniform: 128 | 512)
    int wi = n & 511;
    int h = wi >> 6, d = wi & 63;
    #pragma unroll
    for (int i=0;i<4;++i) {
      int mbase = m0 + wm + i*16 + rquad;
      #pragma unroll
      for (int r=0;r<4;++r) {
        int m = mbase + r;
        int b = m >> 11, l = m & 2047;
        int bh = b*H_ + h;
        float cv = acc[i][j][r] + bv;
        if (part == 0) cv *= 0.125f;       // fold 1/sqrt(dh) into q
        ushort c = f2b(cv);
        if (part == 0)      qb[((size_t)bh*L_ + l)*DH_ + d] = c;
        else if (part == 1) kb[((size_t)bh*L_ + l)*DH_ + d] = c;
        else                vtb[((size_t)bh*DH_ + d)*L_ + l] = c;
      }
    }
  }
}

// ---------------- MFMA flash attention, one-pass softmax ----------------
__global__ __launch_bounds__(256) void attn_mfma(
    const ushort* __restrict__ qb, const ushort* __restrict__ kb,
    const ushort* __restrict__ vtb, ushort* __restrict__ outa)
{
  __shared__ ushort Qs[64*72];
  __shared__ ushort Ks[64*72];
  __shared__ ushort Vts[64*72];
  __shared__ ushort Ps[4*16*72];
  __shared__ float dls[64];

  int t = threadIdx.x;
  int lane = t & 63, w = t >> 6;
  int qt = blockIdx.x & 31;
  int h  = (blockIdx.x >> 5) & 7;
  int b  = blockIdx.x >> 8;
  int l0 = qt * 64;
  bool isgen = (l0 >= P_);
  int bh = b*H_ + h;

  const ushort* qg  = qb  + ((size_t)bh*L_ + l0)*DH_;
  const ushort* kgb = kb  + (size_t)bh*L_*DH_;
  const ushort* vtg = vtb + (size_t)bh*DH_*L_;

  int sr = t >> 3, sc = (t & 7) * 8;

  {
    uint4 x0 = *(const uint4*)(qg + (size_t)sr*DH_ + sc);
    uint4 x1 = *(const uint4*)(qg + (size_t)(sr+32)*DH_ + sc);
    *(uint4*)(Qs + sr*72 + sc) = x0;
    *(uint4*)(Qs + (sr+32)*72 + sc) = x1;
  }
  __syncthreads();

  int fr = lane & 15, fq = lane >> 4;
  bf16x8 qf[2];
  qf[0] = *(const bf16x8*)(Qs + (16*w + fr)*72 + 0*32 + fq*8);
  qf[1] = *(const bf16x8*)(Qs + (16*w + fr)*72 + 1*32 + fq*8);

  float den[4] = {0.f, 0.f, 0.f, 0.f};
  f32x4 o[4] = {};

  ushort* Pw = Ps + w*16*72;

  // register prefetch of K/V tile kt=0
  uint4 pk0 = *(const uint4*)(kgb + (size_t)sr*DH_ + sc);
  uint4 pk1 = *(const uint4*)(kgb + (size_t)(sr+32)*DH_ + sc);
  uint4 pv0 = *(const uint4*)(vtg + (size_t)sr*L_ + sc);
  uint4 pv1 = *(const uint4*)(vtg + (size_t)(sr+32)*L_ + sc);

  for (int kt = 0; kt < 16; ++kt) {
    __syncthreads();
    *(uint4*)(Ks + sr*72 + sc) = pk0;
    *(uint4*)(Ks + (sr+32)*72 + sc) = pk1;
    *(uint4*)(Vts + sr*72 + sc) = pv0;
    *(uint4*)(Vts + (sr+32)*72 + sc) = pv1;
    __syncthreads();

    if (kt < 15) {
      int p1 = (kt + 1) * 64;
      pk0 = *(const uint4*)(kgb + (size_t)(p1+sr)*DH_ + sc);
      pk1 = *(const uint4*)(kgb + (size_t)(p1+sr+32)*DH_ + sc);
      pv0 = *(const uint4*)(vtg + (size_t)sr*L_ + p1 + sc);
      pv1 = *(const uint4*)(vtg + (size_t)(sr+32)*L_ + p1 + sc);
    }

    f32x4 sc4[4] = {};
    #pragma unroll
    for (int s=0;s<2;++s) {
      #pragma unroll
      for (int j=0;j<4;++j) {
        bf16x8 kf = *(const bf16x8*)(Ks + (j*16 + fr)*72 + s*32 + fq*8);
        sc4[j] = __builtin_amdgcn_mfma_f32_16x16x32_bf16(qf[s], kf, sc4[j], 0, 0, 0);
      }
    }

    #pragma unroll
    for (int r=0;r<4;++r) {
      float e0 = __expf(sc4[0][r]);
      float e1 = __expf(sc4[1][r]);
      float e2 = __expf(sc4[2][r]);
      float e3 = __expf(sc4[3][r]);
      den[r] += (e0+e1) + (e2+e3);
      Pw[(fq*4+r)*72 +  0 + fr] = (ushort)(__float_as_uint(e0) >> 16);
      Pw[(fq*4+r)*72 + 16 + fr] = (ushort)(__float_as_uint(e1) >> 16);
      Pw[(fq*4+r)*72 + 32 + fr] = (ushort)(__float_as_uint(e2) >> 16);
      Pw[(fq*4+r)*72 + 48 + fr] = (ushort)(__float_as_uint(e3) >> 16);
    }
    asm volatile("s_waitcnt lgkmcnt(0)" ::: "memory");

    #pragma unroll
    for (int s=0;s<2;++s) {
      bf16x8 pf = *(const bf16x8*)(Pw + fr*72 + s*32 + fq*8);
      #pragma unroll
      for (int j=0;j<4;++j) {
        bf16x8 vf = *(const bf16x8*)(Vts + (j*16 + fr)*72 + s*32 + fq*8);
        o[j] = __builtin_amdgcn_mfma_f32_16x16x32_bf16(pf, vf, o[j], 0, 0, 0);
      }
    }
  }

  #pragma unroll
  for (int r=0;r<4;++r) {
    float d = den[r];
    d += __shfl_xor(d, 1, 16);
    d += __shfl_xor(d, 2, 16);
    d += __shfl_xor(d, 4, 16);
    d += __shfl_xor(d, 8, 16);
    den[r] = d;
  }

  if (isgen) {
    __syncthreads();
    {
      uint4 k0v = *(const uint4*)(kgb + (size_t)(l0+sr)*DH_ + sc);
      uint4 k1v = *(const uint4*)(kgb + (size_t)(l0+sr+32)*DH_ + sc);
      uint4 v0v = *(const uint4*)(vtg + (size_t)sr*L_ + l0 + sc);
      uint4 v1v = *(const uint4*)(vtg + (size_t)(sr+32)*L_ + l0 + sc);
      *(uint4*)(Ks + sr*72 + sc) = k0v;
      *(uint4*)(Ks + (sr+32)*72 + sc) = k1v;
      *(uint4*)(Vts + sr*72 + sc) = v0v;
      *(uint4*)(Vts + (sr+32)*72 + sc) = v1v;
    }
    __syncthreads();
    {
      int row = t >> 2, part = t & 3;
      float dsum = 0.f;
      #pragma unroll
      for (int u=0;u<16;++u) {
        int d = part*16 + u;
        dsum = fmaf(b2f(Qs[row*72+d]), b2f(Ks[row*72+d]), dsum);
      }
      dsum += __shfl_xor(dsum, 1, 4);
      dsum += __shfl_xor(dsum, 2, 4);
      if (part == 0) dls[row] = dsum;
    }
    __syncthreads();
    #pragma unroll
    for (int r=0;r<4;++r) {
      int rr = 16*w + fq*4 + r;
      float ed = __expf(dls[rr]);
      den[r] += ed;
      #pragma unroll
      for (int j=0;j<4;++j) {
        float vv = b2f(Vts[(j*16 + fr)*72 + rr]);
        o[j][r] += ed*vv;
      }
    }
  }

  #pragma unroll
  for (int r=0;r<4;++r) {
    float inv = 1.f / den[r];
    int l = l0 + 16*w + fq*4 + r;
    #pragma unroll
    for (int j=0;j<4;++j)
      outa[((size_t)b*L_ + l)*D_ + h*DH_ + j*16 + fr] = f2b(o[j][r]*inv);
  }
}

// ---------------- LayerNorm -> x fp32 + xbf bf16 ----------------
__global__ __launch_bounds__(64) void ln_kernel(const float* __restrict__ y,
    const float* __restrict__ gw, const float* __restrict__ bw,
    float* __restrict__ x, ushort* __restrict__ xb)
{
  int row = blockIdx.x, t = threadIdx.x;
  const float4* yr = (const float4*)(y + (size_t)row*D_);
  float4 v0 = yr[t], v1 = yr[t+64];
  float s = v0.x+v0.y+v0.z+v0.w + v1.x+v1.y+v1.z+v1.w;
  for (int off=32; off>0; off>>=1) s += __shfl_down(s, off, 64);
  s = __shfl(s, 0, 64);
  float mu = s * (1.f/D_);
  float dx;
  float q = 0.f;
  dx=v0.x-mu; q+=dx*dx; dx=v0.y-mu; q+=dx*dx; dx=v0.z-mu; q+=dx*dx; dx=v0.w-mu; q+=dx*dx;
  dx=v1.x-mu; q+=dx*dx; dx=v1.y-mu; q+=dx*dx; dx=v1.z-mu; q+=dx*dx; dx=v1.w-mu; q+=dx*dx;
  for (int off=32; off>0; off>>=1) q += __shfl_down(q, off, 64);
  q = __shfl(q, 0, 64);
  float rinv = rsqrtf(q*(1.f/D_) + LN_EPS_);
  const float4* g4 = (const float4*)gw;
  const float4* b4 = (const float4*)bw;
  float4 gv0=g4[t], gv1=g4[t+64], bv0=b4[t], bv1=b4[t+64];
  float4 o0, o1;
  o0.x=(v0.x-mu)*rinv*gv0.x+bv0.x; o0.y=(v0.y-mu)*rinv*gv0.y+bv0.y;
  o0.z=(v0.z-mu)*rinv*gv0.z+bv0.z; o0.w=(v0.w-mu)*rinv*gv0.w+bv0.w;
  o1.x=(v1.x-mu)*rinv*gv1.x+bv1.x; o1.y=(v1.y-mu)*rinv*gv1.y+bv1.y;
  o1.z=(v1.z-mu)*rinv*gv1.z+bv1.z; o1.w=(v1.w-mu)*rinv*gv1.w+bv1.w;
  float4* xr = (float4*)(x + (size_t)row*D_);
  xr[t]=o0; xr[t+64]=o1;
  ushort4 h0, h1;
  h0.x=f2b(o0.x); h0.y=f2b(o0.y); h0.z=f2b(o0.z); h0.w=f2b(o0.w);
  h1.x=f2b(o1.x); h1.y=f2b(o1.y); h1.z=f2b(o1.z); h1.w=f2b(o1.w);
  ushort4* xbr = (ushort4*)(xb + (size_t)row*D_);
  xbr[t]=h0; xbr[t+64]=h1;
}

extern "C" void kernel_launch(void* const* d_in, const int* in_sizes, int n_in,
                              void* d_out, int out_size, void* d_ws, size_t ws_size,
                              hipStream_t stream) {
  const float* pcpt = (const float*)d_in[0];
  const float* gen  = (const float*)d_in[1];
  const float* Wqkv = (const float*)d_in[3];
  const float* bqkv = (const float*)d_in[4];
  const float* Wo   = (const float*)d_in[5];
  const float* bo   = (const float*)d_in[6];
  const float* W1   = (const float*)d_in[7];
  const float* b1   = (const float*)d_in[8];
  const float* W2   = (const float*)d_in[9];
  const float* b2   = (const float*)d_in[10];
  const float* g1   = (const float*)d_in[11];
  const float* be1  = (const float*)d_in[12];
  const float* g2   = (const float*)d_in[13];
  const float* be2  = (const float*)d_in[14];
  float* out = (float*)d_out;

  const size_t XD  = (size_t)B_*L_*D_;
  const size_t HKV = (size_t)B_*H_*L_*DH_;
  const size_t HFF = (size_t)B_*L_*FF_;

  float*  xbuf = (float*)d_ws;
  ushort* xbf  = (ushort*)(xbuf + XD);
  ushort* region = xbf + XD;
  ushort* qb  = region;                        // aliased with hbf
  ushort* kb  = region + HKV;
  ushort* vtb = region + 2*HKV;
  ushort* hbf = region;
  ushort* abf = region + HFF;
  ushort* wb  = abf + XD;
  ushort* wqkv_b = wb;
  ushort* wo_b   = wqkv_b + (size_t)4*3*D_*D_;
  ushort* w1_b   = wo_b   + (size_t)4*D_*D_;
  ushort* w2_b   = w1_b   + (size_t)4*FF_*D_;
  float*  ybuf = out;

  const int M = B_*L_;

  wconv_kernel<<<dim3(3*D_/32, D_/32, 4), 256, 0, stream>>>(Wqkv, wqkv_b, D_, 3*D_);
  wconv_kernel<<<dim3(D_/32,   D_/32, 4), 256, 0, stream>>>(Wo,   wo_b,   D_, D_);
  wconv_kernel<<<dim3(FF_/32,  D_/32, 4), 256, 0, stream>>>(W1,   w1_b,   D_, FF_);
  wconv_kernel<<<dim3(D_/32,  FF_/32, 4), 256, 0, stream>>>(W2,   w2_b,   FF_, D_);

  concat_kernel<<<4096, 256, 0, stream>>>(pcpt, gen, xbuf, xbf);

  for (int i = 0; i < LAYERS_; ++i) {
    const ushort* wqkv_i = wqkv_b + (size_t)i*3*D_*D_;
    const ushort* wo_i   = wo_b   + (size_t)i*D_*D_;
    const ushort* w1_i   = w1_b   + (size_t)i*FF_*D_;
    const ushort* w2_i   = w2_b   + (size_t)i*D_*FF_;
    const float* bqkv_i = bqkv + (size_t)i*3*D_;
    const float* bo_i   = bo   + (size_t)i*D_;
    const float* b1_i   = b1   + (size_t)i*FF_;
    const float* b2_i   = b2   + (size_t)i*D_;
    const float* g1_i   = g1   + (size_t)i*D_;
    const float* be1_i  = be1  + (size_t)i*D_;
    const float* g2_i   = g2   + (size_t)i*D_;
    const float* be2_i  = be2  + (size_t)i*D_;

    // grid: (m-tiles, n-tiles) -> n-tiles of an m-band share an XCD
    mgemm_qkv<<<dim3(M/128, 3*D_/128), 256, 0, stream>>>(
        xbf, wqkv_i, bqkv_i, qb, kb, vtb);

    attn_mfma<<<B_*H_*(L_/64), 256, 0, stream>>>(qb, kb, vtb, abf);

    mgemm<64,0,1,0><<<dim3(M/128, D_/64), 256, 0, stream>>>(
        abf, wo_i, bo_i, xbuf, ybuf, M, D_, D_);

    ln_kernel<<<M, 64, 0, stream>>>(ybuf, g1_i, be1_i, xbuf, xbf);

    mgemm<128,1,0,1><<<dim3(M/128, FF_/128), 256, 0, stream>>>(
        xbf, w1_i, b1_i, nullptr, hbf, M, FF_, D_);

    mgemm<64,0,1,0><<<dim3(M/128, D_/64), 256, 0, stream>>>(
        hbf, w2_i, b2_i, xbuf, ybuf, M, D_, FF_);

    ln_kernel<<<M, 64, 0, stream>>>(ybuf, g2_i, be2_i, xbuf, xbf);
  }

  writeout_kernel<<<4096, 256, 0, stream>>>(xbuf, out);
}

// Round 9
// 795.902 us; speedup vs baseline: 23.1856x; 1.0475x over previous
//
#include <hip/hip_runtime.h>
#include <hip/hip_bf16.h>

#define B_ 4
#define P_ 1024
#define G_ 1024
#define L_ 2048
#define D_ 512
#define FF_ 2048
#define H_ 8
#define DH_ 64
#define LAYERS_ 4
#define LN_EPS_ 1e-5f

typedef __attribute__((ext_vector_type(8))) short bf16x8;
typedef __attribute__((ext_vector_type(4))) float f32x4;

__device__ __forceinline__ ushort f2b(float f) {
  unsigned u = __float_as_uint(f);
  unsigned r = (u + 0x7fffu + ((u >> 16) & 1u)) >> 16;
  return (ushort)r;
}
__device__ __forceinline__ float b2f(ushort u) {
  return __uint_as_float(((unsigned)u) << 16);
}

// async 16B global->LDS (DMA; dest = wave-uniform base + lane*16)
__device__ __forceinline__ void gld16(const ushort* g, ushort* l) {
  __builtin_amdgcn_global_load_lds(
      (const __attribute__((address_space(1))) void*)g,
      (__attribute__((address_space(3))) void*)l, 16, 0, 0);
}

// ---------------- concat pcpt+gen -> x (fp32) + xbf (bf16) ----------------
__global__ __launch_bounds__(256) void concat_kernel(const float* __restrict__ p,
    const float* __restrict__ g, float* __restrict__ x, ushort* __restrict__ xb)
{
  const int LD4 = L_*D_/4, PD4 = P_*D_/4;
  int i = blockIdx.x*256 + threadIdx.x;
  int b = i / LD4, r = i - b*LD4;
  float4 v;
  if (r < PD4) v = ((const float4*)p)[(size_t)b*PD4 + r];
  else         v = ((const float4*)g)[(size_t)b*PD4 + (r-PD4)];
  ((float4*)x)[i] = v;
  ushort4 h; h.x=f2b(v.x); h.y=f2b(v.y); h.z=f2b(v.z); h.w=f2b(v.w);
  ((ushort4*)xb)[i] = h;
}

// ---------------- writeout ----------------
__global__ __launch_bounds__(256) void writeout_kernel(const float* __restrict__ x,
    float* __restrict__ out)
{
  const int LD4 = L_*D_/4, PD4 = P_*D_/4, HALF = B_*PD4;
  int i = blockIdx.x*256 + threadIdx.x;
  int half = (i >= HALF) ? 1 : 0;
  int r = i - half*HALF;
  int b = r / PD4, q = r - b*PD4;
  ((float4*)out)[i] = ((const float4*)x)[(size_t)b*LD4 + half*PD4 + q];
}

// ---------------- weight transpose+convert: src K x N fp32 -> dst N x K bf16 ----------------
__global__ __launch_bounds__(256) void wconv_kernel(const float* __restrict__ src,
    ushort* __restrict__ dst, int K, int N)
{
  __shared__ float tile[32][33];
  int n0 = blockIdx.x*32, k0 = blockIdx.y*32, l = blockIdx.z;
  src += (size_t)l*K*N; dst += (size_t)l*K*N;
  int tx = threadIdx.x & 31, ty = threadIdx.x >> 5;
  #pragma unroll
  for (int u=0;u<4;++u) tile[ty+8*u][tx] = src[(size_t)(k0+ty+8*u)*N + n0+tx];
  __syncthreads();
  #pragma unroll
  for (int u=0;u<4;++u) dst[(size_t)(n0+ty+8*u)*K + k0+tx] = f2b(tile[tx][ty+8*u]);
}

// ---------------- bf16 MFMA GEMM, BN_ in {128,64}, BM=128, BK=64 ----------------
// LDS: 16B chunk c (0..7) of row r -> slot r*8 + (c ^ (r&7)); loader chunk col
// cch = (t&7)^((t>>3)&7) is invariant across the 4 row-groups; reader offset
// ((s*4+fq) ^ (fr&7))*8. Max 2 lanes/bank -> conflict-free. BK=64 halves the
// number of vmcnt(0) barrier drains vs BK=32 (the latency binder at K<=2048).
template<int BN_, int RELU, int RES, int OUTBF>
__global__ __launch_bounds__(256) void mgemm(
    const ushort* __restrict__ A, const ushort* __restrict__ Bt,
    const float* __restrict__ bias, const float* __restrict__ res,
    void* __restrict__ Cout, int M, int N, int K)
{
  constexpr int MI = (BN_ == 128) ? 4 : 2;
  constexpr int BL = BN_ / 32;               // B loader row-groups
  __shared__ ushort As[128*64];
  __shared__ ushort Bs[BN_*64];
  int t = threadIdx.x;
  int lane = t & 63, w = t >> 6;
  int wm = (BN_ == 128) ? (w >> 1) * 64 : w * 32;
  int wn = (BN_ == 128) ? (w & 1) * 64 : 0;
  int m0 = blockIdx.x * 128, n0 = blockIdx.y * BN_;

  f32x4 acc[MI][4] = {};

  int rbase = t >> 3;                        // 0..31
  int cch   = (t & 7) ^ ((t >> 3) & 7);      // swizzled chunk col (L-invariant)
  const ushort* Ag = A  + (size_t)(m0 + rbase)*K + cch*8;
  const ushort* Bg = Bt + (size_t)(n0 + rbase)*K + cch*8;
  ushort* Asl = As + t*8;
  ushort* Bsl = Bs + t*8;
  const size_t rowK32 = (size_t)32 * K;

  int fr = lane & 15, fq = lane >> 4;
  int swr[2];
  swr[0] = ((0*4 + fq) ^ (fr & 7)) * 8;
  swr[1] = ((1*4 + fq) ^ (fr & 7)) * 8;
  const ushort* Ard = As + (wm + fr)*64;
  const ushort* Brd = Bs + (wn + fr)*64;

  for (int k0 = 0; k0 < K; k0 += 64) {
    __syncthreads();
    #pragma unroll
    for (int L = 0; L < 4; ++L)  gld16(Ag + L*rowK32, Asl + L*2048);
    #pragma unroll
    for (int L = 0; L < BL; ++L) gld16(Bg + L*rowK32, Bsl + L*2048);
    Ag += 64; Bg += 64;
    __syncthreads();
    #pragma unroll
    for (int s = 0; s < 2; ++s) {
      int sw = swr[s];
      bf16x8 af[MI], bfr[4];
      #pragma unroll
      for (int i=0;i<MI;++i) af[i]  = *(const bf16x8*)(Ard + i*16*64 + sw);
      #pragma unroll
      for (int j=0;j<4;++j)  bfr[j] = *(const bf16x8*)(Brd + j*16*64 + sw);
      #pragma unroll
      for (int i=0;i<MI;++i)
        #pragma unroll
        for (int j=0;j<4;++j)
          acc[i][j] = __builtin_amdgcn_mfma_f32_16x16x32_bf16(af[i], bfr[j], acc[i][j], 0, 0, 0);
    }
  }

  int ncol = lane & 15;
  int rquad = (lane >> 4) * 4;
  #pragma unroll
  for (int j=0;j<4;++j) {
    int n = n0 + wn + j*16 + ncol;
    float bv = bias[n];
    #pragma unroll
    for (int i=0;i<MI;++i) {
      int mbase = m0 + wm + i*16 + rquad;
      #pragma unroll
      for (int r=0;r<4;++r) {
        int m = mbase + r;
        float c = acc[i][j][r] + bv;
        if (RES) c += res[(size_t)m*N + n];
        if (RELU) c = fmaxf(c, 0.f);
        if (OUTBF) ((ushort*)Cout)[(size_t)m*N + n] = f2b(c);
        else       ((float*)Cout)[(size_t)m*N + n] = c;
      }
    }
  }
}

// ---------------- QKV GEMM (BK=64): bf16 out; q pre-scaled; v transposed ----------------
__global__ __launch_bounds__(256) void mgemm_qkv(
    const ushort* __restrict__ A,    // M x 512 bf16 (x)
    const ushort* __restrict__ Bt,   // 1536 x 512 bf16
    const float* __restrict__ bias,  // 1536
    ushort* __restrict__ qb,         // [b,h,l,64]  (pre-scaled by 0.125)
    ushort* __restrict__ kb,         // [b,h,l,64]
    ushort* __restrict__ vtb)        // [b,h,64,l]
{
  const int K = D_;
  __shared__ ushort As[128*64];
  __shared__ ushort Bs[128*64];
  int t = threadIdx.x;
  int lane = t & 63, w = t >> 6;
  int wm = (w >> 1) * 64, wn = (w & 1) * 64;
  int m0 = blockIdx.x * 128, n0 = blockIdx.y * 128;

  f32x4 acc[4][4] = {};

  int rbase = t >> 3;
  int cch   = (t & 7) ^ ((t >> 3) & 7);
  const ushort* Ag = A  + (size_t)(m0 + rbase)*K + cch*8;
  const ushort* Bg = Bt + (size_t)(n0 + rbase)*K + cch*8;
  ushort* Asl = As + t*8;
  ushort* Bsl = Bs + t*8;
  const size_t rowK32 = (size_t)32 * K;

  int fr = lane & 15, fq = lane >> 4;
  int swr[2];
  swr[0] = ((0*4 + fq) ^ (fr & 7)) * 8;
  swr[1] = ((1*4 + fq) ^ (fr & 7)) * 8;
  const ushort* Ard = As + (wm + fr)*64;
  const ushort* Brd = Bs + (wn + fr)*64;

  for (int k0 = 0; k0 < K; k0 += 64) {
    __syncthreads();
    #pragma unroll
    for (int L = 0; L < 4; ++L) gld16(Ag + L*rowK32, Asl + L*2048);
    #pragma unroll
    for (int L = 0; L < 4; ++L) gld16(Bg + L*rowK32, Bsl + L*2048);
    Ag += 64; Bg += 64;
    __syncthreads();
    #pragma unroll
    for (int s = 0; s < 2; ++s) {
      int sw = swr[s];
      bf16x8 af[4], bfr[4];
      #pragma unroll
      for (int i=0;i<4;++i) af[i]  = *(const bf16x8*)(Ard + i*16*64 + sw);
      #pragma unroll
      for (int j=0;j<4;++j) bfr[j] = *(const bf16x8*)(Brd + j*16*64 + sw);
      #pragma unroll
      for (int i=0;i<4;++i)
        #pragma unroll
        for (int j=0;j<4;++j)
          acc[i][j] = __builtin_amdgcn_mfma_f32_16x16x32_bf16(af[i], bfr[j], acc[i][j], 0, 0, 0);
    }
  }

  int ncol = lane & 15;
  int rquad = (lane >> 4) * 4;
  #pragma unroll
  for (int j=0;j<4;++j) {
    int n = n0 + wn + j*16 + ncol;
    float bv = bias[n];
    int part = n >> 9;            // 0=q 1=k 2=v (block-uniform: 128 | 512)
    int wi = n & 511;
    int h = wi >> 6, d = wi & 63;
    #pragma unroll
    for (int i=0;i<4;++i) {
      int mbase = m0 + wm + i*16 + rquad;
      #pragma unroll
      for (int r=0;r<4;++r) {
        int m = mbase + r;
        int b = m >> 11, l = m & 2047;
        int bh = b*H_ + h;
        float cv = acc[i][j][r] + bv;
        if (part == 0) cv *= 0.125f;       // fold 1/sqrt(dh) into q
        ushort c = f2b(cv);
        if (part == 0)      qb[((size_t)bh*L_ + l)*DH_ + d] = c;
        else if (part == 1) kb[((size_t)bh*L_ + l)*DH_ + d] = c;
        else                vtb[((size_t)bh*DH_ + d)*L_ + l] = c;
      }
    }
  }
}

// ---------------- MFMA flash attention, one-pass softmax ----------------
__global__ __launch_bounds__(256) void attn_mfma(
    const ushort* __restrict__ qb, const ushort* __restrict__ kb,
    const ushort* __restrict__ vtb, ushort* __restrict__ outa)
{
  __shared__ ushort Qs[64*72];
  __shared__ ushort Ks[64*72];
  __shared__ ushort Vts[64*72];
  __shared__ ushort Ps[4*16*72];
  __shared__ float dls[64];

  int t = threadIdx.x;
  int lane = t & 63, w = t >> 6;
  int qt = blockIdx.x & 31;
  int h  = (blockIdx.x >> 5) & 7;
  int b  = blockIdx.x >> 8;
  int l0 = qt * 64;
  bool isgen = (l0 >= P_);
  int bh = b*H_ + h;

  const ushort* qg  = qb  + ((size_t)bh*L_ + l0)*DH_;
  const ushort* kgb = kb  + (size_t)bh*L_*DH_;
  const ushort* vtg = vtb + (size_t)bh*DH_*L_;

  int sr = t >> 3, sc = (t & 7) * 8;

  {
    uint4 x0 = *(const uint4*)(qg + (size_t)sr*DH_ + sc);
    uint4 x1 = *(const uint4*)(qg + (size_t)(sr+32)*DH_ + sc);
    *(uint4*)(Qs + sr*72 + sc) = x0;
    *(uint4*)(Qs + (sr+32)*72 + sc) = x1;
  }
  __syncthreads();

  int fr = lane & 15, fq = lane >> 4;
  bf16x8 qf[2];
  qf[0] = *(const bf16x8*)(Qs + (16*w + fr)*72 + 0*32 + fq*8);
  qf[1] = *(const bf16x8*)(Qs + (16*w + fr)*72 + 1*32 + fq*8);

  float den[4] = {0.f, 0.f, 0.f, 0.f};
  f32x4 o[4] = {};

  ushort* Pw = Ps + w*16*72;

  // register prefetch of K/V tile kt=0
  uint4 pk0 = *(const uint4*)(kgb + (size_t)sr*DH_ + sc);
  uint4 pk1 = *(const uint4*)(kgb + (size_t)(sr+32)*DH_ + sc);
  uint4 pv0 = *(const uint4*)(vtg + (size_t)sr*L_ + sc);
  uint4 pv1 = *(const uint4*)(vtg + (size_t)(sr+32)*L_ + sc);

  for (int kt = 0; kt < 16; ++kt) {
    __syncthreads();
    *(uint4*)(Ks + sr*72 + sc) = pk0;
    *(uint4*)(Ks + (sr+32)*72 + sc) = pk1;
    *(uint4*)(Vts + sr*72 + sc) = pv0;
    *(uint4*)(Vts + (sr+32)*72 + sc) = pv1;
    __syncthreads();

    if (kt < 15) {
      int p1 = (kt + 1) * 64;
      pk0 = *(const uint4*)(kgb + (size_t)(p1+sr)*DH_ + sc);
      pk1 = *(const uint4*)(kgb + (size_t)(p1+sr+32)*DH_ + sc);
      pv0 = *(const uint4*)(vtg + (size_t)sr*L_ + p1 + sc);
      pv1 = *(const uint4*)(vtg + (size_t)(sr+32)*L_ + p1 + sc);
    }

    f32x4 sc4[4] = {};
    #pragma unroll
    for (int s=0;s<2;++s) {
      #pragma unroll
      for (int j=0;j<4;++j) {
        bf16x8 kf = *(const bf16x8*)(Ks + (j*16 + fr)*72 + s*32 + fq*8);
        sc4[j] = __builtin_amdgcn_mfma_f32_16x16x32_bf16(qf[s], kf, sc4[j], 0, 0, 0);
      }
    }

    #pragma unroll
    for (int r=0;r<4;++r) {
      float e0 = __expf(sc4[0][r]);
      float e1 = __expf(sc4[1][r]);
      float e2 = __expf(sc4[2][r]);
      float e3 = __expf(sc4[3][r]);
      den[r] += (e0+e1) + (e2+e3);
      Pw[(fq*4+r)*72 +  0 + fr] = (ushort)(__float_as_uint(e0) >> 16);
      Pw[(fq*4+r)*72 + 16 + fr] = (ushort)(__float_as_uint(e1) >> 16);
      Pw[(fq*4+r)*72 + 32 + fr] = (ushort)(__float_as_uint(e2) >> 16);
      Pw[(fq*4+r)*72 + 48 + fr] = (ushort)(__float_as_uint(e3) >> 16);
    }
    asm volatile("s_waitcnt lgkmcnt(0)" ::: "memory");

    #pragma unroll
    for (int s=0;s<2;++s) {
      bf16x8 pf = *(const bf16x8*)(Pw + fr*72 + s*32 + fq*8);
      #pragma unroll
      for (int j=0;j<4;++j) {
        bf16x8 vf = *(const bf16x8*)(Vts + (j*16 + fr)*72 + s*32 + fq*8);
        o[j] = __builtin_amdgcn_mfma_f32_16x16x32_bf16(pf, vf, o[j], 0, 0, 0);
      }
    }
  }

  #pragma unroll
  for (int r=0;r<4;++r) {
    float d = den[r];
    d += __shfl_xor(d, 1, 16);
    d += __shfl_xor(d, 2, 16);
    d += __shfl_xor(d, 4, 16);
    d += __shfl_xor(d, 8, 16);
    den[r] = d;
  }

  if (isgen) {
    __syncthreads();
    {
      uint4 k0v = *(const uint4*)(kgb + (size_t)(l0+sr)*DH_ + sc);
      uint4 k1v = *(const uint4*)(kgb + (size_t)(l0+sr+32)*DH_ + sc);
      uint4 v0v = *(const uint4*)(vtg + (size_t)sr*L_ + l0 + sc);
      uint4 v1v = *(const uint4*)(vtg + (size_t)(sr+32)*L_ + l0 + sc);
      *(uint4*)(Ks + sr*72 + sc) = k0v;
      *(uint4*)(Ks + (sr+32)*72 + sc) = k1v;
      *(uint4*)(Vts + sr*72 + sc) = v0v;
      *(uint4*)(Vts + (sr+32)*72 + sc) = v1v;
    }
    __syncthreads();
    {
      int row = t >> 2, part = t & 3;
      float dsum = 0.f;
      #pragma unroll
      for (int u=0;u<16;++u) {
        int d = part*16 + u;
        dsum = fmaf(b2f(Qs[row*72+d]), b2f(Ks[row*72+d]), dsum);
      }
      dsum += __shfl_xor(dsum, 1, 4);
      dsum += __shfl_xor(dsum, 2, 4);
      if (part == 0) dls[row] = dsum;
    }
    __syncthreads();
    #pragma unroll
    for (int r=0;r<4;++r) {
      int rr = 16*w + fq*4 + r;
      float ed = __expf(dls[rr]);
      den[r] += ed;
      #pragma unroll
      for (int j=0;j<4;++j) {
        float vv = b2f(Vts[(j*16 + fr)*72 + rr]);
        o[j][r] += ed*vv;
      }
    }
  }

  #pragma unroll
  for (int r=0;r<4;++r) {
    float inv = 1.f / den[r];
    int l = l0 + 16*w + fq*4 + r;
    #pragma unroll
    for (int j=0;j<4;++j)
      outa[((size_t)b*L_ + l)*D_ + h*DH_ + j*16 + fr] = f2b(o[j][r]*inv);
  }
}

// ---------------- LayerNorm -> x fp32 + xbf bf16 ----------------
__global__ __launch_bounds__(64) void ln_kernel(const float* __restrict__ y,
    const float* __restrict__ gw, const float* __restrict__ bw,
    float* __restrict__ x, ushort* __restrict__ xb)
{
  int row = blockIdx.x, t = threadIdx.x;
  const float4* yr = (const float4*)(y + (size_t)row*D_);
  float4 v0 = yr[t], v1 = yr[t+64];
  float s = v0.x+v0.y+v0.z+v0.w + v1.x+v1.y+v1.z+v1.w;
  for (int off=32; off>0; off>>=1) s += __shfl_down(s, off, 64);
  s = __shfl(s, 0, 64);
  float mu = s * (1.f/D_);
  float dx;
  float q = 0.f;
  dx=v0.x-mu; q+=dx*dx; dx=v0.y-mu; q+=dx*dx; dx=v0.z-mu; q+=dx*dx; dx=v0.w-mu; q+=dx*dx;
  dx=v1.x-mu; q+=dx*dx; dx=v1.y-mu; q+=dx*dx; dx=v1.z-mu; q+=dx*dx; dx=v1.w-mu; q+=dx*dx;
  for (int off=32; off>0; off>>=1) q += __shfl_down(q, off, 64);
  q = __shfl(q, 0, 64);
  float rinv = rsqrtf(q*(1.f/D_) + LN_EPS_);
  const float4* g4 = (const float4*)gw;
  const float4* b4 = (const float4*)bw;
  float4 gv0=g4[t], gv1=g4[t+64], bv0=b4[t], bv1=b4[t+64];
  float4 o0, o1;
  o0.x=(v0.x-mu)*rinv*gv0.x+bv0.x; o0.y=(v0.y-mu)*rinv*gv0.y+bv0.y;
  o0.z=(v0.z-mu)*rinv*gv0.z+bv0.z; o0.w=(v0.w-mu)*rinv*gv0.w+bv0.w;
  o1.x=(v1.x-mu)*rinv*gv1.x+bv1.x; o1.y=(v1.y-mu)*rinv*gv1.y+bv1.y;
  o1.z=(v1.z-mu)*rinv*gv1.z+bv1.z; o1.w=(v1.w-mu)*rinv*gv1.w+bv1.w;
  float4* xr = (float4*)(x + (size_t)row*D_);
  xr[t]=o0; xr[t+64]=o1;
  ushort4 h0, h1;
  h0.x=f2b(o0.x); h0.y=f2b(o0.y); h0.z=f2b(o0.z); h0.w=f2b(o0.w);
  h1.x=f2b(o1.x); h1.y=f2b(o1.y); h1.z=f2b(o1.z); h1.w=f2b(o1.w);
  ushort4* xbr = (ushort4*)(xb + (size_t)row*D_);
  xbr[t]=h0; xbr[t+64]=h1;
}

extern "C" void kernel_launch(void* const* d_in, const int* in_sizes, int n_in,
                              void* d_out, int out_size, void* d_ws, size_t ws_size,
                              hipStream_t stream) {
  const float* pcpt = (const float*)d_in[0];
  const float* gen  = (const float*)d_in[1];
  const float* Wqkv = (const float*)d_in[3];
  const float* bqkv = (const float*)d_in[4];
  const float* Wo   = (const float*)d_in[5];
  const float* bo   = (const float*)d_in[6];
  const float* W1   = (const float*)d_in[7];
  const float* b1   = (const float*)d_in[8];
  const float* W2   = (const float*)d_in[9];
  const float* b2   = (const float*)d_in[10];
  const float* g1   = (const float*)d_in[11];
  const float* be1  = (const float*)d_in[12];
  const float* g2   = (const float*)d_in[13];
  const float* be2  = (const float*)d_in[14];
  float* out = (float*)d_out;

  const size_t XD  = (size_t)B_*L_*D_;
  const size_t HKV = (size_t)B_*H_*L_*DH_;
  const size_t HFF = (size_t)B_*L_*FF_;

  float*  xbuf = (float*)d_ws;
  ushort* xbf  = (ushort*)(xbuf + XD);
  ushort* region = xbf + XD;
  ushort* qb  = region;                        // aliased with hbf
  ushort* kb  = region + HKV;
  ushort* vtb = region + 2*HKV;
  ushort* hbf = region;
  ushort* abf = region + HFF;
  ushort* wb  = abf + XD;
  ushort* wqkv_b = wb;
  ushort* wo_b   = wqkv_b + (size_t)4*3*D_*D_;
  ushort* w1_b   = wo_b   + (size_t)4*D_*D_;
  ushort* w2_b   = w1_b   + (size_t)4*FF_*D_;
  float*  ybuf = out;

  const int M = B_*L_;

  wconv_kernel<<<dim3(3*D_/32, D_/32, 4), 256, 0, stream>>>(Wqkv, wqkv_b, D_, 3*D_);
  wconv_kernel<<<dim3(D_/32,   D_/32, 4), 256, 0, stream>>>(Wo,   wo_b,   D_, D_);
  wconv_kernel<<<dim3(FF_/32,  D_/32, 4), 256, 0, stream>>>(W1,   w1_b,   D_, FF_);
  wconv_kernel<<<dim3(D_/32,  FF_/32, 4), 256, 0, stream>>>(W2,   w2_b,   FF_, D_);

  concat_kernel<<<4096, 256, 0, stream>>>(pcpt, gen, xbuf, xbf);

  for (int i = 0; i < LAYERS_; ++i) {
    const ushort* wqkv_i = wqkv_b + (size_t)i*3*D_*D_;
    const ushort* wo_i   = wo_b   + (size_t)i*D_*D_;
    const ushort* w1_i   = w1_b   + (size_t)i*FF_*D_;
    const ushort* w2_i   = w2_b   + (size_t)i*D_*FF_;
    const float* bqkv_i = bqkv + (size_t)i*3*D_;
    const float* bo_i   = bo   + (size_t)i*D_;
    const float* b1_i   = b1   + (size_t)i*FF_;
    const float* b2_i   = b2   + (size_t)i*D_;
    const float* g1_i   = g1   + (size_t)i*D_;
    const float* be1_i  = be1  + (size_t)i*D_;
    const float* g2_i   = g2   + (size_t)i*D_;
    const float* be2_i  = be2  + (size_t)i*D_;

    // grid: (m-tiles, n-tiles) -> n-tiles of an m-band share an XCD
    mgemm_qkv<<<dim3(M/128, 3*D_/128), 256, 0, stream>>>(
        xbf, wqkv_i, bqkv_i, qb, kb, vtb);

    attn_mfma<<<B_*H_*(L_/64), 256, 0, stream>>>(qb, kb, vtb, abf);

    mgemm<64,0,1,0><<<dim3(M/128, D_/64), 256, 0, stream>>>(
        abf, wo_i, bo_i, xbuf, ybuf, M, D_, D_);

    ln_kernel<<<M, 64, 0, stream>>>(ybuf, g1_i, be1_i, xbuf, xbf);

    mgemm<128,1,0,1><<<dim3(M/128, FF_/128), 256, 0, stream>>>(
        xbf, w1_i, b1_i, nullptr, hbf, M, FF_, D_);

    mgemm<64,0,1,0><<<dim3(M/128, D_/64), 256, 0, stream>>>(
        hbf, w2_i, b2_i, xbuf, ybuf, M, D_, FF_);

    ln_kernel<<<M, 64, 0, stream>>>(ybuf, g2_i, be2_i, xbuf, xbf);
  }

  writeout_kernel<<<4096, 256, 0, stream>>>(xbuf, out);
}